// Round 2
// baseline (3092.823 us; speedup 1.0000x reference)
//
#include <hip/hip_runtime.h>
#include <math.h>

#define B_ 4
#define L_ 2048
#define G_ 256
#define T_ 2304          // G_ + L_
#define DM 1024
#define DINNER 2048
#define NH 16
#define HD 128
#define NSTATE 64
#define CONVD 2176       // DINNER + 2*NSTATE
#define DPROJ 4240       // 2*DINNER + 2*NSTATE + NH
#define NCHUNK 9
#define CK 256
#define EPSV 1e-5f

typedef unsigned short bf16t;

__device__ __forceinline__ float bf2f(bf16t u) {
  return __uint_as_float(((unsigned int)u) << 16);
}
__device__ __forceinline__ bf16t f2bf(float f) {
  unsigned int u = __float_as_uint(f);
  u += 0x7FFFu + ((u >> 16) & 1u);
  return (bf16t)(u >> 16);
}

// ---------- block-wide reduction of two values (blockDim == 256) ----------
__device__ __forceinline__ float2 block_reduce2(float a, float b) {
  __shared__ float sa[4], sb[4];
  #pragma unroll
  for (int off = 32; off > 0; off >>= 1) {
    a += __shfl_down(a, off, 64);
    b += __shfl_down(b, off, 64);
  }
  int lane = threadIdx.x & 63, wid = threadIdx.x >> 6;
  if (lane == 0) { sa[wid] = a; sb[wid] = b; }
  __syncthreads();
  return make_float2(sa[0] + sa[1] + sa[2] + sa[3], sb[0] + sb[1] + sb[2] + sb[3]);
}

// ---------- LayerNorm(local) / LayerNorm(global) + concat -> x (bf16) ----------
__global__ __launch_bounds__(256) void ln_concat_kernel(
    const float* __restrict__ localr, const float* __restrict__ globalr,
    const float* __restrict__ w1, const float* __restrict__ b1,
    const float* __restrict__ w2, const float* __restrict__ b2,
    bf16t* __restrict__ x) {
  int r = blockIdx.x;          // b*T_ + t
  int t = r % T_, b = r / T_;
  const float *src, *w, *bb;
  if (t < G_) { src = globalr + ((long)b * G_ + t) * DM;        w = w2; bb = b2; }
  else        { src = localr  + ((long)b * L_ + (t - G_)) * DM; w = w1; bb = b1; }
  float v[4]; float s = 0.f, sq = 0.f;
  #pragma unroll
  for (int i = 0; i < 4; i++) {
    v[i] = src[threadIdx.x + 256 * i];
    s += v[i]; sq += v[i] * v[i];
  }
  float2 r2 = block_reduce2(s, sq);
  float mu = r2.x * (1.f / DM);
  float var = r2.y * (1.f / DM) - mu * mu;
  float rstd = rsqrtf(var + EPSV);
  bf16t* dst = x + (long)r * DM;
  #pragma unroll
  for (int i = 0; i < 4; i++) {
    int d = threadIdx.x + 256 * i;
    dst[d] = f2bf((v[i] - mu) * rstd * w[d] + bb[d]);
  }
}

// ---------- in_proj GEMM: x(bf16) @ W^T, routed epilogue -> z / xBCpre / dtraw ----------
__global__ __launch_bounds__(256) void gemm_inproj(
    const bf16t* __restrict__ A, const float* __restrict__ W,
    bf16t* __restrict__ z, bf16t* __restrict__ xpre, float* __restrict__ dtr) {
  const int N = DPROJ, K = DM;
  __shared__ float As[16][68];
  __shared__ float Ws[16][68];
  int bm = blockIdx.y * 64, bn = blockIdx.x * 64;
  int tid = threadIdx.x;
  int tx = tid & 15, ty = tid >> 4;
  int lrow = tid >> 2, lk = (tid & 3) << 2;
  float acc[4][4] = {};
  const bf16t* Ap = A + (long)(bm + lrow) * K + lk;
  const float* Wp = W + (long)(bn + lrow) * K + lk;
  bool wok = (bn + lrow) < N;
  for (int k0 = 0; k0 < K; k0 += 16) {
    ushort4 au = *(const ushort4*)(Ap + k0);
    float4 av = make_float4(bf2f(au.x), bf2f(au.y), bf2f(au.z), bf2f(au.w));
    float4 wv = make_float4(0.f, 0.f, 0.f, 0.f);
    if (wok) wv = *(const float4*)(Wp + k0);
    __syncthreads();
    As[lk + 0][lrow] = av.x; As[lk + 1][lrow] = av.y;
    As[lk + 2][lrow] = av.z; As[lk + 3][lrow] = av.w;
    Ws[lk + 0][lrow] = wv.x; Ws[lk + 1][lrow] = wv.y;
    Ws[lk + 2][lrow] = wv.z; Ws[lk + 3][lrow] = wv.w;
    __syncthreads();
    #pragma unroll
    for (int kk = 0; kk < 16; kk++) {
      float4 a4 = *(const float4*)&As[kk][ty * 4];
      float4 b4 = *(const float4*)&Ws[kk][tx * 4];
      float aa[4] = {a4.x, a4.y, a4.z, a4.w};
      float bv[4] = {b4.x, b4.y, b4.z, b4.w};
      #pragma unroll
      for (int i = 0; i < 4; i++)
        #pragma unroll
        for (int j = 0; j < 4; j++) acc[i][j] += aa[i] * bv[j];
    }
  }
  #pragma unroll
  for (int i = 0; i < 4; i++) {
    int row = bm + ty * 4 + i;
    #pragma unroll
    for (int j = 0; j < 4; j++) {
      int col = bn + tx * 4 + j;
      if (col < N) {
        float v = acc[i][j];
        if (bn < DINNER)                z[(long)row * DINNER + col] = f2bf(v);
        else if (bn < DINNER + CONVD)   xpre[(long)row * CONVD + (col - DINNER)] = f2bf(v);
        else                            dtr[(long)row * NH + (col - DINNER - CONVD)] = v;
      }
    }
  }
}

// ---------- generic C[M,N] = act(A[M,K] @ W[N,K]^T + bias) + res ----------
// ACT: 0 none, 1 exact gelu. ABF: A is bf16. M%64==0, K%16==0; N guarded.
template<int ACT, bool BIAS, bool RES, bool ABF>
__global__ __launch_bounds__(256) void gemm_tn(
    const void* __restrict__ Av, const float* __restrict__ W,
    const float* __restrict__ bias, const float* __restrict__ res,
    float* __restrict__ C, int M, int N, int K) {
  __shared__ float As[16][68];
  __shared__ float Ws[16][68];
  int bm = blockIdx.y * 64, bn = blockIdx.x * 64;
  int tid = threadIdx.x;
  int tx = tid & 15, ty = tid >> 4;
  int lrow = tid >> 2, lk = (tid & 3) << 2;
  float acc[4][4] = {};
  const float* Wp = W + (long)(bn + lrow) * K + lk;
  bool wok = (bn + lrow) < N;
  for (int k0 = 0; k0 < K; k0 += 16) {
    float4 av;
    if (ABF) {
      const bf16t* Ap = (const bf16t*)Av + (long)(bm + lrow) * K + lk + k0;
      ushort4 au = *(const ushort4*)Ap;
      av = make_float4(bf2f(au.x), bf2f(au.y), bf2f(au.z), bf2f(au.w));
    } else {
      const float* Ap = (const float*)Av + (long)(bm + lrow) * K + lk + k0;
      av = *(const float4*)Ap;
    }
    float4 wv = make_float4(0.f, 0.f, 0.f, 0.f);
    if (wok) wv = *(const float4*)(Wp + k0);
    __syncthreads();
    As[lk + 0][lrow] = av.x; As[lk + 1][lrow] = av.y;
    As[lk + 2][lrow] = av.z; As[lk + 3][lrow] = av.w;
    Ws[lk + 0][lrow] = wv.x; Ws[lk + 1][lrow] = wv.y;
    Ws[lk + 2][lrow] = wv.z; Ws[lk + 3][lrow] = wv.w;
    __syncthreads();
    #pragma unroll
    for (int kk = 0; kk < 16; kk++) {
      float4 a4 = *(const float4*)&As[kk][ty * 4];
      float4 b4 = *(const float4*)&Ws[kk][tx * 4];
      float aa[4] = {a4.x, a4.y, a4.z, a4.w};
      float bv[4] = {b4.x, b4.y, b4.z, b4.w};
      #pragma unroll
      for (int i = 0; i < 4; i++)
        #pragma unroll
        for (int j = 0; j < 4; j++) acc[i][j] += aa[i] * bv[j];
    }
  }
  #pragma unroll
  for (int i = 0; i < 4; i++) {
    int row = bm + ty * 4 + i;
    #pragma unroll
    for (int j = 0; j < 4; j++) {
      int col = bn + tx * 4 + j;
      if (col < N) {
        float v = acc[i][j];
        if (BIAS) v += bias[col];
        if (ACT == 1) v = 0.5f * v * (1.f + erff(v * 0.70710678118f));
        if (RES) v += res[(long)row * N + col];
        C[(long)row * N + col] = v;
      }
    }
  }
}

// ---------- dt = softplus(dtraw + dt_bias) ----------
__global__ __launch_bounds__(256) void dt_kernel(
    const float* __restrict__ dtr, const float* __restrict__ dt_bias,
    float* __restrict__ dt) {
  int idx = blockIdx.x * 256 + threadIdx.x;   // < B_*T_*NH
  int h = idx & 15;
  float v = dtr[idx] + dt_bias[h];
  dt[idx] = (v > 20.f) ? v : log1pf(expf(v));
}

// ---------- causal depthwise conv(4) + bias + silu (bf16 in/out) ----------
__global__ __launch_bounds__(256) void conv_kernel(
    const bf16t* __restrict__ xpre, const float* __restrict__ cw,
    const float* __restrict__ cb, bf16t* __restrict__ out) {
  long idx = (long)blockIdx.x * 256 + threadIdx.x;
  if (idx >= (long)B_ * T_ * CONVD) return;
  int c = (int)(idx % CONVD);
  long r = idx / CONVD;          // b*T_ + t
  int t = (int)(r % T_);
  float acc = cb[c];
  #pragma unroll
  for (int i = 0; i < 4; i++) {
    int ts = t - 3 + i;
    if (ts >= 0) acc += bf2f(xpre[(r + (ts - t)) * CONVD + c]) * cw[c * 4 + i];
  }
  out[idx] = f2bf(acc / (1.f + expf(-acc)));   // silu
}

// ---------- per-chunk inclusive cumsum of dt*A  (Acum[(b*NH+h)*NC+c][k]) ----------
__global__ __launch_bounds__(256) void cumsum_kernel(
    const float* __restrict__ dt, const float* __restrict__ A_log,
    float* __restrict__ Acum) {
  int bid = blockIdx.x;                 // (b*NH+h)*NCHUNK + c
  int c = bid % NCHUNK; int hh = bid / NCHUNK;
  int h = hh % NH; int b = hh / NH;
  int k = threadIdx.x;
  float a = -expf(A_log[h]);
  long t = (long)b * T_ + c * CK + k;
  float v = dt[t * NH + h] * a;
  __shared__ float buf[2][CK];
  int cur = 0;
  buf[0][k] = v; __syncthreads();
  for (int off = 1; off < CK; off <<= 1) {
    float tv = buf[cur][k];
    if (k >= off) tv += buf[cur][k - off];
    buf[1 - cur][k] = tv; cur ^= 1; __syncthreads();
  }
  Acum[(long)bid * CK + k] = buf[cur][k];
}

// ---------- per-chunk states: cs[(b*NC+c)*NH+h][p][n] ----------
__global__ __launch_bounds__(256) void chunk_states_kernel(
    const bf16t* __restrict__ xbc, const float* __restrict__ dt,
    const float* __restrict__ Acum, float* __restrict__ cs) {
  int bid = blockIdx.x;                 // (b*NCHUNK+c)*NH + h
  int h = bid % NH; int bc = bid / NH;
  int c = bc % NCHUNK; int b = bc / NCHUNK;
  int tid = threadIdx.x;
  int pg = tid >> 4, ng = tid & 15;     // p0 = pg*8, n0 = ng*4
  __shared__ float Xs[32][128];
  __shared__ float Bs[32][68];
  __shared__ float wk[32];
  int acb = ((b * NH + h) * NCHUNK + c) * CK;
  float Alast = Acum[acb + CK - 1];
  float acc[8][4] = {};
  for (int k0 = 0; k0 < CK; k0 += 32) {
    __syncthreads();
    if (tid < 32) {
      long t = (long)b * T_ + c * CK + k0 + tid;
      wk[tid] = expf(Alast - Acum[acb + k0 + tid]) * dt[t * NH + h];
    }
    for (int e = tid; e < 32 * 64; e += 256) {
      int kk = e >> 6, pp = (e & 63) * 2;
      long t = (long)b * T_ + c * CK + k0 + kk;
      ushort2 u = *(const ushort2*)&xbc[t * CONVD + h * HD + pp];
      Xs[kk][pp] = bf2f(u.x); Xs[kk][pp + 1] = bf2f(u.y);
    }
    for (int e = tid; e < 32 * 32; e += 256) {
      int kk = e >> 5, nn = (e & 31) * 2;
      long t = (long)b * T_ + c * CK + k0 + kk;
      ushort2 u = *(const ushort2*)&xbc[t * CONVD + DINNER + nn];
      Bs[kk][nn] = bf2f(u.x); Bs[kk][nn + 1] = bf2f(u.y);
    }
    __syncthreads();
    for (int kk = 0; kk < 32; kk++) {
      float w = wk[kk];
      float bv[4];
      #pragma unroll
      for (int j = 0; j < 4; j++) bv[j] = Bs[kk][ng * 4 + j];
      #pragma unroll
      for (int i = 0; i < 8; i++) {
        float xv = Xs[kk][pg * 8 + i] * w;
        #pragma unroll
        for (int j = 0; j < 4; j++) acc[i][j] += xv * bv[j];
      }
    }
  }
  float* out = cs + (long)bid * HD * NSTATE;
  #pragma unroll
  for (int i = 0; i < 8; i++) {
    float4 v4 = make_float4(acc[i][0], acc[i][1], acc[i][2], acc[i][3]);
    *(float4*)&out[(pg * 8 + i) * NSTATE + ng * 4] = v4;
  }
}

// ---------- sequential inter-chunk recurrence, IN PLACE: cs[c] <- state entering c ----------
__global__ __launch_bounds__(256) void state_pass_kernel(
    float* __restrict__ cs, const float* __restrict__ Acum) {
  int bh = blockIdx.x;                  // b*NH + h
  int b = bh / NH, h = bh % NH;
  int e0 = blockIdx.y * 1024 + threadIdx.x;
  for (int q = 0; q < 4; q++) {
    int e = e0 + q * 256;
    float s = 0.f;
    for (int c = 0; c < NCHUNK; c++) {
      long idx = ((long)(b * NCHUNK + c) * NH + h) * (HD * NSTATE) + e;
      float tmp = cs[idx];
      cs[idx] = s;
      float g = expf(Acum[((b * NH + h) * NCHUNK + c) * CK + CK - 1]);
      s = s * g + tmp;
    }
  }
}

// ---------- Y = tril(C B^T * decay) X*dt + C . state_in * exp(Acum) + Dskip*xs ----------
__global__ __launch_bounds__(256) void ssd_y_kernel(
    const bf16t* __restrict__ xbc, const float* __restrict__ dt,
    const float* __restrict__ Acum, const float* __restrict__ sin_,
    const float* __restrict__ Dskip, bf16t* __restrict__ Y) {
  int bid = blockIdx.x;                 // (b*NCHUNK+c)*NH + h
  int h = bid % NH; int bc = bid / NH;
  int c = bc % NCHUNK; int b = bc / NCHUNK;
  int kb = blockIdx.y;                  // k-tile (32 rows)
  int tid = threadIdx.x;
  int kr = tid >> 3, pg = tid & 7;      // row kr, cols pg*4 + 32u + {0..3}
  __shared__ float Cs[32][68];
  __shared__ float Bs[32][68];
  __shared__ float Xs[32][128];
  __shared__ float Ss[32][33];
  __shared__ float Ak[32], Asb[32];
  int acb = ((b * NH + h) * NCHUNK + c) * CK;
  if (tid < 32) Ak[tid] = Acum[acb + kb * 32 + tid];
  for (int e = tid; e < 32 * 32; e += 256) {
    int kk = e >> 5, nn = (e & 31) * 2;
    long t = (long)b * T_ + c * CK + kb * 32 + kk;
    ushort2 u = *(const ushort2*)&xbc[t * CONVD + DINNER + NSTATE + nn];
    Cs[kk][nn] = bf2f(u.x); Cs[kk][nn + 1] = bf2f(u.y);
  }
  float acc[4][4] = {};
  for (int sb = 0; sb <= kb; sb++) {
    __syncthreads();
    if (tid < 32) Asb[tid] = Acum[acb + sb * 32 + tid];
    for (int e = tid; e < 32 * 32; e += 256) {
      int ss = e >> 5, nn = (e & 31) * 2;
      long t = (long)b * T_ + c * CK + sb * 32 + ss;
      ushort2 u = *(const ushort2*)&xbc[t * CONVD + DINNER + nn];
      Bs[ss][nn] = bf2f(u.x); Bs[ss][nn + 1] = bf2f(u.y);
    }
    for (int e = tid; e < 32 * 64; e += 256) {
      int ss = e >> 6, pp = (e & 63) * 2;
      long t = (long)b * T_ + c * CK + sb * 32 + ss;
      ushort2 u = *(const ushort2*)&xbc[t * CONVD + h * HD + pp];
      float dtv = dt[t * NH + h];
      Xs[ss][pp] = bf2f(u.x) * dtv; Xs[ss][pp + 1] = bf2f(u.y) * dtv;
    }
    __syncthreads();
    {
      int kr2 = tid >> 3, sbase = tid & 7;
      #pragma unroll
      for (int q = 0; q < 4; q++) {
        int ss2 = sbase + 8 * q;
        float dp = 0.f;
        #pragma unroll 8
        for (int n = 0; n < 64; n++) dp += Cs[kr2][n] * Bs[ss2][n];
        float val = 0.f;
        if (sb < kb || ss2 <= kr2) val = dp * expf(Ak[kr2] - Asb[ss2]);
        Ss[kr2][ss2] = val;
      }
    }
    __syncthreads();
    for (int ss = 0; ss < 32; ss++) {
      float sv = Ss[kr][ss];
      #pragma unroll
      for (int u = 0; u < 4; u++) {
        float4 xv = *(const float4*)&Xs[ss][pg * 4 + 32 * u];
        acc[u][0] += sv * xv.x; acc[u][1] += sv * xv.y;
        acc[u][2] += sv * xv.z; acc[u][3] += sv * xv.w;
      }
    }
  }
  // epilogue: Y_off + D_skip * xs, write out (bf16)
  float ek = expf(Ak[kr]);
  float dsk = Dskip[h];
  const float* sinb = sin_ + (long)bid * HD * NSTATE;
  long t = (long)b * T_ + c * CK + kb * 32 + kr;
  const bf16t* xrow = xbc + t * CONVD + h * HD;
  bf16t* yrow = Y + t * DINNER + h * HD;
  #pragma unroll
  for (int u = 0; u < 4; u++) {
    int p0 = pg * 4 + 32 * u;
    float off[4];
    #pragma unroll
    for (int j = 0; j < 4; j++) {
      const float4* sp = (const float4*)&sinb[(p0 + j) * NSTATE];
      float o = 0.f;
      #pragma unroll
      for (int n4 = 0; n4 < 16; n4++) {
        float4 s4 = sp[n4];
        float4 c4 = *(const float4*)&Cs[kr][n4 * 4];
        o += c4.x * s4.x + c4.y * s4.y + c4.z * s4.z + c4.w * s4.w;
      }
      off[j] = o;
    }
    ushort4 xu = *(const ushort4*)&xrow[p0];
    ushort4 r;
    r.x = f2bf(acc[u][0] + ek * off[0] + dsk * bf2f(xu.x));
    r.y = f2bf(acc[u][1] + ek * off[1] + dsk * bf2f(xu.y));
    r.z = f2bf(acc[u][2] + ek * off[2] + dsk * bf2f(xu.z));
    r.w = f2bf(acc[u][3] + ek * off[3] + dsk * bf2f(xu.w));
    *(ushort4*)&yrow[p0] = r;
  }
}

// ---------- y *= silu(z); RMSNorm * ssd_norm_w (in place on Y, bf16) ----------
__global__ __launch_bounds__(256) void gate_rms_kernel(
    const bf16t* __restrict__ z, const float* __restrict__ nw,
    bf16t* __restrict__ Y) {
  long r = blockIdx.x;
  const bf16t* zrow = z + r * DINNER;
  bf16t* yrow = Y + r * DINNER;
  int tid = threadIdx.x;
  float v[8]; float sq = 0.f;
  #pragma unroll
  for (int i = 0; i < 4; i++) {
    int d = tid * 2 + 512 * i;
    ushort2 zu = *(const ushort2*)&zrow[d];
    ushort2 yu = *(const ushort2*)&yrow[d];
    float z0 = bf2f(zu.x), z1 = bf2f(zu.y);
    float y0 = bf2f(yu.x) * (z0 / (1.f + expf(-z0)));
    float y1 = bf2f(yu.y) * (z1 / (1.f + expf(-z1)));
    v[2 * i] = y0; v[2 * i + 1] = y1;
    sq += y0 * y0 + y1 * y1;
  }
  float2 r2 = block_reduce2(sq, 0.f);
  float rms = rsqrtf(r2.x * (1.f / DINNER) + EPSV);
  #pragma unroll
  for (int i = 0; i < 4; i++) {
    int d = tid * 2 + 512 * i;
    ushort2 o;
    o.x = f2bf(v[2 * i] * rms * nw[d]);
    o.y = f2bf(v[2 * i + 1] * rms * nw[d + 1]);
    *(ushort2*)&yrow[d] = o;
  }
}

// ---------- residual add (last L rows) + LayerNorm3 ----------
__global__ __launch_bounds__(256) void res_ln3_kernel(
    const float* __restrict__ mfull, const bf16t* __restrict__ x,
    const float* __restrict__ w3, const float* __restrict__ b3,
    float* __restrict__ x2) {
  int rl = blockIdx.x;                  // b*L_ + tl
  int tl = rl % L_, b = rl / L_;
  long rt = (long)b * T_ + G_ + tl;
  const float* m = mfull + rt * DM;
  const bf16t* xr = x + rt * DM;
  float v[4]; float s = 0.f, sq = 0.f;
  #pragma unroll
  for (int i = 0; i < 4; i++) {
    int d = threadIdx.x + 256 * i;
    v[i] = m[d] + bf2f(xr[d]);
    s += v[i]; sq += v[i] * v[i];
  }
  float2 r2 = block_reduce2(s, sq);
  float mu = r2.x * (1.f / DM);
  float var = r2.y * (1.f / DM) - mu * mu;
  float rstd = rsqrtf(var + EPSV);
  float* dst = x2 + (long)rl * DM;
  #pragma unroll
  for (int i = 0; i < 4; i++) {
    int d = threadIdx.x + 256 * i;
    dst[d] = (v[i] - mu) * rstd * w3[d] + b3[d];
  }
}

extern "C" void kernel_launch(void* const* d_in, const int* in_sizes, int n_in,
                              void* d_out, int out_size, void* d_ws, size_t ws_size,
                              hipStream_t stream) {
  const float* localr = (const float*)d_in[0];
  const float* globalr= (const float*)d_in[1];
  const float* n1w = (const float*)d_in[2];
  const float* n1b = (const float*)d_in[3];
  const float* n2w = (const float*)d_in[4];
  const float* n2b = (const float*)d_in[5];
  const float* n3w = (const float*)d_in[6];
  const float* n3b = (const float*)d_in[7];
  const float* inpw= (const float*)d_in[8];
  const float* convw=(const float*)d_in[9];
  const float* convb=(const float*)d_in[10];
  const float* dtb = (const float*)d_in[11];
  const float* alog= (const float*)d_in[12];
  const float* dskp= (const float*)d_in[13];
  const float* ssdw= (const float*)d_in[14];
  const float* outw= (const float*)d_in[15];
  const float* f1w = (const float*)d_in[16];
  const float* f1b = (const float*)d_in[17];
  const float* f2w = (const float*)d_in[18];
  const float* f2b = (const float*)d_in[19];

  // ---- workspace layout (byte offsets); peak = 157,483,008 B (~150 MB) ----
  char* ws = (char*)d_ws;
  bf16t* x     = (bf16t*)(ws + 0);             // 9216*1024 bf16   = 18,874,368 B
  bf16t* z     = (bf16t*)(ws + 18874368);      // 9216*2048 bf16   = 37,748,736 B
  float* mfull = (float*)(ws + 18874368);      //   overlay: 9216*1024 f32 (after gate_rms)
  bf16t* xpre  = (bf16t*)(ws + 56623104);      // 9216*2176 bf16   = 40,108,032 B
  bf16t* Yb    = (bf16t*)(ws + 56623104);      //   overlay: 9216*2048 bf16 (after conv)
  float* dtraw = (float*)(ws + 96731136);      // 9216*16 f32      = 589,824 B
  float* dt    = (float*)(ws + 97320960);      // 9216*16 f32      = 589,824 B
  float* Acum  = (float*)(ws + 97910784);      // 64*9*256 f32     = 589,824 B
  bf16t* xbc   = (bf16t*)(ws + 98500608);      // 9216*2176 bf16   = 40,108,032 B
  float* x2    = (float*)(ws + 98500608);      //   overlay: 8192*1024 f32 (after ssd_y)
  float* cs    = (float*)(ws + 138608640);     // 576*8192 f32     = 18,874,368 B
  float* hbuf  = (float*)(ws + 138608640);     //   overlay: 8192*512 f32 (after ssd_y)

  ln_concat_kernel<<<B_ * T_, 256, 0, stream>>>(localr, globalr, n1w, n1b, n2w, n2b, x);

  gemm_inproj<<<dim3((DPROJ + 63) / 64, (B_ * T_) / 64), 256, 0, stream>>>(
      x, inpw, z, xpre, dtraw);

  dt_kernel<<<(B_ * T_ * NH) / 256, 256, 0, stream>>>(dtraw, dtb, dt);

  conv_kernel<<<(int)(((long)B_ * T_ * CONVD + 255) / 256), 256, 0, stream>>>(
      xpre, convw, convb, xbc);

  cumsum_kernel<<<B_ * NH * NCHUNK, 256, 0, stream>>>(dt, alog, Acum);

  chunk_states_kernel<<<B_ * NCHUNK * NH, 256, 0, stream>>>(xbc, dt, Acum, cs);

  state_pass_kernel<<<dim3(B_ * NH, 8), 256, 0, stream>>>(cs, Acum);

  ssd_y_kernel<<<dim3(B_ * NCHUNK * NH, 8), 256, 0, stream>>>(xbc, dt, Acum, cs, dskp, Yb);

  gate_rms_kernel<<<B_ * T_, 256, 0, stream>>>(z, ssdw, Yb);

  gemm_tn<0, false, false, true><<<dim3(DM / 64, (B_ * T_) / 64), 256, 0, stream>>>(
      Yb, outw, nullptr, nullptr, mfull, B_ * T_, DM, DINNER);

  res_ln3_kernel<<<B_ * L_, 256, 0, stream>>>(mfull, x, n3w, n3b, x2);

  gemm_tn<1, true, false, false><<<dim3((DM / 2) / 64, (B_ * L_) / 64), 256, 0, stream>>>(
      x2, f1w, f1b, nullptr, hbuf, B_ * L_, DM / 2, DM);

  gemm_tn<0, true, true, false><<<dim3(DM / 64, (B_ * L_) / 64), 256, 0, stream>>>(
      hbuf, f2w, f2b, x2, (float*)d_out, B_ * L_, DM, DM / 2);
}

// Round 3
// 1508.739 us; speedup vs baseline: 2.0499x; 2.0499x over previous
//
#include <hip/hip_runtime.h>
#include <math.h>

#define B_ 4
#define L_ 2048
#define G_ 256
#define T_ 2304          // G_ + L_
#define DM 1024
#define DINNER 2048
#define NH 16
#define HD 128
#define NSTATE 64
#define CONVD 2176       // DINNER + 2*NSTATE
#define DPROJ 4240       // 2*DINNER + 2*NSTATE + NH
#define NPROJ_PAD 4352   // DPROJ padded to 128
#define NCHUNK 9
#define CK 256
#define EPSV 1e-5f

typedef unsigned short bf16t;
using bf16x8 = __attribute__((ext_vector_type(8))) short;
using f32x4  = __attribute__((ext_vector_type(4))) float;

__device__ __forceinline__ float bf2f(bf16t u) {
  return __uint_as_float(((unsigned int)u) << 16);
}
__device__ __forceinline__ bf16t f2bf(float f) {
  unsigned int u = __float_as_uint(f);
  u += 0x7FFFu + ((u >> 16) & 1u);
  return (bf16t)(u >> 16);
}

__device__ __forceinline__ void g2lds16(const bf16t* g, short* l) {
  __builtin_amdgcn_global_load_lds(
      (const __attribute__((address_space(1))) unsigned int*)g,
      (__attribute__((address_space(3))) unsigned int*)l, 16, 0, 0);
}

// ---------- block-wide reduction of two values (blockDim == 256) ----------
__device__ __forceinline__ float2 block_reduce2(float a, float b) {
  __shared__ float sa[4], sb[4];
  #pragma unroll
  for (int off = 32; off > 0; off >>= 1) {
    a += __shfl_down(a, off, 64);
    b += __shfl_down(b, off, 64);
  }
  int lane = threadIdx.x & 63, wid = threadIdx.x >> 6;
  if (lane == 0) { sa[wid] = a; sb[wid] = b; }
  __syncthreads();
  return make_float2(sa[0] + sa[1] + sa[2] + sa[3], sb[0] + sb[1] + sb[2] + sb[3]);
}

// ---------- fp32 -> bf16 weight convert with zero row-padding ----------
__global__ __launch_bounds__(256) void cvt_pad_kernel(
    const float* __restrict__ w, bf16t* __restrict__ o, long nreal, long ntot) {
  long i = (long)blockIdx.x * 256 + threadIdx.x;
  if (i < ntot) o[i] = (i < nreal) ? f2bf(w[i]) : (bf16t)0;
}

// ---------- LayerNorm(local) / LayerNorm(global) + concat -> x (bf16) ----------
__global__ __launch_bounds__(256) void ln_concat_kernel(
    const float* __restrict__ localr, const float* __restrict__ globalr,
    const float* __restrict__ w1, const float* __restrict__ b1,
    const float* __restrict__ w2, const float* __restrict__ b2,
    bf16t* __restrict__ x) {
  int r = blockIdx.x;          // b*T_ + t
  int t = r % T_, b = r / T_;
  const float *src, *w, *bb;
  if (t < G_) { src = globalr + ((long)b * G_ + t) * DM;        w = w2; bb = b2; }
  else        { src = localr  + ((long)b * L_ + (t - G_)) * DM; w = w1; bb = b1; }
  float v[4]; float s = 0.f, sq = 0.f;
  #pragma unroll
  for (int i = 0; i < 4; i++) {
    v[i] = src[threadIdx.x + 256 * i];
    s += v[i]; sq += v[i] * v[i];
  }
  float2 r2 = block_reduce2(s, sq);
  float mu = r2.x * (1.f / DM);
  float var = r2.y * (1.f / DM) - mu * mu;
  float rstd = rsqrtf(var + EPSV);
  bf16t* dst = x + (long)r * DM;
  #pragma unroll
  for (int i = 0; i < 4; i++) {
    int d = threadIdx.x + 256 * i;
    dst[d] = f2bf((v[i] - mu) * rstd * w[d] + bb[d]);
  }
}

// ---------- MFMA bf16 GEMM: D[M,N] = A[M,K] @ W[N,K]^T, fused epilogues ----------
// EPI 0: route -> z(bf16) / xpre(bf16) / dtraw(f32)   (in_proj, N padded)
// EPI 1: Cf = f32 plain                               (out_proj)
// EPI 2: Cb = bf16 gelu(v + bias)                     (ffn1)
// EPI 3: Cf = f32 v + bias + bf16 res                 (ffn2 + residual)
template<int EPI>
__global__ __launch_bounds__(256) void gemm_mfma(
    const bf16t* __restrict__ A, const bf16t* __restrict__ W,
    const float* __restrict__ bias, const bf16t* __restrict__ res,
    float* __restrict__ Cf, bf16t* __restrict__ Cb,
    bf16t* __restrict__ z, bf16t* __restrict__ xpre, float* __restrict__ dtr,
    int M, int N, int K) {
  __shared__ __align__(16) short As[128 * 32];
  __shared__ __align__(16) short Ws[128 * 32];
  int tid = threadIdx.x;
  int lane = tid & 63, w = tid >> 6;
  int wr = w >> 1, wc = w & 1;
  int bm = blockIdx.y * 128, bn = blockIdx.x * 128;

  // staging chunks: 512 x 16B per matrix; thread handles chunk tid and tid+256
  int r1 = tid >> 2,         s1 = (tid & 3) * 8;
  int r2 = (tid + 256) >> 2, s2 = ((tid + 256) & 3) * 8;
  const bf16t* gA1 = A + (long)(bm + r1) * K + s1;
  const bf16t* gA2 = A + (long)(bm + r2) * K + s2;
  const bf16t* gW1 = W + (long)(bn + r1) * K + s1;
  const bf16t* gW2 = W + (long)(bn + r2) * K + s2;
  short* lA1 = As + tid * 8;
  short* lA2 = As + (tid + 256) * 8;
  short* lW1 = Ws + tid * 8;
  short* lW2 = Ws + (tid + 256) * 8;

  int arow = wr * 64 + (lane & 15);
  int brow = wc * 64 + (lane & 15);
  int koff = (lane >> 4) * 8;

  f32x4 acc[4][4] = {};
  for (int k0 = 0; k0 < K; k0 += 32) {
    g2lds16(gA1 + k0, lA1);
    g2lds16(gA2 + k0, lA2);
    g2lds16(gW1 + k0, lW1);
    g2lds16(gW2 + k0, lW2);
    __syncthreads();
    bf16x8 af[4], bf[4];
    #pragma unroll
    for (int mi = 0; mi < 4; mi++) af[mi] = *(bf16x8*)&As[(arow + mi * 16) * 32 + koff];
    #pragma unroll
    for (int ni = 0; ni < 4; ni++) bf[ni] = *(bf16x8*)&Ws[(brow + ni * 16) * 32 + koff];
    #pragma unroll
    for (int mi = 0; mi < 4; mi++)
      #pragma unroll
      for (int ni = 0; ni < 4; ni++)
        acc[mi][ni] = __builtin_amdgcn_mfma_f32_16x16x32_bf16(af[mi], bf[ni], acc[mi][ni], 0, 0, 0);
    __syncthreads();
  }

  // epilogue: D row = (lane>>4)*4 + reg, col = lane&15  (within 16x16 tile)
  int rb = wr * 64 + (lane >> 4) * 4;
  int cb = wc * 64 + (lane & 15);
  #pragma unroll
  for (int mi = 0; mi < 4; mi++) {
    #pragma unroll
    for (int ni = 0; ni < 4; ni++) {
      #pragma unroll
      for (int r = 0; r < 4; r++) {
        int row = bm + rb + mi * 16 + r;
        int col = bn + cb + ni * 16;
        float v = acc[mi][ni][r];
        if (EPI == 0) {
          if (col < DINNER)            z[(long)row * DINNER + col] = f2bf(v);
          else if (col < DINNER+CONVD) xpre[(long)row * CONVD + (col - DINNER)] = f2bf(v);
          else if (col < DPROJ)        dtr[(long)row * NH + (col - DINNER - CONVD)] = v;
        } else if (EPI == 1) {
          Cf[(long)row * N + col] = v;
        } else if (EPI == 2) {
          v += bias[col];
          v = 0.5f * v * (1.f + erff(v * 0.70710678118f));
          Cb[(long)row * N + col] = f2bf(v);
        } else {
          v += bias[col] + bf2f(res[(long)row * N + col]);
          Cf[(long)row * N + col] = v;
        }
      }
    }
  }
}

// ---------- dt = softplus(dtraw + dt_bias) ----------
__global__ __launch_bounds__(256) void dt_kernel(
    const float* __restrict__ dtr, const float* __restrict__ dt_bias,
    float* __restrict__ dt) {
  int idx = blockIdx.x * 256 + threadIdx.x;   // < B_*T_*NH
  int h = idx & 15;
  float v = dtr[idx] + dt_bias[h];
  dt[idx] = (v > 20.f) ? v : log1pf(expf(v));
}

// ---------- causal depthwise conv(4) + bias + silu (bf16 in/out) ----------
__global__ __launch_bounds__(256) void conv_kernel(
    const bf16t* __restrict__ xpre, const float* __restrict__ cw,
    const float* __restrict__ cb, bf16t* __restrict__ out) {
  long idx = (long)blockIdx.x * 256 + threadIdx.x;
  if (idx >= (long)B_ * T_ * CONVD) return;
  int c = (int)(idx % CONVD);
  long r = idx / CONVD;          // b*T_ + t
  int t = (int)(r % T_);
  float acc = cb[c];
  #pragma unroll
  for (int i = 0; i < 4; i++) {
    int ts = t - 3 + i;
    if (ts >= 0) acc += bf2f(xpre[(r + (ts - t)) * CONVD + c]) * cw[c * 4 + i];
  }
  out[idx] = f2bf(acc / (1.f + expf(-acc)));   // silu
}

// ---------- per-chunk inclusive cumsum of dt*A  (Acum[(b*NH+h)*NC+c][k]) ----------
__global__ __launch_bounds__(256) void cumsum_kernel(
    const float* __restrict__ dt, const float* __restrict__ A_log,
    float* __restrict__ Acum) {
  int bid = blockIdx.x;                 // (b*NH+h)*NCHUNK + c
  int c = bid % NCHUNK; int hh = bid / NCHUNK;
  int h = hh % NH; int b = hh / NH;
  int k = threadIdx.x;
  float a = -expf(A_log[h]);
  long t = (long)b * T_ + c * CK + k;
  float v = dt[t * NH + h] * a;
  __shared__ float buf[2][CK];
  int cur = 0;
  buf[0][k] = v; __syncthreads();
  for (int off = 1; off < CK; off <<= 1) {
    float tv = buf[cur][k];
    if (k >= off) tv += buf[cur][k - off];
    buf[1 - cur][k] = tv; cur ^= 1; __syncthreads();
  }
  Acum[(long)bid * CK + k] = buf[cur][k];
}

// ---------- per-chunk states: cs[(b*NC+c)*NH+h][p][n] ----------
__global__ __launch_bounds__(256) void chunk_states_kernel(
    const bf16t* __restrict__ xbc, const float* __restrict__ dt,
    const float* __restrict__ Acum, float* __restrict__ cs) {
  int bid = blockIdx.x;                 // (b*NCHUNK+c)*NH + h
  int h = bid % NH; int bc = bid / NH;
  int c = bc % NCHUNK; int b = bc / NCHUNK;
  int tid = threadIdx.x;
  int pg = tid >> 4, ng = tid & 15;     // p0 = pg*8, n0 = ng*4
  __shared__ float Xs[32][128];
  __shared__ float Bs[32][68];
  __shared__ float wk[32];
  int acb = ((b * NH + h) * NCHUNK + c) * CK;
  float Alast = Acum[acb + CK - 1];
  float acc[8][4] = {};
  for (int k0 = 0; k0 < CK; k0 += 32) {
    __syncthreads();
    if (tid < 32) {
      long t = (long)b * T_ + c * CK + k0 + tid;
      wk[tid] = expf(Alast - Acum[acb + k0 + tid]) * dt[t * NH + h];
    }
    for (int e = tid; e < 32 * 64; e += 256) {
      int kk = e >> 6, pp = (e & 63) * 2;
      long t = (long)b * T_ + c * CK + k0 + kk;
      ushort2 u = *(const ushort2*)&xbc[t * CONVD + h * HD + pp];
      Xs[kk][pp] = bf2f(u.x); Xs[kk][pp + 1] = bf2f(u.y);
    }
    for (int e = tid; e < 32 * 32; e += 256) {
      int kk = e >> 5, nn = (e & 31) * 2;
      long t = (long)b * T_ + c * CK + k0 + kk;
      ushort2 u = *(const ushort2*)&xbc[t * CONVD + DINNER + nn];
      Bs[kk][nn] = bf2f(u.x); Bs[kk][nn + 1] = bf2f(u.y);
    }
    __syncthreads();
    for (int kk = 0; kk < 32; kk++) {
      float w = wk[kk];
      float bv[4];
      #pragma unroll
      for (int j = 0; j < 4; j++) bv[j] = Bs[kk][ng * 4 + j];
      #pragma unroll
      for (int i = 0; i < 8; i++) {
        float xv = Xs[kk][pg * 8 + i] * w;
        #pragma unroll
        for (int j = 0; j < 4; j++) acc[i][j] += xv * bv[j];
      }
    }
  }
  float* out = cs + (long)bid * HD * NSTATE;
  #pragma unroll
  for (int i = 0; i < 8; i++) {
    float4 v4 = make_float4(acc[i][0], acc[i][1], acc[i][2], acc[i][3]);
    *(float4*)&out[(pg * 8 + i) * NSTATE + ng * 4] = v4;
  }
}

// ---------- sequential inter-chunk recurrence, IN PLACE: cs[c] <- state entering c ----------
__global__ __launch_bounds__(256) void state_pass_kernel(
    float* __restrict__ cs, const float* __restrict__ Acum) {
  int bh = blockIdx.x;                  // b*NH + h
  int b = bh / NH, h = bh % NH;
  int e0 = blockIdx.y * 1024 + threadIdx.x;
  for (int q = 0; q < 4; q++) {
    int e = e0 + q * 256;
    float s = 0.f;
    for (int c = 0; c < NCHUNK; c++) {
      long idx = ((long)(b * NCHUNK + c) * NH + h) * (HD * NSTATE) + e;
      float tmp = cs[idx];
      cs[idx] = s;
      float g = expf(Acum[((b * NH + h) * NCHUNK + c) * CK + CK - 1]);
      s = s * g + tmp;
    }
  }
}

// ---------- Y = tril(C B^T * decay) X*dt + C . state_in * exp(Acum) + Dskip*xs ----------
__global__ __launch_bounds__(256) void ssd_y_kernel(
    const bf16t* __restrict__ xbc, const float* __restrict__ dt,
    const float* __restrict__ Acum, const float* __restrict__ sin_,
    const float* __restrict__ Dskip, bf16t* __restrict__ Y) {
  int bid = blockIdx.x;                 // (b*NCHUNK+c)*NH + h
  int h = bid % NH; int bc = bid / NH;
  int c = bc % NCHUNK; int b = bc / NCHUNK;
  int kb = blockIdx.y;                  // k-tile (32 rows)
  int tid = threadIdx.x;
  int kr = tid >> 3, pg = tid & 7;      // row kr, cols pg*4 + 32u + {0..3}
  __shared__ float Cs[32][68];
  __shared__ float Bs[32][68];
  __shared__ float Xs[32][128];
  __shared__ float Ss[32][33];
  __shared__ float Ak[32], Asb[32];
  int acb = ((b * NH + h) * NCHUNK + c) * CK;
  if (tid < 32) Ak[tid] = Acum[acb + kb * 32 + tid];
  for (int e = tid; e < 32 * 32; e += 256) {
    int kk = e >> 5, nn = (e & 31) * 2;
    long t = (long)b * T_ + c * CK + kb * 32 + kk;
    ushort2 u = *(const ushort2*)&xbc[t * CONVD + DINNER + NSTATE + nn];
    Cs[kk][nn] = bf2f(u.x); Cs[kk][nn + 1] = bf2f(u.y);
  }
  float acc[4][4] = {};
  for (int sb = 0; sb <= kb; sb++) {
    __syncthreads();
    if (tid < 32) Asb[tid] = Acum[acb + sb * 32 + tid];
    for (int e = tid; e < 32 * 32; e += 256) {
      int ss = e >> 5, nn = (e & 31) * 2;
      long t = (long)b * T_ + c * CK + sb * 32 + ss;
      ushort2 u = *(const ushort2*)&xbc[t * CONVD + DINNER + nn];
      Bs[ss][nn] = bf2f(u.x); Bs[ss][nn + 1] = bf2f(u.y);
    }
    for (int e = tid; e < 32 * 64; e += 256) {
      int ss = e >> 6, pp = (e & 63) * 2;
      long t = (long)b * T_ + c * CK + sb * 32 + ss;
      ushort2 u = *(const ushort2*)&xbc[t * CONVD + h * HD + pp];
      float dtv = dt[t * NH + h];
      Xs[ss][pp] = bf2f(u.x) * dtv; Xs[ss][pp + 1] = bf2f(u.y) * dtv;
    }
    __syncthreads();
    {
      int kr2 = tid >> 3, sbase = tid & 7;
      #pragma unroll
      for (int q = 0; q < 4; q++) {
        int ss2 = sbase + 8 * q;
        float dp = 0.f;
        #pragma unroll 8
        for (int n = 0; n < 64; n++) dp += Cs[kr2][n] * Bs[ss2][n];
        float val = 0.f;
        if (sb < kb || ss2 <= kr2) val = dp * expf(Ak[kr2] - Asb[ss2]);
        Ss[kr2][ss2] = val;
      }
    }
    __syncthreads();
    for (int ss = 0; ss < 32; ss++) {
      float sv = Ss[kr][ss];
      #pragma unroll
      for (int u = 0; u < 4; u++) {
        float4 xv = *(const float4*)&Xs[ss][pg * 4 + 32 * u];
        acc[u][0] += sv * xv.x; acc[u][1] += sv * xv.y;
        acc[u][2] += sv * xv.z; acc[u][3] += sv * xv.w;
      }
    }
  }
  // epilogue: Y_off + D_skip * xs, write out (bf16)
  float ek = expf(Ak[kr]);
  float dsk = Dskip[h];
  const float* sinb = sin_ + (long)bid * HD * NSTATE;
  long t = (long)b * T_ + c * CK + kb * 32 + kr;
  const bf16t* xrow = xbc + t * CONVD + h * HD;
  bf16t* yrow = Y + t * DINNER + h * HD;
  #pragma unroll
  for (int u = 0; u < 4; u++) {
    int p0 = pg * 4 + 32 * u;
    float off[4];
    #pragma unroll
    for (int j = 0; j < 4; j++) {
      const float4* sp = (const float4*)&sinb[(p0 + j) * NSTATE];
      float o = 0.f;
      #pragma unroll
      for (int n4 = 0; n4 < 16; n4++) {
        float4 s4 = sp[n4];
        float4 c4 = *(const float4*)&Cs[kr][n4 * 4];
        o += c4.x * s4.x + c4.y * s4.y + c4.z * s4.z + c4.w * s4.w;
      }
      off[j] = o;
    }
    ushort4 xu = *(const ushort4*)&xrow[p0];
    ushort4 r;
    r.x = f2bf(acc[u][0] + ek * off[0] + dsk * bf2f(xu.x));
    r.y = f2bf(acc[u][1] + ek * off[1] + dsk * bf2f(xu.y));
    r.z = f2bf(acc[u][2] + ek * off[2] + dsk * bf2f(xu.z));
    r.w = f2bf(acc[u][3] + ek * off[3] + dsk * bf2f(xu.w));
    *(ushort4*)&yrow[p0] = r;
  }
}

// ---------- y *= silu(z); RMSNorm * ssd_norm_w (in place on Y, bf16) ----------
__global__ __launch_bounds__(256) void gate_rms_kernel(
    const bf16t* __restrict__ z, const float* __restrict__ nw,
    bf16t* __restrict__ Y) {
  long r = blockIdx.x;
  const bf16t* zrow = z + r * DINNER;
  bf16t* yrow = Y + r * DINNER;
  int tid = threadIdx.x;
  float v[8]; float sq = 0.f;
  #pragma unroll
  for (int i = 0; i < 4; i++) {
    int d = tid * 2 + 512 * i;
    ushort2 zu = *(const ushort2*)&zrow[d];
    ushort2 yu = *(const ushort2*)&yrow[d];
    float z0 = bf2f(zu.x), z1 = bf2f(zu.y);
    float y0 = bf2f(yu.x) * (z0 / (1.f + expf(-z0)));
    float y1 = bf2f(yu.y) * (z1 / (1.f + expf(-z1)));
    v[2 * i] = y0; v[2 * i + 1] = y1;
    sq += y0 * y0 + y1 * y1;
  }
  float2 r2 = block_reduce2(sq, 0.f);
  float rms = rsqrtf(r2.x * (1.f / DINNER) + EPSV);
  #pragma unroll
  for (int i = 0; i < 4; i++) {
    int d = tid * 2 + 512 * i;
    ushort2 o;
    o.x = f2bf(v[2 * i] * rms * nw[d]);
    o.y = f2bf(v[2 * i + 1] * rms * nw[d + 1]);
    *(ushort2*)&yrow[d] = o;
  }
}

// ---------- residual add (last L rows) + LayerNorm3 -> bf16 ----------
__global__ __launch_bounds__(256) void res_ln3_kernel(
    const float* __restrict__ mfull, const bf16t* __restrict__ x,
    const float* __restrict__ w3, const float* __restrict__ b3,
    bf16t* __restrict__ x2) {
  int rl = blockIdx.x;                  // b*L_ + tl
  int tl = rl % L_, b = rl / L_;
  long rt = (long)b * T_ + G_ + tl;
  const float* m = mfull + rt * DM;
  const bf16t* xr = x + rt * DM;
  float v[4]; float s = 0.f, sq = 0.f;
  #pragma unroll
  for (int i = 0; i < 4; i++) {
    int d = threadIdx.x + 256 * i;
    v[i] = m[d] + bf2f(xr[d]);
    s += v[i]; sq += v[i] * v[i];
  }
  float2 r2 = block_reduce2(s, sq);
  float mu = r2.x * (1.f / DM);
  float var = r2.y * (1.f / DM) - mu * mu;
  float rstd = rsqrtf(var + EPSV);
  bf16t* dst = x2 + (long)rl * DM;
  #pragma unroll
  for (int i = 0; i < 4; i++) {
    int d = threadIdx.x + 256 * i;
    dst[d] = f2bf((v[i] - mu) * rstd * w3[d] + b3[d]);
  }
}

extern "C" void kernel_launch(void* const* d_in, const int* in_sizes, int n_in,
                              void* d_out, int out_size, void* d_ws, size_t ws_size,
                              hipStream_t stream) {
  const float* localr = (const float*)d_in[0];
  const float* globalr= (const float*)d_in[1];
  const float* n1w = (const float*)d_in[2];
  const float* n1b = (const float*)d_in[3];
  const float* n2w = (const float*)d_in[4];
  const float* n2b = (const float*)d_in[5];
  const float* n3w = (const float*)d_in[6];
  const float* n3b = (const float*)d_in[7];
  const float* inpw= (const float*)d_in[8];
  const float* convw=(const float*)d_in[9];
  const float* convb=(const float*)d_in[10];
  const float* dtb = (const float*)d_in[11];
  const float* alog= (const float*)d_in[12];
  const float* dskp= (const float*)d_in[13];
  const float* ssdw= (const float*)d_in[14];
  const float* outw= (const float*)d_in[15];
  const float* f1w = (const float*)d_in[16];
  const float* f1b = (const float*)d_in[17];
  const float* f2w = (const float*)d_in[18];
  const float* f2b = (const float*)d_in[19];

  // ---- workspace layout (byte offsets); peak = 157,483,008 B (~150 MB) ----
  char* ws = (char*)d_ws;
  bf16t* x     = (bf16t*)(ws + 0);             // 9216*1024 bf16   = 18,874,368 B
  bf16t* z     = (bf16t*)(ws + 18874368);      // 9216*2048 bf16   = 37,748,736 B
  float* mfull = (float*)(ws + 18874368);      //   overlay: 9216*1024 f32 (after gate_rms)
  bf16t* xpre  = (bf16t*)(ws + 56623104);      // 9216*2176 bf16   = 40,108,032 B
  bf16t* Yb    = (bf16t*)(ws + 56623104);      //   overlay: 9216*2048 bf16 (after conv)
  float* dtraw = (float*)(ws + 96731136);      // 9216*16 f32      = 589,824 B
  float* dt    = (float*)(ws + 97320960);      // 9216*16 f32      = 589,824 B
  float* Acum  = (float*)(ws + 97910784);      // 64*9*256 f32     = 589,824 B
  bf16t* xbc   = (bf16t*)(ws + 98500608);      // 9216*2176 bf16   = 40,108,032 B
  bf16t* x2bf  = (bf16t*)(ws + 98500608);      //   overlay after ssd_y: 8192*1024 bf16
  bf16t* hbuf  = (bf16t*)(ws + 115277824);     //   overlay: 8192*512 bf16
  bf16t* outw_bf = (bf16t*)(ws + 123666432);   //   overlay: 1024*2048 bf16 = 4,194,304 B
  bf16t* f1w_bf  = (bf16t*)(ws + 127860736);   //   overlay: 512*1024 bf16  = 1,048,576 B
  bf16t* f2w_bf  = (bf16t*)(ws + 128909312);   //   overlay: 1024*512 bf16  = 1,048,576 B
  float* cs    = (float*)(ws + 138608640);     // 576*8192 f32     = 18,874,368 B
  bf16t* inpw_bf = (bf16t*)(ws + 138608640);   //   overlay BEFORE chunk_states: 4352*1024 bf16 = 8,912,896 B

  // in_proj weight -> bf16 (padded to 4352 rows), lives in cs region until chunk_states
  {
    long nreal = (long)DPROJ * DM, ntot = (long)NPROJ_PAD * DM;
    cvt_pad_kernel<<<(int)((ntot + 255) / 256), 256, 0, stream>>>(inpw, inpw_bf, nreal, ntot);
  }

  ln_concat_kernel<<<B_ * T_, 256, 0, stream>>>(localr, globalr, n1w, n1b, n2w, n2b, x);

  gemm_mfma<0><<<dim3(NPROJ_PAD / 128, (B_ * T_) / 128), 256, 0, stream>>>(
      x, inpw_bf, nullptr, nullptr, nullptr, nullptr, z, xpre, dtraw, B_ * T_, NPROJ_PAD, DM);

  dt_kernel<<<(B_ * T_ * NH) / 256, 256, 0, stream>>>(dtraw, dtb, dt);

  conv_kernel<<<(int)(((long)B_ * T_ * CONVD + 255) / 256), 256, 0, stream>>>(
      xpre, convw, convb, xbc);

  cumsum_kernel<<<B_ * NH * NCHUNK, 256, 0, stream>>>(dt, alog, Acum);

  chunk_states_kernel<<<B_ * NCHUNK * NH, 256, 0, stream>>>(xbc, dt, Acum, cs);

  state_pass_kernel<<<dim3(B_ * NH, 8), 256, 0, stream>>>(cs, Acum);

  ssd_y_kernel<<<dim3(B_ * NCHUNK * NH, 8), 256, 0, stream>>>(xbc, dt, Acum, cs, dskp, Yb);

  // late weights -> bf16 (xbc region is dead now)
  cvt_pad_kernel<<<(DM * DINNER + 255) / 256, 256, 0, stream>>>(outw, outw_bf, (long)DM * DINNER, (long)DM * DINNER);
  cvt_pad_kernel<<<((DM / 2) * DM + 255) / 256, 256, 0, stream>>>(f1w, f1w_bf, (long)(DM / 2) * DM, (long)(DM / 2) * DM);
  cvt_pad_kernel<<<(DM * (DM / 2) + 255) / 256, 256, 0, stream>>>(f2w, f2w_bf, (long)DM * (DM / 2), (long)DM * (DM / 2));

  gate_rms_kernel<<<B_ * T_, 256, 0, stream>>>(z, ssdw, Yb);

  gemm_mfma<1><<<dim3(DM / 128, (B_ * T_) / 128), 256, 0, stream>>>(
      Yb, outw_bf, nullptr, nullptr, mfull, nullptr, nullptr, nullptr, nullptr,
      B_ * T_, DM, DINNER);

  res_ln3_kernel<<<B_ * L_, 256, 0, stream>>>(mfull, x, n3w, n3b, x2bf);

  gemm_mfma<2><<<dim3((DM / 2) / 128, (B_ * L_) / 128), 256, 0, stream>>>(
      x2bf, f1w_bf, f1b, nullptr, nullptr, hbuf, nullptr, nullptr, nullptr,
      B_ * L_, DM / 2, DM);

  gemm_mfma<3><<<dim3(DM / 128, (B_ * L_) / 128), 256, 0, stream>>>(
      hbuf, f2w_bf, f2b, x2bf, (float*)d_out, nullptr, nullptr, nullptr, nullptr,
      B_ * L_, DM, DM / 2);
}

// Round 4
// 717.698 us; speedup vs baseline: 4.3094x; 2.1022x over previous
//
#include <hip/hip_runtime.h>
#include <math.h>

#define B_ 4
#define L_ 2048
#define G_ 256
#define T_ 2304          // G_ + L_
#define DM 1024
#define DINNER 2048
#define NH 16
#define HD 128
#define NSTATE 64
#define CONVD 2176       // DINNER + 2*NSTATE
#define DPROJ 4240       // 2*DINNER + 2*NSTATE + NH
#define NPROJ_PAD 4352   // DPROJ padded to 128
#define NCHUNK 9
#define CK 256
#define EPSV 1e-5f

typedef unsigned short bf16t;
using bf16x8 = __attribute__((ext_vector_type(8))) short;
using f32x4  = __attribute__((ext_vector_type(4))) float;

__device__ __forceinline__ float bf2f(bf16t u) {
  return __uint_as_float(((unsigned int)u) << 16);
}
__device__ __forceinline__ bf16t f2bf(float f) {
  unsigned int u = __float_as_uint(f);
  u += 0x7FFFu + ((u >> 16) & 1u);
  return (bf16t)(u >> 16);
}

__device__ __forceinline__ void g2lds16(const bf16t* g, short* l) {
  __builtin_amdgcn_global_load_lds(
      (const __attribute__((address_space(1))) unsigned int*)g,
      (__attribute__((address_space(3))) unsigned int*)l, 16, 0, 0);
}

// ---------- block-wide reduction of two values (blockDim == 256) ----------
__device__ __forceinline__ float2 block_reduce2(float a, float b) {
  __shared__ float sa[4], sb[4];
  #pragma unroll
  for (int off = 32; off > 0; off >>= 1) {
    a += __shfl_down(a, off, 64);
    b += __shfl_down(b, off, 64);
  }
  int lane = threadIdx.x & 63, wid = threadIdx.x >> 6;
  if (lane == 0) { sa[wid] = a; sb[wid] = b; }
  __syncthreads();
  return make_float2(sa[0] + sa[1] + sa[2] + sa[3], sb[0] + sb[1] + sb[2] + sb[3]);
}

// ---------- fp32 -> bf16 weight convert with zero row-padding ----------
__global__ __launch_bounds__(256) void cvt_pad_kernel(
    const float* __restrict__ w, bf16t* __restrict__ o, long nreal, long ntot) {
  long i = (long)blockIdx.x * 256 + threadIdx.x;
  if (i < ntot) o[i] = (i < nreal) ? f2bf(w[i]) : (bf16t)0;
}

// ---------- LayerNorm(local) / LayerNorm(global) + concat -> x (bf16) ----------
__global__ __launch_bounds__(256) void ln_concat_kernel(
    const float* __restrict__ localr, const float* __restrict__ globalr,
    const float* __restrict__ w1, const float* __restrict__ b1,
    const float* __restrict__ w2, const float* __restrict__ b2,
    bf16t* __restrict__ x) {
  int r = blockIdx.x;          // b*T_ + t
  int t = r % T_, b = r / T_;
  const float *src, *w, *bb;
  if (t < G_) { src = globalr + ((long)b * G_ + t) * DM;        w = w2; bb = b2; }
  else        { src = localr  + ((long)b * L_ + (t - G_)) * DM; w = w1; bb = b1; }
  float v[4]; float s = 0.f, sq = 0.f;
  #pragma unroll
  for (int i = 0; i < 4; i++) {
    v[i] = src[threadIdx.x + 256 * i];
    s += v[i]; sq += v[i] * v[i];
  }
  float2 r2 = block_reduce2(s, sq);
  float mu = r2.x * (1.f / DM);
  float var = r2.y * (1.f / DM) - mu * mu;
  float rstd = rsqrtf(var + EPSV);
  bf16t* dst = x + (long)r * DM;
  #pragma unroll
  for (int i = 0; i < 4; i++) {
    int d = threadIdx.x + 256 * i;
    dst[d] = f2bf((v[i] - mu) * rstd * w[d] + bb[d]);
  }
}

// ---------- MFMA bf16 GEMM: D[M,N] = A[M,K] @ W[N,K]^T, fused epilogues ----------
template<int EPI>
__global__ __launch_bounds__(256) void gemm_mfma(
    const bf16t* __restrict__ A, const bf16t* __restrict__ W,
    const float* __restrict__ bias, const bf16t* __restrict__ res,
    float* __restrict__ Cf, bf16t* __restrict__ Cb,
    bf16t* __restrict__ z, bf16t* __restrict__ xpre, float* __restrict__ dtr,
    int M, int N, int K) {
  __shared__ __align__(16) short As[128 * 32];
  __shared__ __align__(16) short Ws[128 * 32];
  int tid = threadIdx.x;
  int lane = tid & 63, w = tid >> 6;
  int wr = w >> 1, wc = w & 1;
  int bm = blockIdx.y * 128, bn = blockIdx.x * 128;

  int r1 = tid >> 2,         s1 = (tid & 3) * 8;
  int r2 = (tid + 256) >> 2, s2 = ((tid + 256) & 3) * 8;
  const bf16t* gA1 = A + (long)(bm + r1) * K + s1;
  const bf16t* gA2 = A + (long)(bm + r2) * K + s2;
  const bf16t* gW1 = W + (long)(bn + r1) * K + s1;
  const bf16t* gW2 = W + (long)(bn + r2) * K + s2;
  short* lA1 = As + tid * 8;
  short* lA2 = As + (tid + 256) * 8;
  short* lW1 = Ws + tid * 8;
  short* lW2 = Ws + (tid + 256) * 8;

  int arow = wr * 64 + (lane & 15);
  int brow = wc * 64 + (lane & 15);
  int koff = (lane >> 4) * 8;

  f32x4 acc[4][4] = {};
  for (int k0 = 0; k0 < K; k0 += 32) {
    g2lds16(gA1 + k0, lA1);
    g2lds16(gA2 + k0, lA2);
    g2lds16(gW1 + k0, lW1);
    g2lds16(gW2 + k0, lW2);
    __syncthreads();
    bf16x8 af[4], bf[4];
    #pragma unroll
    for (int mi = 0; mi < 4; mi++) af[mi] = *(bf16x8*)&As[(arow + mi * 16) * 32 + koff];
    #pragma unroll
    for (int ni = 0; ni < 4; ni++) bf[ni] = *(bf16x8*)&Ws[(brow + ni * 16) * 32 + koff];
    #pragma unroll
    for (int mi = 0; mi < 4; mi++)
      #pragma unroll
      for (int ni = 0; ni < 4; ni++)
        acc[mi][ni] = __builtin_amdgcn_mfma_f32_16x16x32_bf16(af[mi], bf[ni], acc[mi][ni], 0, 0, 0);
    __syncthreads();
  }

  int rb = wr * 64 + (lane >> 4) * 4;
  int cb = wc * 64 + (lane & 15);
  #pragma unroll
  for (int mi = 0; mi < 4; mi++) {
    #pragma unroll
    for (int ni = 0; ni < 4; ni++) {
      #pragma unroll
      for (int r = 0; r < 4; r++) {
        int row = bm + rb + mi * 16 + r;
        int col = bn + cb + ni * 16;
        float v = acc[mi][ni][r];
        if (EPI == 0) {
          if (col < DINNER)            z[(long)row * DINNER + col] = f2bf(v);
          else if (col < DINNER+CONVD) xpre[(long)row * CONVD + (col - DINNER)] = f2bf(v);
          else if (col < DPROJ)        dtr[(long)row * NH + (col - DINNER - CONVD)] = v;
        } else if (EPI == 1) {
          Cf[(long)row * N + col] = v;
        } else if (EPI == 2) {
          v += bias[col];
          v = 0.5f * v * (1.f + erff(v * 0.70710678118f));
          Cb[(long)row * N + col] = f2bf(v);
        } else {
          v += bias[col] + bf2f(res[(long)row * N + col]);
          Cf[(long)row * N + col] = v;
        }
      }
    }
  }
}

// ---------- dt = softplus(dtraw + dt_bias) ----------
__global__ __launch_bounds__(256) void dt_kernel(
    const float* __restrict__ dtr, const float* __restrict__ dt_bias,
    float* __restrict__ dt) {
  int idx = blockIdx.x * 256 + threadIdx.x;   // < B_*T_*NH
  int h = idx & 15;
  float v = dtr[idx] + dt_bias[h];
  dt[idx] = (v > 20.f) ? v : log1pf(expf(v));
}

// ---------- causal depthwise conv(4) + bias + silu (bf16 in/out) ----------
__global__ __launch_bounds__(256) void conv_kernel(
    const bf16t* __restrict__ xpre, const float* __restrict__ cw,
    const float* __restrict__ cb, bf16t* __restrict__ out) {
  long idx = (long)blockIdx.x * 256 + threadIdx.x;
  if (idx >= (long)B_ * T_ * CONVD) return;
  int c = (int)(idx % CONVD);
  long r = idx / CONVD;          // b*T_ + t
  int t = (int)(r % T_);
  float acc = cb[c];
  #pragma unroll
  for (int i = 0; i < 4; i++) {
    int ts = t - 3 + i;
    if (ts >= 0) acc += bf2f(xpre[(r + (ts - t)) * CONVD + c]) * cw[c * 4 + i];
  }
  out[idx] = f2bf(acc / (1.f + expf(-acc)));   // silu
}

// ---------- per-chunk inclusive cumsum of dt*A  (Acum[(b*NH+h)*NC+c][k]) ----------
__global__ __launch_bounds__(256) void cumsum_kernel(
    const float* __restrict__ dt, const float* __restrict__ A_log,
    float* __restrict__ Acum) {
  int bid = blockIdx.x;                 // (b*NH+h)*NCHUNK + c
  int c = bid % NCHUNK; int hh = bid / NCHUNK;
  int h = hh % NH; int b = hh / NH;
  int k = threadIdx.x;
  float a = -expf(A_log[h]);
  long t = (long)b * T_ + c * CK + k;
  float v = dt[t * NH + h] * a;
  __shared__ float buf[2][CK];
  int cur = 0;
  buf[0][k] = v; __syncthreads();
  for (int off = 1; off < CK; off <<= 1) {
    float tv = buf[cur][k];
    if (k >= off) tv += buf[cur][k - off];
    buf[1 - cur][k] = tv; cur ^= 1; __syncthreads();
  }
  Acum[(long)bid * CK + k] = buf[cur][k];
}

// ---------- per-chunk states via MFMA: cs[bid][p][n], bid=(b*NC+c)*NH+h ----------
// states[p][n] = sum_s X[s][p]*w[s] * B[s][n],  w[s]=exp(Alast-Acum[s])*dt[s]
__global__ __launch_bounds__(256) void chunk_states_kernel(
    const bf16t* __restrict__ xbc, const float* __restrict__ dt,
    const float* __restrict__ Acum, float* __restrict__ cs) {
  int bid = blockIdx.x;
  int h = bid % NH; int bc = bid / NH;
  int c = bc % NCHUNK; int b = bc / NCHUNK;
  int tid = threadIdx.x;
  int lane = tid & 63, w = tid >> 6;
  long tch = (long)b * T_ + c * CK;
  int acb = ((b * NH + h) * NCHUNK + c) * CK;
  float Alast = Acum[acb + CK - 1];

  __shared__ bf16t Xt[128][72];   // Xt[p][s]  (x * w)
  __shared__ bf16t Bt[64][72];    // Bt[n][s]
  __shared__ float wk[64];

  f32x4 acc[8] = {};
  for (int kb = 0; kb < 4; kb++) {
    int s0 = kb * 64;
    __syncthreads();
    if (tid < 64)
      wk[tid] = expf(Alast - Acum[acb + s0 + tid]) * dt[(tch + s0 + tid) * NH + h];
    __syncthreads();
    // Xt: transposed staging, consecutive lanes -> consecutive s (conflict-free LDS)
    for (int e = tid; e < 64 * 64; e += 256) {
      int s = e & 63, ppi = e >> 6;
      ushort2 u = *(const ushort2*)&xbc[(tch + s0 + s) * CONVD + h * HD + ppi * 2];
      float wv = wk[s];
      Xt[ppi * 2][s]     = f2bf(bf2f(u.x) * wv);
      Xt[ppi * 2 + 1][s] = f2bf(bf2f(u.y) * wv);
    }
    for (int e = tid; e < 64 * 64; e += 256) {
      int s = e & 63, nn = e >> 6;
      Bt[nn][s] = xbc[(tch + s0 + s) * CONVD + DINNER + nn];
    }
    __syncthreads();
    #pragma unroll
    for (int ks = 0; ks < 2; ks++) {
      int koff = (lane >> 4) * 8 + ks * 32;
      bf16x8 bfr = *(bf16x8*)&Bt[w * 16 + (lane & 15)][koff];
      #pragma unroll
      for (int mi = 0; mi < 8; mi++) {
        bf16x8 af = *(bf16x8*)&Xt[mi * 16 + (lane & 15)][koff];
        acc[mi] = __builtin_amdgcn_mfma_f32_16x16x32_bf16(af, bfr, acc[mi], 0, 0, 0);
      }
    }
  }
  float* out = cs + (long)bid * HD * NSTATE;
  int n = w * 16 + (lane & 15);
  #pragma unroll
  for (int mi = 0; mi < 8; mi++) {
    #pragma unroll
    for (int r = 0; r < 4; r++) {
      int p = mi * 16 + (lane >> 4) * 4 + r;
      out[p * NSTATE + n] = acc[mi][r];
    }
  }
}

// ---------- sequential inter-chunk recurrence, IN PLACE: cs[c] <- state entering c ----------
__global__ __launch_bounds__(256) void state_pass_kernel(
    float* __restrict__ cs, const float* __restrict__ Acum) {
  int bh = blockIdx.x;                  // b*NH + h
  int b = bh / NH, h = bh % NH;
  int e0 = blockIdx.y * 1024 + threadIdx.x;
  for (int q = 0; q < 4; q++) {
    int e = e0 + q * 256;
    float s = 0.f;
    for (int c = 0; c < NCHUNK; c++) {
      long idx = ((long)(b * NCHUNK + c) * NH + h) * (HD * NSTATE) + e;
      float tmp = cs[idx];
      cs[idx] = s;
      float g = expf(Acum[((b * NH + h) * NCHUNK + c) * CK + CK - 1]);
      s = s * g + tmp;
    }
  }
}

// ---------- SSD Y via MFMA ----------
// grid (576, 2): bid=(b*NC+c)*NH+h, rt = 128-row tile. 4 waves.
__global__ __launch_bounds__(256) void ssd_y_kernel(
    const bf16t* __restrict__ xbc, const float* __restrict__ dt,
    const float* __restrict__ Acum, const float* __restrict__ sin_,
    const float* __restrict__ Dskip, bf16t* __restrict__ Y) {
  int bid = blockIdx.x;
  int h = bid % NH; int bc = bid / NH;
  int c = bc % NCHUNK; int b = bc / NCHUNK;
  int rt = blockIdx.y;
  int tid = threadIdx.x;
  int lane = tid & 63, w = tid >> 6;
  int wr = w >> 1, wc = w & 1;
  long tch = (long)b * T_ + c * CK;
  long tbase = tch + rt * 128;
  int acb = ((b * NH + h) * NCHUNK + c) * CK;

  __shared__ bf16t Cs[128][72];   // C rows (row-major)
  __shared__ bf16t Bs[64][72];    // B rows for current s-block
  __shared__ bf16t Xt[128][72];   // Xt[p][s] = X[s][p]*dt[s]
  __shared__ bf16t Sm[128][72];   // masked/decayed S (bf16, row-major)
  __shared__ float Akl[128];
  __shared__ float Asl[64];
  __shared__ float dts[64];

  // stage C tile + Acum rows
  for (int e = tid; e < 128 * 8; e += 256) {
    int row = e >> 3, seg = (e & 7) * 8;
    *(bf16x8*)&Cs[row][seg] =
        *(const bf16x8*)&xbc[(tbase + row) * CONVD + DINNER + NSTATE + seg];
  }
  if (tid < 128) Akl[tid] = Acum[acb + rt * 128 + tid];

  f32x4 acc[4][4] = {};
  int nsb = 2 * (rt + 1);
  for (int sb = 0; sb < nsb; sb++) {
    int s0 = sb * 64;
    __syncthreads();
    if (tid < 64) {
      Asl[tid] = Acum[acb + s0 + tid];
      dts[tid] = dt[(tch + s0 + tid) * NH + h];
    }
    __syncthreads();
    for (int e = tid; e < 64 * 8; e += 256) {
      int row = e >> 3, seg = (e & 7) * 8;
      *(bf16x8*)&Bs[row][seg] =
          *(const bf16x8*)&xbc[(tch + s0 + row) * CONVD + DINNER + seg];
    }
    for (int e = tid; e < 64 * 64; e += 256) {
      int s = e & 63, ppi = e >> 6;
      ushort2 u = *(const ushort2*)&xbc[(tch + s0 + s) * CONVD + h * HD + ppi * 2];
      float dtv = dts[s];
      Xt[ppi * 2][s]     = f2bf(bf2f(u.x) * dtv);
      Xt[ppi * 2 + 1][s] = f2bf(bf2f(u.y) * dtv);
    }
    __syncthreads();
    // S phase: wave w -> rows w*32..w*32+31, all 64 s-cols
    {
      f32x4 sacc[2][4] = {};
      int rw0 = w * 32;
      #pragma unroll
      for (int ks = 0; ks < 2; ks++) {
        int koff = (lane >> 4) * 8 + ks * 32;
        bf16x8 a0 = *(bf16x8*)&Cs[rw0 + (lane & 15)][koff];
        bf16x8 a1 = *(bf16x8*)&Cs[rw0 + 16 + (lane & 15)][koff];
        #pragma unroll
        for (int ni = 0; ni < 4; ni++) {
          bf16x8 bfr = *(bf16x8*)&Bs[ni * 16 + (lane & 15)][koff];
          sacc[0][ni] = __builtin_amdgcn_mfma_f32_16x16x32_bf16(a0, bfr, sacc[0][ni], 0, 0, 0);
          sacc[1][ni] = __builtin_amdgcn_mfma_f32_16x16x32_bf16(a1, bfr, sacc[1][ni], 0, 0, 0);
        }
      }
      #pragma unroll
      for (int mi = 0; mi < 2; mi++) {
        #pragma unroll
        for (int ni = 0; ni < 4; ni++) {
          #pragma unroll
          for (int r = 0; r < 4; r++) {
            int row = rw0 + mi * 16 + (lane >> 4) * 4 + r;
            int scol = ni * 16 + (lane & 15);
            int kglob = rt * 128 + row;
            int sglob = s0 + scol;
            float val = 0.f;
            if (sglob <= kglob) val = sacc[mi][ni][r] * expf(Akl[row] - Asl[scol]);
            Sm[row][scol] = f2bf(val);
          }
        }
      }
    }
    __syncthreads();
    // Y phase: classic 128x128, wave quadrant (wr,wc)
    #pragma unroll
    for (int ks = 0; ks < 2; ks++) {
      int koff = (lane >> 4) * 8 + ks * 32;
      bf16x8 af[4], bfr[4];
      #pragma unroll
      for (int mi = 0; mi < 4; mi++) af[mi] = *(bf16x8*)&Sm[wr * 64 + mi * 16 + (lane & 15)][koff];
      #pragma unroll
      for (int ni = 0; ni < 4; ni++) bfr[ni] = *(bf16x8*)&Xt[wc * 64 + ni * 16 + (lane & 15)][koff];
      #pragma unroll
      for (int mi = 0; mi < 4; mi++)
        #pragma unroll
        for (int ni = 0; ni < 4; ni++)
          acc[mi][ni] = __builtin_amdgcn_mfma_f32_16x16x32_bf16(af[mi], bfr[ni], acc[mi][ni], 0, 0, 0);
    }
  }

  // Y_off = ek[row] * (C . state_in^T); state read f32 from sin_, cvt in-register
  float ekr[16];
  #pragma unroll
  for (int mi = 0; mi < 4; mi++)
    #pragma unroll
    for (int r = 0; r < 4; r++)
      ekr[mi * 4 + r] = expf(Akl[wr * 64 + mi * 16 + (lane >> 4) * 4 + r]);

  const float* sinb = sin_ + (long)bid * HD * NSTATE;
  #pragma unroll
  for (int ni = 0; ni < 4; ni++) {
    f32x4 offacc[4] = {};
    int p = wc * 64 + ni * 16 + (lane & 15);
    #pragma unroll
    for (int ks = 0; ks < 2; ks++) {
      int koff = (lane >> 4) * 8 + ks * 32;
      const float* srow = sinb + p * NSTATE + koff;
      float4 sa = *(const float4*)srow;
      float4 sbv = *(const float4*)(srow + 4);
      bf16x8 bfr;
      bfr[0] = (short)f2bf(sa.x);  bfr[1] = (short)f2bf(sa.y);
      bfr[2] = (short)f2bf(sa.z);  bfr[3] = (short)f2bf(sa.w);
      bfr[4] = (short)f2bf(sbv.x); bfr[5] = (short)f2bf(sbv.y);
      bfr[6] = (short)f2bf(sbv.z); bfr[7] = (short)f2bf(sbv.w);
      #pragma unroll
      for (int mi = 0; mi < 4; mi++) {
        bf16x8 af = *(bf16x8*)&Cs[wr * 64 + mi * 16 + (lane & 15)][koff];
        offacc[mi] = __builtin_amdgcn_mfma_f32_16x16x32_bf16(af, bfr, offacc[mi], 0, 0, 0);
      }
    }
    #pragma unroll
    for (int mi = 0; mi < 4; mi++)
      #pragma unroll
      for (int r = 0; r < 4; r++)
        acc[mi][ni][r] += ekr[mi * 4 + r] * offacc[mi][r];
  }

  // epilogue: + Dskip * xs, write bf16
  float dsk = Dskip[h];
  #pragma unroll
  for (int mi = 0; mi < 4; mi++) {
    #pragma unroll
    for (int r = 0; r < 4; r++) {
      int row = wr * 64 + mi * 16 + (lane >> 4) * 4 + r;
      long t = tbase + row;
      #pragma unroll
      for (int ni = 0; ni < 4; ni++) {
        int p = wc * 64 + ni * 16 + (lane & 15);
        float xsv = bf2f(xbc[t * CONVD + h * HD + p]);
        Y[t * DINNER + h * HD + p] = f2bf(acc[mi][ni][r] + dsk * xsv);
      }
    }
  }
}

// ---------- y *= silu(z); RMSNorm * ssd_norm_w (in place on Y, bf16) ----------
__global__ __launch_bounds__(256) void gate_rms_kernel(
    const bf16t* __restrict__ z, const float* __restrict__ nw,
    bf16t* __restrict__ Y) {
  long r = blockIdx.x;
  const bf16t* zrow = z + r * DINNER;
  bf16t* yrow = Y + r * DINNER;
  int tid = threadIdx.x;
  float v[8]; float sq = 0.f;
  #pragma unroll
  for (int i = 0; i < 4; i++) {
    int d = tid * 2 + 512 * i;
    ushort2 zu = *(const ushort2*)&zrow[d];
    ushort2 yu = *(const ushort2*)&yrow[d];
    float z0 = bf2f(zu.x), z1 = bf2f(zu.y);
    float y0 = bf2f(yu.x) * (z0 / (1.f + expf(-z0)));
    float y1 = bf2f(yu.y) * (z1 / (1.f + expf(-z1)));
    v[2 * i] = y0; v[2 * i + 1] = y1;
    sq += y0 * y0 + y1 * y1;
  }
  float2 r2 = block_reduce2(sq, 0.f);
  float rms = rsqrtf(r2.x * (1.f / DINNER) + EPSV);
  #pragma unroll
  for (int i = 0; i < 4; i++) {
    int d = tid * 2 + 512 * i;
    ushort2 o;
    o.x = f2bf(v[2 * i] * rms * nw[d]);
    o.y = f2bf(v[2 * i + 1] * rms * nw[d + 1]);
    *(ushort2*)&yrow[d] = o;
  }
}

// ---------- residual add (last L rows) + LayerNorm3 -> bf16 ----------
__global__ __launch_bounds__(256) void res_ln3_kernel(
    const float* __restrict__ mfull, const bf16t* __restrict__ x,
    const float* __restrict__ w3, const float* __restrict__ b3,
    bf16t* __restrict__ x2) {
  int rl = blockIdx.x;                  // b*L_ + tl
  int tl = rl % L_, b = rl / L_;
  long rt = (long)b * T_ + G_ + tl;
  const float* m = mfull + rt * DM;
  const bf16t* xr = x + rt * DM;
  float v[4]; float s = 0.f, sq = 0.f;
  #pragma unroll
  for (int i = 0; i < 4; i++) {
    int d = threadIdx.x + 256 * i;
    v[i] = m[d] + bf2f(xr[d]);
    s += v[i]; sq += v[i] * v[i];
  }
  float2 r2 = block_reduce2(s, sq);
  float mu = r2.x * (1.f / DM);
  float var = r2.y * (1.f / DM) - mu * mu;
  float rstd = rsqrtf(var + EPSV);
  bf16t* dst = x2 + (long)rl * DM;
  #pragma unroll
  for (int i = 0; i < 4; i++) {
    int d = threadIdx.x + 256 * i;
    dst[d] = f2bf((v[i] - mu) * rstd * w3[d] + b3[d]);
  }
}

extern "C" void kernel_launch(void* const* d_in, const int* in_sizes, int n_in,
                              void* d_out, int out_size, void* d_ws, size_t ws_size,
                              hipStream_t stream) {
  const float* localr = (const float*)d_in[0];
  const float* globalr= (const float*)d_in[1];
  const float* n1w = (const float*)d_in[2];
  const float* n1b = (const float*)d_in[3];
  const float* n2w = (const float*)d_in[4];
  const float* n2b = (const float*)d_in[5];
  const float* n3w = (const float*)d_in[6];
  const float* n3b = (const float*)d_in[7];
  const float* inpw= (const float*)d_in[8];
  const float* convw=(const float*)d_in[9];
  const float* convb=(const float*)d_in[10];
  const float* dtb = (const float*)d_in[11];
  const float* alog= (const float*)d_in[12];
  const float* dskp= (const float*)d_in[13];
  const float* ssdw= (const float*)d_in[14];
  const float* outw= (const float*)d_in[15];
  const float* f1w = (const float*)d_in[16];
  const float* f1b = (const float*)d_in[17];
  const float* f2w = (const float*)d_in[18];
  const float* f2b = (const float*)d_in[19];

  // ---- workspace layout (byte offsets); peak = 157,483,008 B (~150 MB) ----
  char* ws = (char*)d_ws;
  bf16t* x     = (bf16t*)(ws + 0);             // 9216*1024 bf16   = 18,874,368 B
  bf16t* z     = (bf16t*)(ws + 18874368);      // 9216*2048 bf16   = 37,748,736 B
  float* mfull = (float*)(ws + 18874368);      //   overlay: 9216*1024 f32 (after gate_rms)
  bf16t* xpre  = (bf16t*)(ws + 56623104);      // 9216*2176 bf16   = 40,108,032 B
  bf16t* Yb    = (bf16t*)(ws + 56623104);      //   overlay: 9216*2048 bf16 (after conv)
  float* dtraw = (float*)(ws + 96731136);      // 9216*16 f32      = 589,824 B
  float* dt    = (float*)(ws + 97320960);      // 9216*16 f32      = 589,824 B
  float* Acum  = (float*)(ws + 97910784);      // 64*9*256 f32     = 589,824 B
  bf16t* xbc   = (bf16t*)(ws + 98500608);      // 9216*2176 bf16   = 40,108,032 B
  bf16t* x2bf  = (bf16t*)(ws + 98500608);      //   overlay after ssd_y: 8192*1024 bf16
  bf16t* hbuf  = (bf16t*)(ws + 115277824);     //   overlay: 8192*512 bf16
  bf16t* outw_bf = (bf16t*)(ws + 123666432);   //   overlay: 1024*2048 bf16 = 4,194,304 B
  bf16t* f1w_bf  = (bf16t*)(ws + 127860736);   //   overlay: 512*1024 bf16  = 1,048,576 B
  bf16t* f2w_bf  = (bf16t*)(ws + 128909312);   //   overlay: 1024*512 bf16  = 1,048,576 B
  float* cs    = (float*)(ws + 138608640);     // 576*8192 f32     = 18,874,368 B
  bf16t* inpw_bf = (bf16t*)(ws + 138608640);   //   overlay BEFORE chunk_states: 4352*1024 bf16

  {
    long nreal = (long)DPROJ * DM, ntot = (long)NPROJ_PAD * DM;
    cvt_pad_kernel<<<(int)((ntot + 255) / 256), 256, 0, stream>>>(inpw, inpw_bf, nreal, ntot);
  }

  ln_concat_kernel<<<B_ * T_, 256, 0, stream>>>(localr, globalr, n1w, n1b, n2w, n2b, x);

  gemm_mfma<0><<<dim3(NPROJ_PAD / 128, (B_ * T_) / 128), 256, 0, stream>>>(
      x, inpw_bf, nullptr, nullptr, nullptr, nullptr, z, xpre, dtraw, B_ * T_, NPROJ_PAD, DM);

  dt_kernel<<<(B_ * T_ * NH) / 256, 256, 0, stream>>>(dtraw, dtb, dt);

  conv_kernel<<<(int)(((long)B_ * T_ * CONVD + 255) / 256), 256, 0, stream>>>(
      xpre, convw, convb, xbc);

  cumsum_kernel<<<B_ * NH * NCHUNK, 256, 0, stream>>>(dt, alog, Acum);

  chunk_states_kernel<<<B_ * NCHUNK * NH, 256, 0, stream>>>(xbc, dt, Acum, cs);

  state_pass_kernel<<<dim3(B_ * NH, 8), 256, 0, stream>>>(cs, Acum);

  ssd_y_kernel<<<dim3(B_ * NCHUNK * NH, 2), 256, 0, stream>>>(xbc, dt, Acum, cs, dskp, Yb);

  cvt_pad_kernel<<<(DM * DINNER + 255) / 256, 256, 0, stream>>>(outw, outw_bf, (long)DM * DINNER, (long)DM * DINNER);
  cvt_pad_kernel<<<((DM / 2) * DM + 255) / 256, 256, 0, stream>>>(f1w, f1w_bf, (long)(DM / 2) * DM, (long)(DM / 2) * DM);
  cvt_pad_kernel<<<(DM * (DM / 2) + 255) / 256, 256, 0, stream>>>(f2w, f2w_bf, (long)DM * (DM / 2), (long)DM * (DM / 2));

  gate_rms_kernel<<<B_ * T_, 256, 0, stream>>>(z, ssdw, Yb);

  gemm_mfma<1><<<dim3(DM / 128, (B_ * T_) / 128), 256, 0, stream>>>(
      Yb, outw_bf, nullptr, nullptr, mfull, nullptr, nullptr, nullptr, nullptr,
      B_ * T_, DM, DINNER);

  res_ln3_kernel<<<B_ * L_, 256, 0, stream>>>(mfull, x, n3w, n3b, x2bf);

  gemm_mfma<2><<<dim3((DM / 2) / 128, (B_ * L_) / 128), 256, 0, stream>>>(
      x2bf, f1w_bf, f1b, nullptr, nullptr, hbuf, nullptr, nullptr, nullptr,
      B_ * L_, DM / 2, DM);

  gemm_mfma<3><<<dim3(DM / 128, (B_ * L_) / 128), 256, 0, stream>>>(
      hbuf, f2w_bf, f2b, x2bf, (float*)d_out, nullptr, nullptr, nullptr, nullptr,
      B_ * L_, DM, DM / 2);
}

// Round 6
// 698.516 us; speedup vs baseline: 4.4277x; 1.0275x over previous
//
#include <hip/hip_runtime.h>
#include <math.h>

#define B_ 4
#define L_ 2048
#define G_ 256
#define T_ 2304          // G_ + L_
#define DM 1024
#define DINNER 2048
#define NH 16
#define HD 128
#define NSTATE 64
#define CONVD 2176       // DINNER + 2*NSTATE
#define DPROJ 4240       // 2*DINNER + 2*NSTATE + NH
#define NPROJ_PAD 4352   // DPROJ padded to 128
#define NCHUNK 9
#define CK 256
#define EPSV 1e-5f

typedef unsigned short bf16t;
using bf16x8 = __attribute__((ext_vector_type(8))) short;
using f32x4  = __attribute__((ext_vector_type(4))) float;

__device__ __forceinline__ float bf2f(bf16t u) {
  return __uint_as_float(((unsigned int)u) << 16);
}
__device__ __forceinline__ bf16t f2bf(float f) {
  unsigned int u = __float_as_uint(f);
  u += 0x7FFFu + ((u >> 16) & 1u);
  return (bf16t)(u >> 16);
}

__device__ __forceinline__ void g2lds16(const bf16t* g, short* l) {
  __builtin_amdgcn_global_load_lds(
      (const __attribute__((address_space(1))) unsigned int*)g,
      (__attribute__((address_space(3))) unsigned int*)l, 16, 0, 0);
}

// ---------- block-wide reduction of two values (blockDim == 256) ----------
__device__ __forceinline__ float2 block_reduce2(float a, float b) {
  __shared__ float sa[4], sb[4];
  #pragma unroll
  for (int off = 32; off > 0; off >>= 1) {
    a += __shfl_down(a, off, 64);
    b += __shfl_down(b, off, 64);
  }
  int lane = threadIdx.x & 63, wid = threadIdx.x >> 6;
  if (lane == 0) { sa[wid] = a; sb[wid] = b; }
  __syncthreads();
  return make_float2(sa[0] + sa[1] + sa[2] + sa[3], sb[0] + sb[1] + sb[2] + sb[3]);
}

// ---------- fp32 -> bf16 weight convert: in_proj (padded) ----------
__global__ __launch_bounds__(256) void cvt_inproj_kernel(
    const float* __restrict__ w, bf16t* __restrict__ o) {
  long i = (long)blockIdx.x * 256 + threadIdx.x;
  long nreal = (long)DPROJ * DM, ntot = (long)NPROJ_PAD * DM;
  if (i < ntot) o[i] = (i < nreal) ? f2bf(w[i]) : (bf16t)0;
}

// ---------- fp32 -> bf16 late weights (out_proj + ffn1 + ffn2, one launch) ----------
__global__ __launch_bounds__(256) void cvt_late_kernel(
    const float* __restrict__ outw, const float* __restrict__ f1w,
    const float* __restrict__ f2w, bf16t* __restrict__ o_out,
    bf16t* __restrict__ o_f1, bf16t* __restrict__ o_f2) {
  long i = (long)blockIdx.x * 256 + threadIdx.x;
  const long n1 = (long)DM * DINNER;          // 2097152
  const long n2 = (long)(DM / 2) * DM;        // 524288
  if (i < n1) { o_out[i] = f2bf(outw[i]); return; }
  i -= n1;
  if (i < n2) { o_f1[i] = f2bf(f1w[i]); return; }
  i -= n2;
  if (i < n2) o_f2[i] = f2bf(f2w[i]);
}

// ---------- LayerNorm(local) / LayerNorm(global) + concat -> x (bf16) ----------
__global__ __launch_bounds__(256) void ln_concat_kernel(
    const float* __restrict__ localr, const float* __restrict__ globalr,
    const float* __restrict__ w1, const float* __restrict__ b1,
    const float* __restrict__ w2, const float* __restrict__ b2,
    bf16t* __restrict__ x) {
  int r = blockIdx.x;          // b*T_ + t
  int t = r % T_, b = r / T_;
  const float *src, *w, *bb;
  if (t < G_) { src = globalr + ((long)b * G_ + t) * DM;        w = w2; bb = b2; }
  else        { src = localr  + ((long)b * L_ + (t - G_)) * DM; w = w1; bb = b1; }
  float v[4]; float s = 0.f, sq = 0.f;
  #pragma unroll
  for (int i = 0; i < 4; i++) {
    v[i] = src[threadIdx.x + 256 * i];
    s += v[i]; sq += v[i] * v[i];
  }
  float2 r2 = block_reduce2(s, sq);
  float mu = r2.x * (1.f / DM);
  float var = r2.y * (1.f / DM) - mu * mu;
  float rstd = rsqrtf(var + EPSV);
  bf16t* dst = x + (long)r * DM;
  #pragma unroll
  for (int i = 0; i < 4; i++) {
    int d = threadIdx.x + 256 * i;
    dst[d] = f2bf((v[i] - mu) * rstd * w[d] + bb[d]);
  }
}

// ---------- MFMA bf16 GEMM with coalesced LDS-transpose epilogues ----------
// EPI 0: route -> z(bf16) / xpre(bf16); dtraw block scalar   (in_proj)
// EPI 1: Cb bf16 plain                                       (out_proj -> mfull bf16)
// EPI 2: Cb bf16 gelu(v + bias)                              (ffn1)
// EPI 3: Cf f32 = v + bias + bf16 res (two-pass f32 LDS)     (ffn2 -> d_out)
template<int EPI>
__global__ __launch_bounds__(256) void gemm_mfma(
    const bf16t* __restrict__ A, const bf16t* __restrict__ W,
    const float* __restrict__ bias, const bf16t* __restrict__ res,
    float* __restrict__ Cf, bf16t* __restrict__ Cb,
    bf16t* __restrict__ z, bf16t* __restrict__ xpre, float* __restrict__ dtr,
    int M, int N, int K) {
  __shared__ __align__(16) short LDS[128 * 136];   // 34816 B; front 16 KB = As+Ws
  short* As = LDS;              // [128][32]
  short* Ws = LDS + 128 * 32;   // [128][32]
  int tid = threadIdx.x;
  int lane = tid & 63, w = tid >> 6;
  int wr = w >> 1, wc = w & 1;
  int bm = blockIdx.y * 128, bn = blockIdx.x * 128;

  int r1 = tid >> 2,         s1 = (tid & 3) * 8;
  int r2 = (tid + 256) >> 2, s2 = ((tid + 256) & 3) * 8;
  const bf16t* gA1 = A + (long)(bm + r1) * K + s1;
  const bf16t* gA2 = A + (long)(bm + r2) * K + s2;
  const bf16t* gW1 = W + (long)(bn + r1) * K + s1;
  const bf16t* gW2 = W + (long)(bn + r2) * K + s2;
  short* lA1 = As + tid * 8;
  short* lA2 = As + (tid + 256) * 8;
  short* lW1 = Ws + tid * 8;
  short* lW2 = Ws + (tid + 256) * 8;

  int arow = wr * 64 + (lane & 15);
  int brow = wc * 64 + (lane & 15);
  int koff = (lane >> 4) * 8;

  f32x4 acc[4][4] = {};
  for (int k0 = 0; k0 < K; k0 += 32) {
    g2lds16(gA1 + k0, lA1);
    g2lds16(gA2 + k0, lA2);
    g2lds16(gW1 + k0, lW1);
    g2lds16(gW2 + k0, lW2);
    __syncthreads();
    bf16x8 af[4], bf[4];
    #pragma unroll
    for (int mi = 0; mi < 4; mi++) af[mi] = *(bf16x8*)&As[(arow + mi * 16) * 32 + koff];
    #pragma unroll
    for (int ni = 0; ni < 4; ni++) bf[ni] = *(bf16x8*)&Ws[(brow + ni * 16) * 32 + koff];
    #pragma unroll
    for (int mi = 0; mi < 4; mi++)
      #pragma unroll
      for (int ni = 0; ni < 4; ni++)
        acc[mi][ni] = __builtin_amdgcn_mfma_f32_16x16x32_bf16(af[mi], bf[ni], acc[mi][ni], 0, 0, 0);
    __syncthreads();
  }

  int rb = wr * 64 + (lane >> 4) * 4;
  int cb = wc * 64 + (lane & 15);

  // in_proj dtraw block (bn == 4224): only first 16 cols real, scalar path
  if (EPI == 0 && bn >= DINNER + CONVD) {
    #pragma unroll
    for (int mi = 0; mi < 4; mi++)
      #pragma unroll
      for (int ni = 0; ni < 4; ni++)
        #pragma unroll
        for (int r = 0; r < 4; r++) {
          int col = cb + ni * 16;
          if (col < NH)
            dtr[(long)(bm + rb + mi * 16 + r) * NH + col] = acc[mi][ni][r];
        }
    return;
  }

  if (EPI == 3) {
    // f32 two-pass epilogue: exact final output
    float* Cs32 = (float*)LDS;                 // [64][136]
    #pragma unroll
    for (int pass = 0; pass < 2; pass++) {
      __syncthreads();
      if (wr == pass) {
        #pragma unroll
        for (int mi = 0; mi < 4; mi++)
          #pragma unroll
          for (int ni = 0; ni < 4; ni++)
            #pragma unroll
            for (int r = 0; r < 4; r++) {
              int lrow = (lane >> 4) * 4 + mi * 16 + r;
              Cs32[lrow * 136 + cb + ni * 16] = acc[mi][ni][r];
            }
      }
      __syncthreads();
      #pragma unroll
      for (int q = 0; q < 4; q++) {
        int row = q * 16 + (tid >> 4);
        int col = (tid & 15) * 8;
        long grow = bm + pass * 64 + row; int gcol = bn + col;
        float4 v0 = *(float4*)&Cs32[row * 136 + col];
        float4 v1 = *(float4*)&Cs32[row * 136 + col + 4];
        float4 b0 = *(const float4*)&bias[gcol];
        float4 b1 = *(const float4*)&bias[gcol + 4];
        bf16x8 rv = *(const bf16x8*)&res[grow * N + gcol];
        v0.x += b0.x + bf2f((bf16t)rv[0]); v0.y += b0.y + bf2f((bf16t)rv[1]);
        v0.z += b0.z + bf2f((bf16t)rv[2]); v0.w += b0.w + bf2f((bf16t)rv[3]);
        v1.x += b1.x + bf2f((bf16t)rv[4]); v1.y += b1.y + bf2f((bf16t)rv[5]);
        v1.z += b1.z + bf2f((bf16t)rv[6]); v1.w += b1.w + bf2f((bf16t)rv[7]);
        *(float4*)&Cf[grow * N + gcol] = v0;
        *(float4*)&Cf[grow * N + gcol + 4] = v1;
      }
    }
    return;
  }

  // bf16 one-pass epilogue
  __syncthreads();
  bf16t* Cs = (bf16t*)LDS;                     // [128][136]
  #pragma unroll
  for (int mi = 0; mi < 4; mi++)
    #pragma unroll
    for (int ni = 0; ni < 4; ni++)
      #pragma unroll
      for (int r = 0; r < 4; r++) {
        float v = acc[mi][ni][r];
        if (EPI == 2) {
          v += bias[bn + cb + ni * 16];
          v = 0.5f * v * (1.f + erff(v * 0.70710678118f));
        }
        Cs[(rb + mi * 16 + r) * 136 + cb + ni * 16] = f2bf(v);
      }
  __syncthreads();
  #pragma unroll
  for (int pass = 0; pass < 8; pass++) {
    int row = pass * 16 + (tid >> 4);
    int col = (tid & 15) * 8;
    bf16x8 vv = *(bf16x8*)&Cs[row * 136 + col];
    long grow = bm + row; int gcol = bn + col;
    if (EPI == 0) {
      if (bn < DINNER) *(bf16x8*)&z[grow * DINNER + gcol] = vv;
      else             *(bf16x8*)&xpre[grow * CONVD + (gcol - DINNER)] = vv;
    } else {
      *(bf16x8*)&Cb[grow * N + gcol] = vv;
    }
  }
}

// ---------- dt (softplus) + per-chunk inclusive cumsum of dt*A ----------
__global__ __launch_bounds__(256) void cumsum_kernel(
    const float* __restrict__ dtraw, const float* __restrict__ dt_bias,
    const float* __restrict__ A_log, float* __restrict__ dt,
    float* __restrict__ Acum) {
  int bid = blockIdx.x;                 // (b*NH+h)*NCHUNK + c
  int c = bid % NCHUNK; int hh = bid / NCHUNK;
  int h = hh % NH; int b = hh / NH;
  int k = threadIdx.x;
  float a = -__expf(A_log[h]);
  long t = (long)b * T_ + c * CK + k;
  float v0 = dtraw[t * NH + h] + dt_bias[h];
  float dtv = (v0 > 20.f) ? v0 : log1pf(__expf(v0));
  dt[t * NH + h] = dtv;
  float v = dtv * a;
  __shared__ float buf[2][CK];
  int cur = 0;
  buf[0][k] = v; __syncthreads();
  for (int off = 1; off < CK; off <<= 1) {
    float tv = buf[cur][k];
    if (k >= off) tv += buf[cur][k - off];
    buf[1 - cur][k] = tv; cur ^= 1; __syncthreads();
  }
  Acum[(long)bid * CK + k] = buf[cur][k];
}

// ---------- causal depthwise conv(4) + bias + silu, vectorized x8 ----------
__global__ __launch_bounds__(256) void conv_kernel(
    const bf16t* __restrict__ xpre, const float* __restrict__ cw,
    const float* __restrict__ cb, bf16t* __restrict__ out) {
  int idx = blockIdx.x * 256 + threadIdx.x;   // < 9216*272
  int cg = idx % 272; long r = idx / 272;     // r = b*T_ + t
  int t = (int)(r % T_);
  int c0 = cg * 8;
  float4 cb0 = *(const float4*)&cb[c0];
  float4 cb1 = *(const float4*)&cb[c0 + 4];
  float acc[8] = {cb0.x, cb0.y, cb0.z, cb0.w, cb1.x, cb1.y, cb1.z, cb1.w};
  #pragma unroll
  for (int i = 0; i < 4; i++) {
    int ts = t - 3 + i;
    if (ts >= 0) {
      bf16x8 u = *(const bf16x8*)&xpre[(r - 3 + i) * CONVD + c0];
      #pragma unroll
      for (int j = 0; j < 8; j++) acc[j] += bf2f((bf16t)u[j]) * cw[(c0 + j) * 4 + i];
    }
  }
  bf16x8 o;
  #pragma unroll
  for (int j = 0; j < 8; j++) {
    float s = acc[j] / (1.f + __expf(-acc[j]));
    o[j] = (short)f2bf(s);
  }
  *(bf16x8*)&out[r * CONVD + c0] = o;
}

// ---------- per-chunk states via MFMA: cs[bid][p][n], bid=(b*NC+c)*NH+h ----------
__global__ __launch_bounds__(256) void chunk_states_kernel(
    const bf16t* __restrict__ xbc, const float* __restrict__ dt,
    const float* __restrict__ Acum, float* __restrict__ cs) {
  int bid = blockIdx.x;
  int h = bid % NH; int bc = bid / NH;
  int c = bc % NCHUNK; int b = bc / NCHUNK;
  int tid = threadIdx.x;
  int lane = tid & 63, w = tid >> 6;
  long tch = (long)b * T_ + c * CK;
  int acb = ((b * NH + h) * NCHUNK + c) * CK;
  float Alast = Acum[acb + CK - 1];

  __shared__ bf16t Xt[128][72];   // Xt[p][s]  (x * w)
  __shared__ bf16t Bt[64][72];    // Bt[n][s]
  __shared__ float wk[64];

  f32x4 acc[8] = {};
  for (int kb = 0; kb < 4; kb++) {
    int s0 = kb * 64;
    __syncthreads();
    if (tid < 64)
      wk[tid] = __expf(Alast - Acum[acb + s0 + tid]) * dt[(tch + s0 + tid) * NH + h];
    __syncthreads();
    for (int e = tid; e < 64 * 32; e += 256) {       // p4 in [0,32): all 128 p
      int s = e & 63, p4 = e >> 6;
      ushort4 u = *(const ushort4*)&xbc[(tch + s0 + s) * CONVD + h * HD + p4 * 4];
      float wv = wk[s];
      Xt[p4 * 4 + 0][s] = f2bf(bf2f(u.x) * wv);
      Xt[p4 * 4 + 1][s] = f2bf(bf2f(u.y) * wv);
      Xt[p4 * 4 + 2][s] = f2bf(bf2f(u.z) * wv);
      Xt[p4 * 4 + 3][s] = f2bf(bf2f(u.w) * wv);
    }
    for (int e = tid; e < 64 * 16; e += 256) {       // n4 in [0,16): all 64 n
      int s = e & 63, n4 = e >> 6;
      ushort4 u = *(const ushort4*)&xbc[(tch + s0 + s) * CONVD + DINNER + n4 * 4];
      Bt[n4 * 4 + 0][s] = u.x; Bt[n4 * 4 + 1][s] = u.y;
      Bt[n4 * 4 + 2][s] = u.z; Bt[n4 * 4 + 3][s] = u.w;
    }
    __syncthreads();
    #pragma unroll
    for (int ks = 0; ks < 2; ks++) {
      int koff = (lane >> 4) * 8 + ks * 32;
      bf16x8 bfr = *(bf16x8*)&Bt[w * 16 + (lane & 15)][koff];
      #pragma unroll
      for (int mi = 0; mi < 8; mi++) {
        bf16x8 af = *(bf16x8*)&Xt[mi * 16 + (lane & 15)][koff];
        acc[mi] = __builtin_amdgcn_mfma_f32_16x16x32_bf16(af, bfr, acc[mi], 0, 0, 0);
      }
    }
  }
  float* out = cs + (long)bid * HD * NSTATE;
  int n = w * 16 + (lane & 15);
  #pragma unroll
  for (int mi = 0; mi < 8; mi++) {
    #pragma unroll
    for (int r = 0; r < 4; r++) {
      int p = mi * 16 + (lane >> 4) * 4 + r;
      out[p * NSTATE + n] = acc[mi][r];
    }
  }
}

// ---------- sequential inter-chunk recurrence, IN PLACE ----------
__global__ __launch_bounds__(256) void state_pass_kernel(
    float* __restrict__ cs, const float* __restrict__ Acum) {
  int bh = blockIdx.x;                  // b*NH + h
  int b = bh / NH, h = bh % NH;
  int e0 = blockIdx.y * 1024 + threadIdx.x;
  for (int q = 0; q < 4; q++) {
    int e = e0 + q * 256;
    float s = 0.f;
    for (int c = 0; c < NCHUNK; c++) {
      long idx = ((long)(b * NCHUNK + c) * NH + h) * (HD * NSTATE) + e;
      float tmp = cs[idx];
      cs[idx] = s;
      float g = __expf(Acum[((b * NH + h) * NCHUNK + c) * CK + CK - 1]);
      s = s * g + tmp;
    }
  }
}

// ---------- SSD Y via MFMA ----------
__global__ __launch_bounds__(256) void ssd_y_kernel(
    const bf16t* __restrict__ xbc, const float* __restrict__ dt,
    const float* __restrict__ Acum, const float* __restrict__ sin_,
    const float* __restrict__ Dskip, bf16t* __restrict__ Y) {
  int bid = blockIdx.x;
  int h = bid % NH; int bc = bid / NH;
  int c = bc % NCHUNK; int b = bc / NCHUNK;
  int rt = blockIdx.y;
  int tid = threadIdx.x;
  int lane = tid & 63, w = tid >> 6;
  int wr = w >> 1, wc = w & 1;
  long tch = (long)b * T_ + c * CK;
  long tbase = tch + rt * 128;
  int acb = ((b * NH + h) * NCHUNK + c) * CK;

  __shared__ bf16t Cs[128][72];
  __shared__ bf16t Bs[64][72];
  __shared__ bf16t Xt[128][72];
  __shared__ bf16t Sm[128][72];
  __shared__ float Akl[128];
  __shared__ float Asl[64];
  __shared__ float dts[64];

  for (int e = tid; e < 128 * 8; e += 256) {
    int row = e >> 3, seg = (e & 7) * 8;
    *(bf16x8*)&Cs[row][seg] =
        *(const bf16x8*)&xbc[(tbase + row) * CONVD + DINNER + NSTATE + seg];
  }
  if (tid < 128) Akl[tid] = Acum[acb + rt * 128 + tid];

  f32x4 acc[4][4] = {};
  int nsb = 2 * (rt + 1);
  for (int sb = 0; sb < nsb; sb++) {
    int s0 = sb * 64;
    __syncthreads();
    if (tid < 64) {
      Asl[tid] = Acum[acb + s0 + tid];
      dts[tid] = dt[(tch + s0 + tid) * NH + h];
    }
    __syncthreads();
    for (int e = tid; e < 64 * 8; e += 256) {
      int row = e >> 3, seg = (e & 7) * 8;
      *(bf16x8*)&Bs[row][seg] =
          *(const bf16x8*)&xbc[(tch + s0 + row) * CONVD + DINNER + seg];
    }
    for (int e = tid; e < 64 * 32; e += 256) {       // p4 in [0,32): all 128 p
      int s = e & 63, p4 = e >> 6;
      ushort4 u = *(const ushort4*)&xbc[(tch + s0 + s) * CONVD + h * HD + p4 * 4];
      float dtv = dts[s];
      Xt[p4 * 4 + 0][s] = f2bf(bf2f(u.x) * dtv);
      Xt[p4 * 4 + 1][s] = f2bf(bf2f(u.y) * dtv);
      Xt[p4 * 4 + 2][s] = f2bf(bf2f(u.z) * dtv);
      Xt[p4 * 4 + 3][s] = f2bf(bf2f(u.w) * dtv);
    }
    __syncthreads();
    {
      f32x4 sacc[2][4] = {};
      int rw0 = w * 32;
      #pragma unroll
      for (int ks = 0; ks < 2; ks++) {
        int koff = (lane >> 4) * 8 + ks * 32;
        bf16x8 a0 = *(bf16x8*)&Cs[rw0 + (lane & 15)][koff];
        bf16x8 a1 = *(bf16x8*)&Cs[rw0 + 16 + (lane & 15)][koff];
        #pragma unroll
        for (int ni = 0; ni < 4; ni++) {
          bf16x8 bfr = *(bf16x8*)&Bs[ni * 16 + (lane & 15)][koff];
          sacc[0][ni] = __builtin_amdgcn_mfma_f32_16x16x32_bf16(a0, bfr, sacc[0][ni], 0, 0, 0);
          sacc[1][ni] = __builtin_amdgcn_mfma_f32_16x16x32_bf16(a1, bfr, sacc[1][ni], 0, 0, 0);
        }
      }
      #pragma unroll
      for (int mi = 0; mi < 2; mi++) {
        #pragma unroll
        for (int ni = 0; ni < 4; ni++) {
          #pragma unroll
          for (int r = 0; r < 4; r++) {
            int row = rw0 + mi * 16 + (lane >> 4) * 4 + r;
            int scol = ni * 16 + (lane & 15);
            int kglob = rt * 128 + row;
            int sglob = s0 + scol;
            float val = 0.f;
            if (sglob <= kglob) val = sacc[mi][ni][r] * __expf(Akl[row] - Asl[scol]);
            Sm[row][scol] = f2bf(val);
          }
        }
      }
    }
    __syncthreads();
    #pragma unroll
    for (int ks = 0; ks < 2; ks++) {
      int koff = (lane >> 4) * 8 + ks * 32;
      bf16x8 af[4], bfr[4];
      #pragma unroll
      for (int mi = 0; mi < 4; mi++) af[mi] = *(bf16x8*)&Sm[wr * 64 + mi * 16 + (lane & 15)][koff];
      #pragma unroll
      for (int ni = 0; ni < 4; ni++) bfr[ni] = *(bf16x8*)&Xt[wc * 64 + ni * 16 + (lane & 15)][koff];
      #pragma unroll
      for (int mi = 0; mi < 4; mi++)
        #pragma unroll
        for (int ni = 0; ni < 4; ni++)
          acc[mi][ni] = __builtin_amdgcn_mfma_f32_16x16x32_bf16(af[mi], bfr[ni], acc[mi][ni], 0, 0, 0);
    }
  }

  float ekr[16];
  #pragma unroll
  for (int mi = 0; mi < 4; mi++)
    #pragma unroll
    for (int r = 0; r < 4; r++)
      ekr[mi * 4 + r] = __expf(Akl[wr * 64 + mi * 16 + (lane >> 4) * 4 + r]);

  const float* sinb = sin_ + (long)bid * HD * NSTATE;
  #pragma unroll
  for (int ni = 0; ni < 4; ni++) {
    f32x4 offacc[4] = {};
    int p = wc * 64 + ni * 16 + (lane & 15);
    #pragma unroll
    for (int ks = 0; ks < 2; ks++) {
      int koff = (lane >> 4) * 8 + ks * 32;
      const float* srow = sinb + p * NSTATE + koff;
      float4 sa = *(const float4*)srow;
      float4 sbv = *(const float4*)(srow + 4);
      bf16x8 bfr;
      bfr[0] = (short)f2bf(sa.x);  bfr[1] = (short)f2bf(sa.y);
      bfr[2] = (short)f2bf(sa.z);  bfr[3] = (short)f2bf(sa.w);
      bfr[4] = (short)f2bf(sbv.x); bfr[5] = (short)f2bf(sbv.y);
      bfr[6] = (short)f2bf(sbv.z); bfr[7] = (short)f2bf(sbv.w);
      #pragma unroll
      for (int mi = 0; mi < 4; mi++) {
        bf16x8 af = *(bf16x8*)&Cs[wr * 64 + mi * 16 + (lane & 15)][koff];
        offacc[mi] = __builtin_amdgcn_mfma_f32_16x16x32_bf16(af, bfr, offacc[mi], 0, 0, 0);
      }
    }
    #pragma unroll
    for (int mi = 0; mi < 4; mi++)
      #pragma unroll
      for (int r = 0; r < 4; r++)
        acc[mi][ni][r] += ekr[mi * 4 + r] * offacc[mi][r];
  }

  float dsk = Dskip[h];
  #pragma unroll
  for (int mi = 0; mi < 4; mi++) {
    #pragma unroll
    for (int r = 0; r < 4; r++) {
      int row = wr * 64 + mi * 16 + (lane >> 4) * 4 + r;
      long t = tbase + row;
      #pragma unroll
      for (int ni = 0; ni < 4; ni++) {
        int p = wc * 64 + ni * 16 + (lane & 15);
        float xsv = bf2f(xbc[t * CONVD + h * HD + p]);
        Y[t * DINNER + h * HD + p] = f2bf(acc[mi][ni][r] + dsk * xsv);
      }
    }
  }
}

// ---------- y *= silu(z); RMSNorm * ssd_norm_w (in place on Y, bf16) ----------
__global__ __launch_bounds__(256) void gate_rms_kernel(
    const bf16t* __restrict__ z, const float* __restrict__ nw,
    bf16t* __restrict__ Y) {
  long r = blockIdx.x;
  const bf16t* zrow = z + r * DINNER;
  bf16t* yrow = Y + r * DINNER;
  int tid = threadIdx.x;
  float v[8]; float sq = 0.f;
  #pragma unroll
  for (int i = 0; i < 4; i++) {
    int d = tid * 2 + 512 * i;
    ushort2 zu = *(const ushort2*)&zrow[d];
    ushort2 yu = *(const ushort2*)&yrow[d];
    float z0 = bf2f(zu.x), z1 = bf2f(zu.y);
    float y0 = bf2f(yu.x) * (z0 / (1.f + __expf(-z0)));
    float y1 = bf2f(yu.y) * (z1 / (1.f + __expf(-z1)));
    v[2 * i] = y0; v[2 * i + 1] = y1;
    sq += y0 * y0 + y1 * y1;
  }
  float2 r2 = block_reduce2(sq, 0.f);
  float rms = rsqrtf(r2.x * (1.f / DINNER) + EPSV);
  #pragma unroll
  for (int i = 0; i < 4; i++) {
    int d = tid * 2 + 512 * i;
    ushort2 o;
    o.x = f2bf(v[2 * i] * rms * nw[d]);
    o.y = f2bf(v[2 * i + 1] * rms * nw[d + 1]);
    *(ushort2*)&yrow[d] = o;
  }
}

// ---------- residual add (last L rows) + LayerNorm3 -> bf16 ----------
__global__ __launch_bounds__(256) void res_ln3_kernel(
    const bf16t* __restrict__ mfull, const bf16t* __restrict__ x,
    const float* __restrict__ w3, const float* __restrict__ b3,
    bf16t* __restrict__ x2) {
  int rl = blockIdx.x;                  // b*L_ + tl
  int tl = rl % L_, b = rl / L_;
  long rt = (long)b * T_ + G_ + tl;
  const bf16t* m = mfull + rt * DM;
  const bf16t* xr = x + rt * DM;
  int tid = threadIdx.x;
  float v[4]; float s = 0.f, sq = 0.f;
  #pragma unroll
  for (int i = 0; i < 2; i++) {
    int d = tid * 2 + 512 * i;
    ushort2 mu2 = *(const ushort2*)&m[d];
    ushort2 xu2 = *(const ushort2*)&xr[d];
    float a0 = bf2f(mu2.x) + bf2f(xu2.x);
    float a1 = bf2f(mu2.y) + bf2f(xu2.y);
    v[2 * i] = a0; v[2 * i + 1] = a1;
    s += a0 + a1; sq += a0 * a0 + a1 * a1;
  }
  float2 r2 = block_reduce2(s, sq);
  float mu = r2.x * (1.f / DM);
  float var = r2.y * (1.f / DM) - mu * mu;
  float rstd = rsqrtf(var + EPSV);
  bf16t* dst = x2 + (long)rl * DM;
  #pragma unroll
  for (int i = 0; i < 2; i++) {
    int d = tid * 2 + 512 * i;
    ushort2 o;
    o.x = f2bf((v[2 * i] - mu) * rstd * w3[d] + b3[d]);
    o.y = f2bf((v[2 * i + 1] - mu) * rstd * w3[d + 1] + b3[d + 1]);
    *(ushort2*)&dst[d] = o;
  }
}

extern "C" void kernel_launch(void* const* d_in, const int* in_sizes, int n_in,
                              void* d_out, int out_size, void* d_ws, size_t ws_size,
                              hipStream_t stream) {
  const float* localr = (const float*)d_in[0];
  const float* globalr= (const float*)d_in[1];
  const float* n1w = (const float*)d_in[2];
  const float* n1b = (const float*)d_in[3];
  const float* n2w = (const float*)d_in[4];
  const float* n2b = (const float*)d_in[5];
  const float* n3w = (const float*)d_in[6];
  const float* n3b = (const float*)d_in[7];
  const float* inpw= (const float*)d_in[8];
  const float* convw=(const float*)d_in[9];
  const float* convb=(const float*)d_in[10];
  const float* dtb = (const float*)d_in[11];
  const float* alog= (const float*)d_in[12];
  const float* dskp= (const float*)d_in[13];
  const float* ssdw= (const float*)d_in[14];
  const float* outw= (const float*)d_in[15];
  const float* f1w = (const float*)d_in[16];
  const float* f1b = (const float*)d_in[17];
  const float* f2w = (const float*)d_in[18];
  const float* f2b = (const float*)d_in[19];

  // ---- workspace layout (byte offsets); peak = 157,483,008 B (~150 MB) ----
  char* ws = (char*)d_ws;
  bf16t* x     = (bf16t*)(ws + 0);             // 9216*1024 bf16
  bf16t* z     = (bf16t*)(ws + 18874368);      // 9216*2048 bf16
  bf16t* mfull = (bf16t*)(ws + 18874368);      //   overlay: 9216*1024 bf16 (after gate_rms)
  bf16t* xpre  = (bf16t*)(ws + 56623104);      // 9216*2176 bf16
  bf16t* Yb    = (bf16t*)(ws + 56623104);      //   overlay: 9216*2048 bf16 (after conv)
  float* dtraw = (float*)(ws + 96731136);      // 9216*16 f32
  float* dt    = (float*)(ws + 97320960);      // 9216*16 f32
  float* Acum  = (float*)(ws + 97910784);      // 64*9*256 f32
  bf16t* xbc   = (bf16t*)(ws + 98500608);      // 9216*2176 bf16
  bf16t* x2bf  = (bf16t*)(ws + 98500608);      //   overlay after ssd_y: 8192*1024 bf16
  bf16t* hbuf  = (bf16t*)(ws + 115277824);     //   overlay: 8192*512 bf16
  bf16t* outw_bf = (bf16t*)(ws + 123666432);   //   overlay: 1024*2048 bf16
  bf16t* f1w_bf  = (bf16t*)(ws + 127860736);   //   overlay: 512*1024 bf16
  bf16t* f2w_bf  = (bf16t*)(ws + 128909312);   //   overlay: 1024*512 bf16
  float* cs    = (float*)(ws + 138608640);     // 576*8192 f32
  bf16t* inpw_bf = (bf16t*)(ws + 138608640);   //   overlay BEFORE chunk_states

  cvt_inproj_kernel<<<(int)(((long)NPROJ_PAD * DM + 255) / 256), 256, 0, stream>>>(inpw, inpw_bf);

  ln_concat_kernel<<<B_ * T_, 256, 0, stream>>>(localr, globalr, n1w, n1b, n2w, n2b, x);

  gemm_mfma<0><<<dim3(NPROJ_PAD / 128, (B_ * T_) / 128), 256, 0, stream>>>(
      x, inpw_bf, nullptr, nullptr, nullptr, nullptr, z, xpre, dtraw, B_ * T_, NPROJ_PAD, DM);

  cumsum_kernel<<<B_ * NH * NCHUNK, 256, 0, stream>>>(dtraw, dtb, alog, dt, Acum);

  conv_kernel<<<(B_ * T_ * 272) / 256, 256, 0, stream>>>(xpre, convw, convb, xbc);

  chunk_states_kernel<<<B_ * NCHUNK * NH, 256, 0, stream>>>(xbc, dt, Acum, cs);

  state_pass_kernel<<<dim3(B_ * NH, 8), 256, 0, stream>>>(cs, Acum);

  ssd_y_kernel<<<dim3(B_ * NCHUNK * NH, 2), 256, 0, stream>>>(xbc, dt, Acum, cs, dskp, Yb);

  {
    long ntot = (long)DM * DINNER + 2L * (DM / 2) * DM;
    cvt_late_kernel<<<(int)((ntot + 255) / 256), 256, 0, stream>>>(
        outw, f1w, f2w, outw_bf, f1w_bf, f2w_bf);
  }

  gate_rms_kernel<<<B_ * T_, 256, 0, stream>>>(z, ssdw, Yb);

  gemm_mfma<1><<<dim3(DM / 128, (B_ * T_) / 128), 256, 0, stream>>>(
      Yb, outw_bf, nullptr, nullptr, nullptr, mfull, nullptr, nullptr, nullptr,
      B_ * T_, DM, DINNER);

  res_ln3_kernel<<<B_ * L_, 256, 0, stream>>>(mfull, x, n3w, n3b, x2bf);

  gemm_mfma<2><<<dim3((DM / 2) / 128, (B_ * L_) / 128), 256, 0, stream>>>(
      x2bf, f1w_bf, f1b, nullptr, nullptr, hbuf, nullptr, nullptr, nullptr,
      B_ * L_, DM / 2, DM);

  gemm_mfma<3><<<dim3(DM / 128, (B_ * L_) / 128), 256, 0, stream>>>(
      hbuf, f2w_bf, f2b, x2bf, (float*)d_out, nullptr, nullptr, nullptr, nullptr,
      B_ * L_, DM, DM / 2);
}

// Round 7
// 581.631 us; speedup vs baseline: 5.3175x; 1.2010x over previous
//
#include <hip/hip_runtime.h>
#include <math.h>

#define B_ 4
#define L_ 2048
#define G_ 256
#define T_ 2304          // G_ + L_
#define DM 1024
#define DINNER 2048
#define NH 16
#define HD 128
#define NSTATE 64
#define CONVD 2176       // DINNER + 2*NSTATE
#define DPROJ 4240       // 2*DINNER + 2*NSTATE + NH
#define NPROJ_PAD 4352   // DPROJ padded to 128
#define NCHUNK 9
#define CK 256
#define EPSV 1e-5f
#define CROWS 16         // conv rows per thread

typedef unsigned short bf16t;
using bf16x8 = __attribute__((ext_vector_type(8))) short;
using f32x4  = __attribute__((ext_vector_type(4))) float;

__device__ __forceinline__ float bf2f(bf16t u) {
  return __uint_as_float(((unsigned int)u) << 16);
}
__device__ __forceinline__ bf16t f2bf(float f) {
  unsigned int u = __float_as_uint(f);
  u += 0x7FFFu + ((u >> 16) & 1u);
  return (bf16t)(u >> 16);
}

__device__ __forceinline__ void g2lds16(const bf16t* g, short* l) {
  __builtin_amdgcn_global_load_lds(
      (const __attribute__((address_space(1))) unsigned int*)g,
      (__attribute__((address_space(3))) unsigned int*)l, 16, 0, 0);
}

// ---------- block-wide reduction of two values (blockDim == 256) ----------
__device__ __forceinline__ float2 block_reduce2(float a, float b) {
  __shared__ float sa[4], sb[4];
  #pragma unroll
  for (int off = 32; off > 0; off >>= 1) {
    a += __shfl_down(a, off, 64);
    b += __shfl_down(b, off, 64);
  }
  int lane = threadIdx.x & 63, wid = threadIdx.x >> 6;
  if (lane == 0) { sa[wid] = a; sb[wid] = b; }
  __syncthreads();
  return make_float2(sa[0] + sa[1] + sa[2] + sa[3], sb[0] + sb[1] + sb[2] + sb[3]);
}

// ---------- fp32 -> bf16 weight convert: in_proj (padded) ----------
__global__ __launch_bounds__(256) void cvt_inproj_kernel(
    const float* __restrict__ w, bf16t* __restrict__ o) {
  long i = (long)blockIdx.x * 256 + threadIdx.x;
  long nreal = (long)DPROJ * DM, ntot = (long)NPROJ_PAD * DM;
  if (i < ntot) o[i] = (i < nreal) ? f2bf(w[i]) : (bf16t)0;
}

// ---------- fp32 -> bf16 late weights (out_proj + ffn1 + ffn2, one launch) ----------
__global__ __launch_bounds__(256) void cvt_late_kernel(
    const float* __restrict__ outw, const float* __restrict__ f1w,
    const float* __restrict__ f2w, bf16t* __restrict__ o_out,
    bf16t* __restrict__ o_f1, bf16t* __restrict__ o_f2) {
  long i = (long)blockIdx.x * 256 + threadIdx.x;
  const long n1 = (long)DM * DINNER;          // 2097152
  const long n2 = (long)(DM / 2) * DM;        // 524288
  if (i < n1) { o_out[i] = f2bf(outw[i]); return; }
  i -= n1;
  if (i < n2) { o_f1[i] = f2bf(f1w[i]); return; }
  i -= n2;
  if (i < n2) o_f2[i] = f2bf(f2w[i]);
}

// ---------- LayerNorm(local) / LayerNorm(global) + concat -> x (bf16) ----------
__global__ __launch_bounds__(256) void ln_concat_kernel(
    const float* __restrict__ localr, const float* __restrict__ globalr,
    const float* __restrict__ w1, const float* __restrict__ b1,
    const float* __restrict__ w2, const float* __restrict__ b2,
    bf16t* __restrict__ x) {
  int r = blockIdx.x;          // b*T_ + t
  int t = r % T_, b = r / T_;
  const float *src, *w, *bb;
  if (t < G_) { src = globalr + ((long)b * G_ + t) * DM;        w = w2; bb = b2; }
  else        { src = localr  + ((long)b * L_ + (t - G_)) * DM; w = w1; bb = b1; }
  float v[4]; float s = 0.f, sq = 0.f;
  #pragma unroll
  for (int i = 0; i < 4; i++) {
    v[i] = src[threadIdx.x + 256 * i];
    s += v[i]; sq += v[i] * v[i];
  }
  float2 r2 = block_reduce2(s, sq);
  float mu = r2.x * (1.f / DM);
  float var = r2.y * (1.f / DM) - mu * mu;
  float rstd = rsqrtf(var + EPSV);
  bf16t* dst = x + (long)r * DM;
  #pragma unroll
  for (int i = 0; i < 4; i++) {
    int d = threadIdx.x + 256 * i;
    dst[d] = f2bf((v[i] - mu) * rstd * w[d] + bb[d]);
  }
}

// ---------- MFMA bf16 GEMM with coalesced LDS-transpose epilogues ----------
// EPI 0: route -> z(bf16) / xpre(bf16); dtraw block scalar   (in_proj)
// EPI 1: Cb bf16 plain                                       (out_proj -> mfull bf16)
// EPI 2: Cb bf16 gelu(v + bias)                              (ffn1)
// EPI 3: Cf f32 = v + bias + bf16 res (two-pass f32 LDS)     (ffn2 -> d_out)
template<int EPI>
__global__ __launch_bounds__(256) void gemm_mfma(
    const bf16t* __restrict__ A, const bf16t* __restrict__ W,
    const float* __restrict__ bias, const bf16t* __restrict__ res,
    float* __restrict__ Cf, bf16t* __restrict__ Cb,
    bf16t* __restrict__ z, bf16t* __restrict__ xpre, float* __restrict__ dtr,
    int M, int N, int K) {
  __shared__ __align__(16) short LDS[128 * 136];   // 34816 B; front 16 KB = As+Ws
  short* As = LDS;              // [128][32]
  short* Ws = LDS + 128 * 32;   // [128][32]
  int tid = threadIdx.x;
  int lane = tid & 63, w = tid >> 6;
  int wr = w >> 1, wc = w & 1;
  int bm = blockIdx.y * 128, bn = blockIdx.x * 128;

  int r1 = tid >> 2,         s1 = (tid & 3) * 8;
  int r2 = (tid + 256) >> 2, s2 = ((tid + 256) & 3) * 8;
  const bf16t* gA1 = A + (long)(bm + r1) * K + s1;
  const bf16t* gA2 = A + (long)(bm + r2) * K + s2;
  const bf16t* gW1 = W + (long)(bn + r1) * K + s1;
  const bf16t* gW2 = W + (long)(bn + r2) * K + s2;
  short* lA1 = As + tid * 8;
  short* lA2 = As + (tid + 256) * 8;
  short* lW1 = Ws + tid * 8;
  short* lW2 = Ws + (tid + 256) * 8;

  int arow = wr * 64 + (lane & 15);
  int brow = wc * 64 + (lane & 15);
  int koff = (lane >> 4) * 8;

  f32x4 acc[4][4] = {};
  for (int k0 = 0; k0 < K; k0 += 32) {
    g2lds16(gA1 + k0, lA1);
    g2lds16(gA2 + k0, lA2);
    g2lds16(gW1 + k0, lW1);
    g2lds16(gW2 + k0, lW2);
    __syncthreads();
    bf16x8 af[4], bf[4];
    #pragma unroll
    for (int mi = 0; mi < 4; mi++) af[mi] = *(bf16x8*)&As[(arow + mi * 16) * 32 + koff];
    #pragma unroll
    for (int ni = 0; ni < 4; ni++) bf[ni] = *(bf16x8*)&Ws[(brow + ni * 16) * 32 + koff];
    #pragma unroll
    for (int mi = 0; mi < 4; mi++)
      #pragma unroll
      for (int ni = 0; ni < 4; ni++)
        acc[mi][ni] = __builtin_amdgcn_mfma_f32_16x16x32_bf16(af[mi], bf[ni], acc[mi][ni], 0, 0, 0);
    __syncthreads();
  }

  int rb = wr * 64 + (lane >> 4) * 4;
  int cb = wc * 64 + (lane & 15);

  // in_proj dtraw block (bn == 4224): only first 16 cols real, scalar path
  if (EPI == 0 && bn >= DINNER + CONVD) {
    #pragma unroll
    for (int mi = 0; mi < 4; mi++)
      #pragma unroll
      for (int ni = 0; ni < 4; ni++)
        #pragma unroll
        for (int r = 0; r < 4; r++) {
          int col = cb + ni * 16;
          if (col < NH)
            dtr[(long)(bm + rb + mi * 16 + r) * NH + col] = acc[mi][ni][r];
        }
    return;
  }

  if (EPI == 3) {
    // f32 two-pass epilogue: exact final output
    float* Cs32 = (float*)LDS;                 // [64][136]
    #pragma unroll
    for (int pass = 0; pass < 2; pass++) {
      __syncthreads();
      if (wr == pass) {
        #pragma unroll
        for (int mi = 0; mi < 4; mi++)
          #pragma unroll
          for (int ni = 0; ni < 4; ni++)
            #pragma unroll
            for (int r = 0; r < 4; r++) {
              int lrow = (lane >> 4) * 4 + mi * 16 + r;
              Cs32[lrow * 136 + cb + ni * 16] = acc[mi][ni][r];
            }
      }
      __syncthreads();
      #pragma unroll
      for (int q = 0; q < 4; q++) {
        int row = q * 16 + (tid >> 4);
        int col = (tid & 15) * 8;
        long grow = bm + pass * 64 + row; int gcol = bn + col;
        float4 v0 = *(float4*)&Cs32[row * 136 + col];
        float4 v1 = *(float4*)&Cs32[row * 136 + col + 4];
        float4 b0 = *(const float4*)&bias[gcol];
        float4 b1 = *(const float4*)&bias[gcol + 4];
        bf16x8 rv = *(const bf16x8*)&res[grow * N + gcol];
        v0.x += b0.x + bf2f((bf16t)rv[0]); v0.y += b0.y + bf2f((bf16t)rv[1]);
        v0.z += b0.z + bf2f((bf16t)rv[2]); v0.w += b0.w + bf2f((bf16t)rv[3]);
        v1.x += b1.x + bf2f((bf16t)rv[4]); v1.y += b1.y + bf2f((bf16t)rv[5]);
        v1.z += b1.z + bf2f((bf16t)rv[6]); v1.w += b1.w + bf2f((bf16t)rv[7]);
        *(float4*)&Cf[grow * N + gcol] = v0;
        *(float4*)&Cf[grow * N + gcol + 4] = v1;
      }
    }
    return;
  }

  // bf16 one-pass epilogue
  __syncthreads();
  bf16t* Cs = (bf16t*)LDS;                     // [128][136]
  #pragma unroll
  for (int mi = 0; mi < 4; mi++)
    #pragma unroll
    for (int ni = 0; ni < 4; ni++)
      #pragma unroll
      for (int r = 0; r < 4; r++) {
        float v = acc[mi][ni][r];
        if (EPI == 2) {
          v += bias[bn + cb + ni * 16];
          v = 0.5f * v * (1.f + erff(v * 0.70710678118f));
        }
        Cs[(rb + mi * 16 + r) * 136 + cb + ni * 16] = f2bf(v);
      }
  __syncthreads();
  #pragma unroll
  for (int pass = 0; pass < 8; pass++) {
    int row = pass * 16 + (tid >> 4);
    int col = (tid & 15) * 8;
    bf16x8 vv = *(bf16x8*)&Cs[row * 136 + col];
    long grow = bm + row; int gcol = bn + col;
    if (EPI == 0) {
      if (bn < DINNER) *(bf16x8*)&z[grow * DINNER + gcol] = vv;
      else             *(bf16x8*)&xpre[grow * CONVD + (gcol - DINNER)] = vv;
    } else {
      *(bf16x8*)&Cb[grow * N + gcol] = vv;
    }
  }
}

// ---------- dt (softplus) + per-chunk inclusive cumsum of dt*A ----------
__global__ __launch_bounds__(256) void cumsum_kernel(
    const float* __restrict__ dtraw, const float* __restrict__ dt_bias,
    const float* __restrict__ A_log, float* __restrict__ dt,
    float* __restrict__ Acum) {
  int bid = blockIdx.x;                 // (b*NH+h)*NCHUNK + c
  int c = bid % NCHUNK; int hh = bid / NCHUNK;
  int h = hh % NH; int b = hh / NH;
  int k = threadIdx.x;
  float a = -__expf(A_log[h]);
  long t = (long)b * T_ + c * CK + k;
  float v0 = dtraw[t * NH + h] + dt_bias[h];
  float dtv = (v0 > 20.f) ? v0 : log1pf(__expf(v0));
  dt[t * NH + h] = dtv;
  float v = dtv * a;
  __shared__ float buf[2][CK];
  int cur = 0;
  buf[0][k] = v; __syncthreads();
  for (int off = 1; off < CK; off <<= 1) {
    float tv = buf[cur][k];
    if (k >= off) tv += buf[cur][k - off];
    buf[1 - cur][k] = tv; cur ^= 1; __syncthreads();
  }
  Acum[(long)bid * CK + k] = buf[cur][k];
}

// ---------- causal conv(4) + bias + silu: rolling window, weights amortized ----------
// thread = (channel-group of 8, row-tile of CROWS). Each input row read ONCE.
__global__ __launch_bounds__(256) void conv_kernel(
    const bf16t* __restrict__ xpre, const float* __restrict__ cw,
    const float* __restrict__ cb, bf16t* __restrict__ out) {
  int gt = blockIdx.x * 256 + threadIdx.x;    // < 576*272
  int cg = gt % 272; int rt = gt / 272;
  int c0 = cg * 8;
  long r0 = (long)rt * CROWS;                 // b*T_ + t ; tiles never cross batches
  int t0 = (int)(r0 % T_);

  // weights: 8 channels x 4 taps (32 consecutive floats), loaded once
  float wreg[4][8];
  #pragma unroll
  for (int j = 0; j < 8; j++) {
    float4 wa = *(const float4*)&cw[(c0 + j) * 4];
    wreg[0][j] = wa.x; wreg[1][j] = wa.y; wreg[2][j] = wa.z; wreg[3][j] = wa.w;
  }
  float4 cb0 = *(const float4*)&cb[c0];
  float4 cb1 = *(const float4*)&cb[c0 + 4];
  float bias[8] = {cb0.x, cb0.y, cb0.z, cb0.w, cb1.x, cb1.y, cb1.z, cb1.w};

  // rolling window win[i] = input row (t-3+i) for current output row t
  bf16x8 win[4];
  #pragma unroll
  for (int i = 0; i < 3; i++) {
    if (t0 - 3 + i >= 0) win[i] = *(const bf16x8*)&xpre[(r0 - 3 + i) * CONVD + c0];
    else                 win[i] = bf16x8{0,0,0,0,0,0,0,0};
  }

  #pragma unroll
  for (int k = 0; k < CROWS; k++) {
    win[3] = *(const bf16x8*)&xpre[(r0 + k) * CONVD + c0];
    float acc[8];
    #pragma unroll
    for (int j = 0; j < 8; j++) acc[j] = bias[j];
    #pragma unroll
    for (int i = 0; i < 4; i++)
      #pragma unroll
      for (int j = 0; j < 8; j++)
        acc[j] += bf2f((bf16t)win[i][j]) * wreg[i][j];
    bf16x8 o;
    #pragma unroll
    for (int j = 0; j < 8; j++) {
      float s = acc[j] / (1.f + __expf(-acc[j]));
      o[j] = (short)f2bf(s);
    }
    *(bf16x8*)&out[(r0 + k) * CONVD + c0] = o;
    win[0] = win[1]; win[1] = win[2]; win[2] = win[3];
  }
}

// ---------- per-chunk states via MFMA: cs[bid][p][n], bid=(b*NC+c)*NH+h ----------
__global__ __launch_bounds__(256) void chunk_states_kernel(
    const bf16t* __restrict__ xbc, const float* __restrict__ dt,
    const float* __restrict__ Acum, float* __restrict__ cs) {
  int bid = blockIdx.x;
  int h = bid % NH; int bc = bid / NH;
  int c = bc % NCHUNK; int b = bc / NCHUNK;
  int tid = threadIdx.x;
  int lane = tid & 63, w = tid >> 6;
  long tch = (long)b * T_ + c * CK;
  int acb = ((b * NH + h) * NCHUNK + c) * CK;
  float Alast = Acum[acb + CK - 1];

  __shared__ bf16t Xt[128][72];   // Xt[p][s]  (x * w)
  __shared__ bf16t Bt[64][72];    // Bt[n][s]
  __shared__ float wk[64];

  f32x4 acc[8] = {};
  for (int kb = 0; kb < 4; kb++) {
    int s0 = kb * 64;
    __syncthreads();
    if (tid < 64)
      wk[tid] = __expf(Alast - Acum[acb + s0 + tid]) * dt[(tch + s0 + tid) * NH + h];
    __syncthreads();
    for (int e = tid; e < 64 * 32; e += 256) {       // p4 in [0,32): all 128 p
      int s = e & 63, p4 = e >> 6;
      ushort4 u = *(const ushort4*)&xbc[(tch + s0 + s) * CONVD + h * HD + p4 * 4];
      float wv = wk[s];
      Xt[p4 * 4 + 0][s] = f2bf(bf2f(u.x) * wv);
      Xt[p4 * 4 + 1][s] = f2bf(bf2f(u.y) * wv);
      Xt[p4 * 4 + 2][s] = f2bf(bf2f(u.z) * wv);
      Xt[p4 * 4 + 3][s] = f2bf(bf2f(u.w) * wv);
    }
    for (int e = tid; e < 64 * 16; e += 256) {       // n4 in [0,16): all 64 n
      int s = e & 63, n4 = e >> 6;
      ushort4 u = *(const ushort4*)&xbc[(tch + s0 + s) * CONVD + DINNER + n4 * 4];
      Bt[n4 * 4 + 0][s] = u.x; Bt[n4 * 4 + 1][s] = u.y;
      Bt[n4 * 4 + 2][s] = u.z; Bt[n4 * 4 + 3][s] = u.w;
    }
    __syncthreads();
    #pragma unroll
    for (int ks = 0; ks < 2; ks++) {
      int koff = (lane >> 4) * 8 + ks * 32;
      bf16x8 bfr = *(bf16x8*)&Bt[w * 16 + (lane & 15)][koff];
      #pragma unroll
      for (int mi = 0; mi < 8; mi++) {
        bf16x8 af = *(bf16x8*)&Xt[mi * 16 + (lane & 15)][koff];
        acc[mi] = __builtin_amdgcn_mfma_f32_16x16x32_bf16(af, bfr, acc[mi], 0, 0, 0);
      }
    }
  }
  float* out = cs + (long)bid * HD * NSTATE;
  int n = w * 16 + (lane & 15);
  #pragma unroll
  for (int mi = 0; mi < 8; mi++) {
    #pragma unroll
    for (int r = 0; r < 4; r++) {
      int p = mi * 16 + (lane >> 4) * 4 + r;
      out[p * NSTATE + n] = acc[mi][r];
    }
  }
}

// ---------- sequential inter-chunk recurrence, IN PLACE ----------
__global__ __launch_bounds__(256) void state_pass_kernel(
    float* __restrict__ cs, const float* __restrict__ Acum) {
  int bh = blockIdx.x;                  // b*NH + h
  int b = bh / NH, h = bh % NH;
  int e0 = blockIdx.y * 1024 + threadIdx.x;
  for (int q = 0; q < 4; q++) {
    int e = e0 + q * 256;
    float s = 0.f;
    for (int c = 0; c < NCHUNK; c++) {
      long idx = ((long)(b * NCHUNK + c) * NH + h) * (HD * NSTATE) + e;
      float tmp = cs[idx];
      cs[idx] = s;
      float g = __expf(Acum[((b * NH + h) * NCHUNK + c) * CK + CK - 1]);
      s = s * g + tmp;
    }
  }
}

// ---------- SSD Y via MFMA ----------
__global__ __launch_bounds__(256) void ssd_y_kernel(
    const bf16t* __restrict__ xbc, const float* __restrict__ dt,
    const float* __restrict__ Acum, const float* __restrict__ sin_,
    const float* __restrict__ Dskip, bf16t* __restrict__ Y) {
  int bid = blockIdx.x;
  int h = bid % NH; int bc = bid / NH;
  int c = bc % NCHUNK; int b = bc / NCHUNK;
  int rt = blockIdx.y;
  int tid = threadIdx.x;
  int lane = tid & 63, w = tid >> 6;
  int wr = w >> 1, wc = w & 1;
  long tch = (long)b * T_ + c * CK;
  long tbase = tch + rt * 128;
  int acb = ((b * NH + h) * NCHUNK + c) * CK;

  __shared__ bf16t Cs[128][72];
  __shared__ bf16t Bs[64][72];
  __shared__ bf16t Xt[128][72];
  __shared__ bf16t Sm[128][72];
  __shared__ float Akl[128];
  __shared__ float Asl[64];
  __shared__ float dts[64];

  for (int e = tid; e < 128 * 8; e += 256) {
    int row = e >> 3, seg = (e & 7) * 8;
    *(bf16x8*)&Cs[row][seg] =
        *(const bf16x8*)&xbc[(tbase + row) * CONVD + DINNER + NSTATE + seg];
  }
  if (tid < 128) Akl[tid] = Acum[acb + rt * 128 + tid];

  f32x4 acc[4][4] = {};
  int nsb = 2 * (rt + 1);
  for (int sb = 0; sb < nsb; sb++) {
    int s0 = sb * 64;
    __syncthreads();
    if (tid < 64) {
      Asl[tid] = Acum[acb + s0 + tid];
      dts[tid] = dt[(tch + s0 + tid) * NH + h];
    }
    __syncthreads();
    for (int e = tid; e < 64 * 8; e += 256) {
      int row = e >> 3, seg = (e & 7) * 8;
      *(bf16x8*)&Bs[row][seg] =
          *(const bf16x8*)&xbc[(tch + s0 + row) * CONVD + DINNER + seg];
    }
    for (int e = tid; e < 64 * 32; e += 256) {       // p4 in [0,32): all 128 p
      int s = e & 63, p4 = e >> 6;
      ushort4 u = *(const ushort4*)&xbc[(tch + s0 + s) * CONVD + h * HD + p4 * 4];
      float dtv = dts[s];
      Xt[p4 * 4 + 0][s] = f2bf(bf2f(u.x) * dtv);
      Xt[p4 * 4 + 1][s] = f2bf(bf2f(u.y) * dtv);
      Xt[p4 * 4 + 2][s] = f2bf(bf2f(u.z) * dtv);
      Xt[p4 * 4 + 3][s] = f2bf(bf2f(u.w) * dtv);
    }
    __syncthreads();
    {
      f32x4 sacc[2][4] = {};
      int rw0 = w * 32;
      #pragma unroll
      for (int ks = 0; ks < 2; ks++) {
        int koff = (lane >> 4) * 8 + ks * 32;
        bf16x8 a0 = *(bf16x8*)&Cs[rw0 + (lane & 15)][koff];
        bf16x8 a1 = *(bf16x8*)&Cs[rw0 + 16 + (lane & 15)][koff];
        #pragma unroll
        for (int ni = 0; ni < 4; ni++) {
          bf16x8 bfr = *(bf16x8*)&Bs[ni * 16 + (lane & 15)][koff];
          sacc[0][ni] = __builtin_amdgcn_mfma_f32_16x16x32_bf16(a0, bfr, sacc[0][ni], 0, 0, 0);
          sacc[1][ni] = __builtin_amdgcn_mfma_f32_16x16x32_bf16(a1, bfr, sacc[1][ni], 0, 0, 0);
        }
      }
      #pragma unroll
      for (int mi = 0; mi < 2; mi++) {
        #pragma unroll
        for (int ni = 0; ni < 4; ni++) {
          #pragma unroll
          for (int r = 0; r < 4; r++) {
            int row = rw0 + mi * 16 + (lane >> 4) * 4 + r;
            int scol = ni * 16 + (lane & 15);
            int kglob = rt * 128 + row;
            int sglob = s0 + scol;
            float val = 0.f;
            if (sglob <= kglob) val = sacc[mi][ni][r] * __expf(Akl[row] - Asl[scol]);
            Sm[row][scol] = f2bf(val);
          }
        }
      }
    }
    __syncthreads();
    #pragma unroll
    for (int ks = 0; ks < 2; ks++) {
      int koff = (lane >> 4) * 8 + ks * 32;
      bf16x8 af[4], bfr[4];
      #pragma unroll
      for (int mi = 0; mi < 4; mi++) af[mi] = *(bf16x8*)&Sm[wr * 64 + mi * 16 + (lane & 15)][koff];
      #pragma unroll
      for (int ni = 0; ni < 4; ni++) bfr[ni] = *(bf16x8*)&Xt[wc * 64 + ni * 16 + (lane & 15)][koff];
      #pragma unroll
      for (int mi = 0; mi < 4; mi++)
        #pragma unroll
        for (int ni = 0; ni < 4; ni++)
          acc[mi][ni] = __builtin_amdgcn_mfma_f32_16x16x32_bf16(af[mi], bfr[ni], acc[mi][ni], 0, 0, 0);
    }
  }

  float ekr[16];
  #pragma unroll
  for (int mi = 0; mi < 4; mi++)
    #pragma unroll
    for (int r = 0; r < 4; r++)
      ekr[mi * 4 + r] = __expf(Akl[wr * 64 + mi * 16 + (lane >> 4) * 4 + r]);

  const float* sinb = sin_ + (long)bid * HD * NSTATE;
  #pragma unroll
  for (int ni = 0; ni < 4; ni++) {
    f32x4 offacc[4] = {};
    int p = wc * 64 + ni * 16 + (lane & 15);
    #pragma unroll
    for (int ks = 0; ks < 2; ks++) {
      int koff = (lane >> 4) * 8 + ks * 32;
      const float* srow = sinb + p * NSTATE + koff;
      float4 sa = *(const float4*)srow;
      float4 sbv = *(const float4*)(srow + 4);
      bf16x8 bfr;
      bfr[0] = (short)f2bf(sa.x);  bfr[1] = (short)f2bf(sa.y);
      bfr[2] = (short)f2bf(sa.z);  bfr[3] = (short)f2bf(sa.w);
      bfr[4] = (short)f2bf(sbv.x); bfr[5] = (short)f2bf(sbv.y);
      bfr[6] = (short)f2bf(sbv.z); bfr[7] = (short)f2bf(sbv.w);
      #pragma unroll
      for (int mi = 0; mi < 4; mi++) {
        bf16x8 af = *(bf16x8*)&Cs[wr * 64 + mi * 16 + (lane & 15)][koff];
        offacc[mi] = __builtin_amdgcn_mfma_f32_16x16x32_bf16(af, bfr, offacc[mi], 0, 0, 0);
      }
    }
    #pragma unroll
    for (int mi = 0; mi < 4; mi++)
      #pragma unroll
      for (int r = 0; r < 4; r++)
        acc[mi][ni][r] += ekr[mi * 4 + r] * offacc[mi][r];
  }

  float dsk = Dskip[h];
  #pragma unroll
  for (int mi = 0; mi < 4; mi++) {
    #pragma unroll
    for (int r = 0; r < 4; r++) {
      int row = wr * 64 + mi * 16 + (lane >> 4) * 4 + r;
      long t = tbase + row;
      #pragma unroll
      for (int ni = 0; ni < 4; ni++) {
        int p = wc * 64 + ni * 16 + (lane & 15);
        float xsv = bf2f(xbc[t * CONVD + h * HD + p]);
        Y[t * DINNER + h * HD + p] = f2bf(acc[mi][ni][r] + dsk * xsv);
      }
    }
  }
}

// ---------- y *= silu(z); RMSNorm * ssd_norm_w (in place on Y, bf16) ----------
__global__ __launch_bounds__(256) void gate_rms_kernel(
    const bf16t* __restrict__ z, const float* __restrict__ nw,
    bf16t* __restrict__ Y) {
  long r = blockIdx.x;
  const bf16t* zrow = z + r * DINNER;
  bf16t* yrow = Y + r * DINNER;
  int tid = threadIdx.x;
  float v[8]; float sq = 0.f;
  #pragma unroll
  for (int i = 0; i < 4; i++) {
    int d = tid * 2 + 512 * i;
    ushort2 zu = *(const ushort2*)&zrow[d];
    ushort2 yu = *(const ushort2*)&yrow[d];
    float z0 = bf2f(zu.x), z1 = bf2f(zu.y);
    float y0 = bf2f(yu.x) * (z0 / (1.f + __expf(-z0)));
    float y1 = bf2f(yu.y) * (z1 / (1.f + __expf(-z1)));
    v[2 * i] = y0; v[2 * i + 1] = y1;
    sq += y0 * y0 + y1 * y1;
  }
  float2 r2 = block_reduce2(sq, 0.f);
  float rms = rsqrtf(r2.x * (1.f / DINNER) + EPSV);
  #pragma unroll
  for (int i = 0; i < 4; i++) {
    int d = tid * 2 + 512 * i;
    ushort2 o;
    o.x = f2bf(v[2 * i] * rms * nw[d]);
    o.y = f2bf(v[2 * i + 1] * rms * nw[d + 1]);
    *(ushort2*)&yrow[d] = o;
  }
}

// ---------- residual add (last L rows) + LayerNorm3 -> bf16 ----------
__global__ __launch_bounds__(256) void res_ln3_kernel(
    const bf16t* __restrict__ mfull, const bf16t* __restrict__ x,
    const float* __restrict__ w3, const float* __restrict__ b3,
    bf16t* __restrict__ x2) {
  int rl = blockIdx.x;                  // b*L_ + tl
  int tl = rl % L_, b = rl / L_;
  long rt = (long)b * T_ + G_ + tl;
  const bf16t* m = mfull + rt * DM;
  const bf16t* xr = x + rt * DM;
  int tid = threadIdx.x;
  float v[4]; float s = 0.f, sq = 0.f;
  #pragma unroll
  for (int i = 0; i < 2; i++) {
    int d = tid * 2 + 512 * i;
    ushort2 mu2 = *(const ushort2*)&m[d];
    ushort2 xu2 = *(const ushort2*)&xr[d];
    float a0 = bf2f(mu2.x) + bf2f(xu2.x);
    float a1 = bf2f(mu2.y) + bf2f(xu2.y);
    v[2 * i] = a0; v[2 * i + 1] = a1;
    s += a0 + a1; sq += a0 * a0 + a1 * a1;
  }
  float2 r2 = block_reduce2(s, sq);
  float mu = r2.x * (1.f / DM);
  float var = r2.y * (1.f / DM) - mu * mu;
  float rstd = rsqrtf(var + EPSV);
  bf16t* dst = x2 + (long)rl * DM;
  #pragma unroll
  for (int i = 0; i < 2; i++) {
    int d = tid * 2 + 512 * i;
    ushort2 o;
    o.x = f2bf((v[2 * i] - mu) * rstd * w3[d] + b3[d]);
    o.y = f2bf((v[2 * i + 1] - mu) * rstd * w3[d + 1] + b3[d + 1]);
    *(ushort2*)&dst[d] = o;
  }
}

extern "C" void kernel_launch(void* const* d_in, const int* in_sizes, int n_in,
                              void* d_out, int out_size, void* d_ws, size_t ws_size,
                              hipStream_t stream) {
  const float* localr = (const float*)d_in[0];
  const float* globalr= (const float*)d_in[1];
  const float* n1w = (const float*)d_in[2];
  const float* n1b = (const float*)d_in[3];
  const float* n2w = (const float*)d_in[4];
  const float* n2b = (const float*)d_in[5];
  const float* n3w = (const float*)d_in[6];
  const float* n3b = (const float*)d_in[7];
  const float* inpw= (const float*)d_in[8];
  const float* convw=(const float*)d_in[9];
  const float* convb=(const float*)d_in[10];
  const float* dtb = (const float*)d_in[11];
  const float* alog= (const float*)d_in[12];
  const float* dskp= (const float*)d_in[13];
  const float* ssdw= (const float*)d_in[14];
  const float* outw= (const float*)d_in[15];
  const float* f1w = (const float*)d_in[16];
  const float* f1b = (const float*)d_in[17];
  const float* f2w = (const float*)d_in[18];
  const float* f2b = (const float*)d_in[19];

  // ---- workspace layout (byte offsets); peak = 157,483,008 B (~150 MB) ----
  char* ws = (char*)d_ws;
  bf16t* x     = (bf16t*)(ws + 0);             // 9216*1024 bf16
  bf16t* z     = (bf16t*)(ws + 18874368);      // 9216*2048 bf16
  bf16t* mfull = (bf16t*)(ws + 18874368);      //   overlay: 9216*1024 bf16 (after gate_rms)
  bf16t* xpre  = (bf16t*)(ws + 56623104);      // 9216*2176 bf16
  bf16t* Yb    = (bf16t*)(ws + 56623104);      //   overlay: 9216*2048 bf16 (after conv)
  float* dtraw = (float*)(ws + 96731136);      // 9216*16 f32
  float* dt    = (float*)(ws + 97320960);      // 9216*16 f32
  float* Acum  = (float*)(ws + 97910784);      // 64*9*256 f32
  bf16t* xbc   = (bf16t*)(ws + 98500608);      // 9216*2176 bf16
  bf16t* x2bf  = (bf16t*)(ws + 98500608);      //   overlay after ssd_y: 8192*1024 bf16
  bf16t* hbuf  = (bf16t*)(ws + 115277824);     //   overlay: 8192*512 bf16
  bf16t* outw_bf = (bf16t*)(ws + 123666432);   //   overlay: 1024*2048 bf16
  bf16t* f1w_bf  = (bf16t*)(ws + 127860736);   //   overlay: 512*1024 bf16
  bf16t* f2w_bf  = (bf16t*)(ws + 128909312);   //   overlay: 1024*512 bf16
  float* cs    = (float*)(ws + 138608640);     // 576*8192 f32
  bf16t* inpw_bf = (bf16t*)(ws + 138608640);   //   overlay BEFORE chunk_states

  cvt_inproj_kernel<<<(int)(((long)NPROJ_PAD * DM + 255) / 256), 256, 0, stream>>>(inpw, inpw_bf);

  ln_concat_kernel<<<B_ * T_, 256, 0, stream>>>(localr, globalr, n1w, n1b, n2w, n2b, x);

  gemm_mfma<0><<<dim3(NPROJ_PAD / 128, (B_ * T_) / 128), 256, 0, stream>>>(
      x, inpw_bf, nullptr, nullptr, nullptr, nullptr, z, xpre, dtraw, B_ * T_, NPROJ_PAD, DM);

  cumsum_kernel<<<B_ * NH * NCHUNK, 256, 0, stream>>>(dtraw, dtb, alog, dt, Acum);

  conv_kernel<<<(B_ * T_ / CROWS) * 272 / 256, 256, 0, stream>>>(xpre, convw, convb, xbc);

  chunk_states_kernel<<<B_ * NCHUNK * NH, 256, 0, stream>>>(xbc, dt, Acum, cs);

  state_pass_kernel<<<dim3(B_ * NH, 8), 256, 0, stream>>>(cs, Acum);

  ssd_y_kernel<<<dim3(B_ * NCHUNK * NH, 2), 256, 0, stream>>>(xbc, dt, Acum, cs, dskp, Yb);

  {
    long ntot = (long)DM * DINNER + 2L * (DM / 2) * DM;
    cvt_late_kernel<<<(int)((ntot + 255) / 256), 256, 0, stream>>>(
        outw, f1w, f2w, outw_bf, f1w_bf, f2w_bf);
  }

  gate_rms_kernel<<<B_ * T_, 256, 0, stream>>>(z, ssdw, Yb);

  gemm_mfma<1><<<dim3(DM / 128, (B_ * T_) / 128), 256, 0, stream>>>(
      Yb, outw_bf, nullptr, nullptr, nullptr, mfull, nullptr, nullptr, nullptr,
      B_ * T_, DM, DINNER);

  res_ln3_kernel<<<B_ * L_, 256, 0, stream>>>(mfull, x, n3w, n3b, x2bf);

  gemm_mfma<2><<<dim3((DM / 2) / 128, (B_ * L_) / 128), 256, 0, stream>>>(
      x2bf, f1w_bf, f1b, nullptr, nullptr, hbuf, nullptr, nullptr, nullptr,
      B_ * L_, DM / 2, DM);

  gemm_mfma<3><<<dim3(DM / 128, (B_ * L_) / 128), 256, 0, stream>>>(
      hbuf, f2w_bf, f2b, x2bf, (float*)d_out, nullptr, nullptr, nullptr, nullptr,
      B_ * L_, DM, DM / 2);
}

// Round 8
// 554.671 us; speedup vs baseline: 5.5760x; 1.0486x over previous
//
#include <hip/hip_runtime.h>
#include <math.h>

#define B_ 4
#define L_ 2048
#define G_ 256
#define T_ 2304          // G_ + L_
#define DM 1024
#define DINNER 2048
#define NH 16
#define HD 128
#define NSTATE 64
#define CONVD 2176       // DINNER + 2*NSTATE
#define DPROJ 4240       // 2*DINNER + 2*NSTATE + NH
#define NPROJ_PAD 4352   // DPROJ padded to 256
#define NCHUNK 9
#define CK 256
#define EPSV 1e-5f
#define CROWS 16         // conv rows per thread

typedef unsigned short bf16t;
using bf16x8 = __attribute__((ext_vector_type(8))) short;
using f32x4  = __attribute__((ext_vector_type(4))) float;

__device__ __forceinline__ float bf2f(bf16t u) {
  return __uint_as_float(((unsigned int)u) << 16);
}
__device__ __forceinline__ bf16t f2bf(float f) {
  unsigned int u = __float_as_uint(f);
  u += 0x7FFFu + ((u >> 16) & 1u);
  return (bf16t)(u >> 16);
}

__device__ __forceinline__ void g2lds16(const bf16t* g, short* l) {
  __builtin_amdgcn_global_load_lds(
      (const __attribute__((address_space(1))) unsigned int*)g,
      (__attribute__((address_space(3))) unsigned int*)l, 16, 0, 0);
}

// ---------- block-wide reduction of two values (blockDim == 256) ----------
__device__ __forceinline__ float2 block_reduce2(float a, float b) {
  __shared__ float sa[4], sb[4];
  #pragma unroll
  for (int off = 32; off > 0; off >>= 1) {
    a += __shfl_down(a, off, 64);
    b += __shfl_down(b, off, 64);
  }
  int lane = threadIdx.x & 63, wid = threadIdx.x >> 6;
  if (lane == 0) { sa[wid] = a; sb[wid] = b; }
  __syncthreads();
  return make_float2(sa[0] + sa[1] + sa[2] + sa[3], sb[0] + sb[1] + sb[2] + sb[3]);
}

// ---------- LN1/LN2+concat (blocks 0..9215) fused with in_proj weight cvt ----------
__global__ __launch_bounds__(256) void ln_cvt_kernel(
    const float* __restrict__ localr, const float* __restrict__ globalr,
    const float* __restrict__ w1, const float* __restrict__ b1,
    const float* __restrict__ w2, const float* __restrict__ b2,
    bf16t* __restrict__ x, const float* __restrict__ inpw,
    bf16t* __restrict__ inpw_bf) {
  int blk = blockIdx.x;
  if (blk < B_ * T_) {
    int t = blk % T_, b = blk / T_;
    const float *src, *w, *bb;
    if (t < G_) { src = globalr + ((long)b * G_ + t) * DM;        w = w2; bb = b2; }
    else        { src = localr  + ((long)b * L_ + (t - G_)) * DM; w = w1; bb = b1; }
    int d = threadIdx.x * 4;
    float4 v = *(const float4*)&src[d];
    float s = v.x + v.y + v.z + v.w;
    float sq = v.x * v.x + v.y * v.y + v.z * v.z + v.w * v.w;
    float2 r2 = block_reduce2(s, sq);
    float mu = r2.x * (1.f / DM);
    float var = r2.y * (1.f / DM) - mu * mu;
    float rstd = rsqrtf(var + EPSV);
    float4 wv = *(const float4*)&w[d];
    float4 bv = *(const float4*)&bb[d];
    ushort4 o;
    o.x = f2bf((v.x - mu) * rstd * wv.x + bv.x);
    o.y = f2bf((v.y - mu) * rstd * wv.y + bv.y);
    o.z = f2bf((v.z - mu) * rstd * wv.z + bv.z);
    o.w = f2bf((v.w - mu) * rstd * wv.w + bv.w);
    *(ushort4*)&x[(long)blk * DM + d] = o;
  } else {
    long i = (long)(blk - B_ * T_) * 1024 + threadIdx.x * 4;
    const long nreal = (long)DPROJ * DM, ntot = (long)NPROJ_PAD * DM;
    if (i < ntot) {
      ushort4 o = {0, 0, 0, 0};
      if (i < nreal) {
        float4 v = *(const float4*)&inpw[i];
        o.x = f2bf(v.x); o.y = f2bf(v.y); o.z = f2bf(v.z); o.w = f2bf(v.w);
      }
      *(ushort4*)&inpw_bf[i] = o;
    }
  }
}

// ---------- in_proj MFMA GEMM: 128(M) x 256(N) tile, 512 threads, 8 waves ----------
// epilogue: z / xpre via LDS-transpose bf16 stores; dt cols f32 direct from acc.
__global__ __launch_bounds__(512) void gemm_inproj_mfma(
    const bf16t* __restrict__ A, const bf16t* __restrict__ W,
    bf16t* __restrict__ z, bf16t* __restrict__ xpre, float* __restrict__ dtr) {
  const int K = DM;
  __shared__ __align__(16) short LDS[128 * 136];   // 34816 B
  short* As = LDS;              // [128][32]
  short* Ws = LDS + 4096;       // [256][32]
  int tid = threadIdx.x;
  int lane = tid & 63, w = tid >> 6;
  int wr = w >> 2, wc = w & 3;
  int bm = blockIdx.y * 128, bn = blockIdx.x * 256;

  const bf16t* gA  = A + (long)(bm + (tid >> 2)) * K + (tid & 3) * 8;
  const bf16t* gW1 = W + (long)(bn + (tid >> 2)) * K + (tid & 3) * 8;
  const bf16t* gW2 = W + (long)(bn + 128 + (tid >> 2)) * K + (tid & 3) * 8;
  short* lA  = As + tid * 8;
  short* lW1 = Ws + tid * 8;
  short* lW2 = Ws + (tid + 512) * 8;

  int arow = wr * 64 + (lane & 15);
  int brow = wc * 64 + (lane & 15);
  int koff = (lane >> 4) * 8;

  f32x4 acc[4][4] = {};
  for (int k0 = 0; k0 < K; k0 += 32) {
    g2lds16(gA + k0, lA);
    g2lds16(gW1 + k0, lW1);
    g2lds16(gW2 + k0, lW2);
    __syncthreads();
    bf16x8 af[4], bf[4];
    #pragma unroll
    for (int mi = 0; mi < 4; mi++) af[mi] = *(bf16x8*)&As[(arow + mi * 16) * 32 + koff];
    #pragma unroll
    for (int ni = 0; ni < 4; ni++) bf[ni] = *(bf16x8*)&Ws[(brow + ni * 16) * 32 + koff];
    #pragma unroll
    for (int mi = 0; mi < 4; mi++)
      #pragma unroll
      for (int ni = 0; ni < 4; ni++)
        acc[mi][ni] = __builtin_amdgcn_mfma_f32_16x16x32_bf16(af[mi], bf[ni], acc[mi][ni], 0, 0, 0);
    __syncthreads();
  }

  int rb = wr * 64 + (lane >> 4) * 4;
  // dt columns 4224..4239 (tile bn=4096, local cols 128..143): f32 direct
  if (bn == 4096 && wc == 2) {
    #pragma unroll
    for (int mi = 0; mi < 4; mi++)
      #pragma unroll
      for (int r = 0; r < 4; r++)
        dtr[(long)(bm + rb + mi * 16 + r) * NH + (lane & 15)] = acc[mi][0][r];
  }

  bf16t* Cs = (bf16t*)LDS;                     // [128][136]
  int cbh = (wc & 1) * 64 + (lane & 15);
  #pragma unroll
  for (int nh = 0; nh < 2; nh++) {
    __syncthreads();
    if ((wc >> 1) == nh) {
      #pragma unroll
      for (int mi = 0; mi < 4; mi++)
        #pragma unroll
        for (int ni = 0; ni < 4; ni++)
          #pragma unroll
          for (int r = 0; r < 4; r++)
            Cs[(rb + mi * 16 + r) * 136 + cbh + ni * 16] = f2bf(acc[mi][ni][r]);
    }
    __syncthreads();
    #pragma unroll
    for (int pass = 0; pass < 4; pass++) {
      int row = pass * 32 + (tid >> 4);
      int col = (tid & 15) * 8;
      int gcol = bn + nh * 128 + col;
      bf16x8 vv = *(bf16x8*)&Cs[row * 136 + col];
      long grow = bm + row;
      if (gcol < DINNER)                 *(bf16x8*)&z[grow * DINNER + gcol] = vv;
      else if (gcol < DINNER + CONVD)    *(bf16x8*)&xpre[grow * CONVD + (gcol - DINNER)] = vv;
      // dt cols handled above; pad dropped
    }
  }
}

// ---------- MFMA bf16 GEMM (128x128, 256 thr) with fused epilogues ----------
// EPI 1: Cb bf16 plain         (out_proj -> compact mfull; OFFS row remap on A)
// EPI 2: Cb bf16 gelu(v+bias)  (ffn1)
// EPI 3: Cf f32 v+bias+res     (ffn2 -> d_out)
template<int EPI, bool OFFS>
__global__ __launch_bounds__(256) void gemm_mfma(
    const bf16t* __restrict__ A, const bf16t* __restrict__ W,
    const float* __restrict__ bias, const bf16t* __restrict__ res,
    float* __restrict__ Cf, bf16t* __restrict__ Cb, int N, int K) {
  __shared__ __align__(16) short LDS[128 * 136];
  short* As = LDS;              // [128][32]
  short* Ws = LDS + 128 * 32;   // [128][32]
  int tid = threadIdx.x;
  int lane = tid & 63, w = tid >> 6;
  int wr = w >> 1, wc = w & 1;
  int bm = blockIdx.y * 128, bn = blockIdx.x * 128;
  long bmA = OFFS ? ((long)(bm >> 11) * T_ + G_ + (bm & 2047)) : (long)bm;

  int r1 = tid >> 2,         s1 = (tid & 3) * 8;
  int r2 = (tid + 256) >> 2, s2 = ((tid + 256) & 3) * 8;
  const bf16t* gA1 = A + (bmA + r1) * K + s1;
  const bf16t* gA2 = A + (bmA + r2) * K + s2;
  const bf16t* gW1 = W + (long)(bn + r1) * K + s1;
  const bf16t* gW2 = W + (long)(bn + r2) * K + s2;
  short* lA1 = As + tid * 8;
  short* lA2 = As + (tid + 256) * 8;
  short* lW1 = Ws + tid * 8;
  short* lW2 = Ws + (tid + 256) * 8;

  int arow = wr * 64 + (lane & 15);
  int brow = wc * 64 + (lane & 15);
  int koff = (lane >> 4) * 8;

  f32x4 acc[4][4] = {};
  for (int k0 = 0; k0 < K; k0 += 32) {
    g2lds16(gA1 + k0, lA1);
    g2lds16(gA2 + k0, lA2);
    g2lds16(gW1 + k0, lW1);
    g2lds16(gW2 + k0, lW2);
    __syncthreads();
    bf16x8 af[4], bf[4];
    #pragma unroll
    for (int mi = 0; mi < 4; mi++) af[mi] = *(bf16x8*)&As[(arow + mi * 16) * 32 + koff];
    #pragma unroll
    for (int ni = 0; ni < 4; ni++) bf[ni] = *(bf16x8*)&Ws[(brow + ni * 16) * 32 + koff];
    #pragma unroll
    for (int mi = 0; mi < 4; mi++)
      #pragma unroll
      for (int ni = 0; ni < 4; ni++)
        acc[mi][ni] = __builtin_amdgcn_mfma_f32_16x16x32_bf16(af[mi], bf[ni], acc[mi][ni], 0, 0, 0);
    __syncthreads();
  }

  int rb = wr * 64 + (lane >> 4) * 4;
  int cb = wc * 64 + (lane & 15);

  if (EPI == 3) {
    float* Cs32 = (float*)LDS;                 // [64][136]
    #pragma unroll
    for (int pass = 0; pass < 2; pass++) {
      __syncthreads();
      if (wr == pass) {
        #pragma unroll
        for (int mi = 0; mi < 4; mi++)
          #pragma unroll
          for (int ni = 0; ni < 4; ni++)
            #pragma unroll
            for (int r = 0; r < 4; r++) {
              int lrow = (lane >> 4) * 4 + mi * 16 + r;
              Cs32[lrow * 136 + cb + ni * 16] = acc[mi][ni][r];
            }
      }
      __syncthreads();
      #pragma unroll
      for (int q = 0; q < 4; q++) {
        int row = q * 16 + (tid >> 4);
        int col = (tid & 15) * 8;
        long grow = bm + pass * 64 + row; int gcol = bn + col;
        float4 v0 = *(float4*)&Cs32[row * 136 + col];
        float4 v1 = *(float4*)&Cs32[row * 136 + col + 4];
        float4 b0 = *(const float4*)&bias[gcol];
        float4 b1 = *(const float4*)&bias[gcol + 4];
        bf16x8 rv = *(const bf16x8*)&res[grow * N + gcol];
        v0.x += b0.x + bf2f((bf16t)rv[0]); v0.y += b0.y + bf2f((bf16t)rv[1]);
        v0.z += b0.z + bf2f((bf16t)rv[2]); v0.w += b0.w + bf2f((bf16t)rv[3]);
        v1.x += b1.x + bf2f((bf16t)rv[4]); v1.y += b1.y + bf2f((bf16t)rv[5]);
        v1.z += b1.z + bf2f((bf16t)rv[6]); v1.w += b1.w + bf2f((bf16t)rv[7]);
        *(float4*)&Cf[grow * N + gcol] = v0;
        *(float4*)&Cf[grow * N + gcol + 4] = v1;
      }
    }
    return;
  }

  __syncthreads();
  bf16t* Cs = (bf16t*)LDS;                     // [128][136]
  #pragma unroll
  for (int mi = 0; mi < 4; mi++)
    #pragma unroll
    for (int ni = 0; ni < 4; ni++)
      #pragma unroll
      for (int r = 0; r < 4; r++) {
        float v = acc[mi][ni][r];
        if (EPI == 2) {
          v += bias[bn + cb + ni * 16];
          v = 0.5f * v * (1.f + erff(v * 0.70710678118f));
        }
        Cs[(rb + mi * 16 + r) * 136 + cb + ni * 16] = f2bf(v);
      }
  __syncthreads();
  #pragma unroll
  for (int pass = 0; pass < 8; pass++) {
    int row = pass * 16 + (tid >> 4);
    int col = (tid & 15) * 8;
    bf16x8 vv = *(bf16x8*)&Cs[row * 136 + col];
    *(bf16x8*)&Cb[(long)(bm + row) * N + bn + col] = vv;
  }
}

// ---------- dt (softplus) + per-chunk inclusive cumsum of dt*A ----------
__global__ __launch_bounds__(256) void cumsum_kernel(
    const float* __restrict__ dtraw, const float* __restrict__ dt_bias,
    const float* __restrict__ A_log, float* __restrict__ dt,
    float* __restrict__ Acum) {
  int bid = blockIdx.x;                 // (b*NH+h)*NCHUNK + c
  int c = bid % NCHUNK; int hh = bid / NCHUNK;
  int h = hh % NH; int b = hh / NH;
  int k = threadIdx.x;
  float a = -__expf(A_log[h]);
  long t = (long)b * T_ + c * CK + k;
  float v0 = dtraw[t * NH + h] + dt_bias[h];
  float dtv = (v0 > 20.f) ? v0 : log1pf(__expf(v0));
  dt[t * NH + h] = dtv;
  float v = dtv * a;
  __shared__ float buf[2][CK];
  int cur = 0;
  buf[0][k] = v; __syncthreads();
  for (int off = 1; off < CK; off <<= 1) {
    float tv = buf[cur][k];
    if (k >= off) tv += buf[cur][k - off];
    buf[1 - cur][k] = tv; cur ^= 1; __syncthreads();
  }
  Acum[(long)bid * CK + k] = buf[cur][k];
}

// ---------- causal conv(4) + bias + silu: rolling window ----------
__global__ __launch_bounds__(256) void conv_kernel(
    const bf16t* __restrict__ xpre, const float* __restrict__ cw,
    const float* __restrict__ cb, bf16t* __restrict__ out) {
  int gt = blockIdx.x * 256 + threadIdx.x;    // < 576*272
  int cg = gt % 272; int rt = gt / 272;
  int c0 = cg * 8;
  long r0 = (long)rt * CROWS;
  int t0 = (int)(r0 % T_);

  float wreg[4][8];
  #pragma unroll
  for (int j = 0; j < 8; j++) {
    float4 wa = *(const float4*)&cw[(c0 + j) * 4];
    wreg[0][j] = wa.x; wreg[1][j] = wa.y; wreg[2][j] = wa.z; wreg[3][j] = wa.w;
  }
  float4 cb0 = *(const float4*)&cb[c0];
  float4 cb1 = *(const float4*)&cb[c0 + 4];
  float bias[8] = {cb0.x, cb0.y, cb0.z, cb0.w, cb1.x, cb1.y, cb1.z, cb1.w};

  bf16x8 win[4];
  #pragma unroll
  for (int i = 0; i < 3; i++) {
    if (t0 - 3 + i >= 0) win[i] = *(const bf16x8*)&xpre[(r0 - 3 + i) * CONVD + c0];
    else                 win[i] = bf16x8{0,0,0,0,0,0,0,0};
  }

  #pragma unroll
  for (int k = 0; k < CROWS; k++) {
    win[3] = *(const bf16x8*)&xpre[(r0 + k) * CONVD + c0];
    float acc[8];
    #pragma unroll
    for (int j = 0; j < 8; j++) acc[j] = bias[j];
    #pragma unroll
    for (int i = 0; i < 4; i++)
      #pragma unroll
      for (int j = 0; j < 8; j++)
        acc[j] += bf2f((bf16t)win[i][j]) * wreg[i][j];
    bf16x8 o;
    #pragma unroll
    for (int j = 0; j < 8; j++) {
      float s = acc[j] / (1.f + __expf(-acc[j]));
      o[j] = (short)f2bf(s);
    }
    *(bf16x8*)&out[(r0 + k) * CONVD + c0] = o;
    win[0] = win[1]; win[1] = win[2]; win[2] = win[3];
  }
}

// ---------- per-chunk states via MFMA (chunks 0..7 only; chunk 8 unused) ----------
__global__ __launch_bounds__(256) void chunk_states_kernel(
    const bf16t* __restrict__ xbc, const float* __restrict__ dt,
    const float* __restrict__ Acum, float* __restrict__ cs) {
  int bid = blockIdx.x;                 // 512
  int h = bid & 15; int bc = bid >> 4;
  int c = bc & 7; int b = bc >> 3;
  int tid = threadIdx.x;
  int lane = tid & 63, w = tid >> 6;
  long tch = (long)b * T_ + c * CK;
  int acb = ((b * NH + h) * NCHUNK + c) * CK;
  float Alast = Acum[acb + CK - 1];

  __shared__ bf16t Xt[128][72];
  __shared__ bf16t Bt[64][72];
  __shared__ float wk[64];

  f32x4 acc[8] = {};
  for (int kb = 0; kb < 4; kb++) {
    int s0 = kb * 64;
    __syncthreads();
    if (tid < 64)
      wk[tid] = __expf(Alast - Acum[acb + s0 + tid]) * dt[(tch + s0 + tid) * NH + h];
    __syncthreads();
    for (int e = tid; e < 64 * 32; e += 256) {
      int s = e & 63, p4 = e >> 6;
      ushort4 u = *(const ushort4*)&xbc[(tch + s0 + s) * CONVD + h * HD + p4 * 4];
      float wv = wk[s];
      Xt[p4 * 4 + 0][s] = f2bf(bf2f(u.x) * wv);
      Xt[p4 * 4 + 1][s] = f2bf(bf2f(u.y) * wv);
      Xt[p4 * 4 + 2][s] = f2bf(bf2f(u.z) * wv);
      Xt[p4 * 4 + 3][s] = f2bf(bf2f(u.w) * wv);
    }
    for (int e = tid; e < 64 * 16; e += 256) {
      int s = e & 63, n4 = e >> 6;
      ushort4 u = *(const ushort4*)&xbc[(tch + s0 + s) * CONVD + DINNER + n4 * 4];
      Bt[n4 * 4 + 0][s] = u.x; Bt[n4 * 4 + 1][s] = u.y;
      Bt[n4 * 4 + 2][s] = u.z; Bt[n4 * 4 + 3][s] = u.w;
    }
    __syncthreads();
    #pragma unroll
    for (int ks = 0; ks < 2; ks++) {
      int koff = (lane >> 4) * 8 + ks * 32;
      bf16x8 bfr = *(bf16x8*)&Bt[w * 16 + (lane & 15)][koff];
      #pragma unroll
      for (int mi = 0; mi < 8; mi++) {
        bf16x8 af = *(bf16x8*)&Xt[mi * 16 + (lane & 15)][koff];
        acc[mi] = __builtin_amdgcn_mfma_f32_16x16x32_bf16(af, bfr, acc[mi], 0, 0, 0);
      }
    }
  }
  int cbid = (b * NCHUNK + c) * NH + h;
  float* out = cs + (long)cbid * HD * NSTATE;
  int n = w * 16 + (lane & 15);
  #pragma unroll
  for (int mi = 0; mi < 8; mi++) {
    #pragma unroll
    for (int r = 0; r < 4; r++) {
      int p = mi * 16 + (lane >> 4) * 4 + r;
      out[p * NSTATE + n] = acc[mi][r];
    }
  }
}

// ---------- sequential inter-chunk recurrence, IN PLACE ----------
__global__ __launch_bounds__(256) void state_pass_kernel(
    float* __restrict__ cs, const float* __restrict__ Acum) {
  int bh = blockIdx.x;                  // b*NH + h
  int b = bh / NH, h = bh % NH;
  int e0 = blockIdx.y * 1024 + threadIdx.x;
  for (int q = 0; q < 4; q++) {
    int e = e0 + q * 256;
    float s = 0.f;
    for (int c = 0; c < NCHUNK; c++) {
      long idx = ((long)(b * NCHUNK + c) * NH + h) * (HD * NSTATE) + e;
      if (c < NCHUNK - 1) {
        float tmp = cs[idx];
        cs[idx] = s;
        float g = __expf(Acum[((b * NH + h) * NCHUNK + c) * CK + CK - 1]);
        s = s * g + tmp;
      } else {
        cs[idx] = s;
      }
    }
  }
}

// ---------- SSD Y via MFMA (chunks 1..8; chunk 0's Y is discarded downstream) ----------
__global__ __launch_bounds__(256) void ssd_y_kernel(
    const bf16t* __restrict__ xbc, const float* __restrict__ dt,
    const float* __restrict__ Acum, const float* __restrict__ sin_,
    const float* __restrict__ Dskip, bf16t* __restrict__ Y) {
  int bid = blockIdx.x;                 // 512
  int h = bid & 15; int bc = bid >> 4;
  int c = 1 + (bc & 7); int b = bc >> 3;
  int rt = blockIdx.y;
  int tid = threadIdx.x;
  int lane = tid & 63, w = tid >> 6;
  int wr = w >> 1, wc = w & 1;
  long tch = (long)b * T_ + c * CK;
  long tbase = tch + rt * 128;
  int acb = ((b * NH + h) * NCHUNK + c) * CK;

  __shared__ bf16t Cs[128][72];
  __shared__ bf16t Bs[64][72];
  __shared__ bf16t Xt[128][72];
  __shared__ bf16t Sm[128][72];
  __shared__ float Akl[128];
  __shared__ float Asl[64];
  __shared__ float dts[64];

  for (int e = tid; e < 128 * 8; e += 256) {
    int row = e >> 3, seg = (e & 7) * 8;
    *(bf16x8*)&Cs[row][seg] =
        *(const bf16x8*)&xbc[(tbase + row) * CONVD + DINNER + NSTATE + seg];
  }
  if (tid < 128) Akl[tid] = Acum[acb + rt * 128 + tid];

  f32x4 acc[4][4] = {};
  int nsb = 2 * (rt + 1);
  for (int sb = 0; sb < nsb; sb++) {
    int s0 = sb * 64;
    __syncthreads();
    if (tid < 64) {
      Asl[tid] = Acum[acb + s0 + tid];
      dts[tid] = dt[(tch + s0 + tid) * NH + h];
    }
    __syncthreads();
    for (int e = tid; e < 64 * 8; e += 256) {
      int row = e >> 3, seg = (e & 7) * 8;
      *(bf16x8*)&Bs[row][seg] =
          *(const bf16x8*)&xbc[(tch + s0 + row) * CONVD + DINNER + seg];
    }
    for (int e = tid; e < 64 * 32; e += 256) {
      int s = e & 63, p4 = e >> 6;
      ushort4 u = *(const ushort4*)&xbc[(tch + s0 + s) * CONVD + h * HD + p4 * 4];
      float dtv = dts[s];
      Xt[p4 * 4 + 0][s] = f2bf(bf2f(u.x) * dtv);
      Xt[p4 * 4 + 1][s] = f2bf(bf2f(u.y) * dtv);
      Xt[p4 * 4 + 2][s] = f2bf(bf2f(u.z) * dtv);
      Xt[p4 * 4 + 3][s] = f2bf(bf2f(u.w) * dtv);
    }
    __syncthreads();
    {
      f32x4 sacc[2][4] = {};
      int rw0 = w * 32;
      #pragma unroll
      for (int ks = 0; ks < 2; ks++) {
        int koff = (lane >> 4) * 8 + ks * 32;
        bf16x8 a0 = *(bf16x8*)&Cs[rw0 + (lane & 15)][koff];
        bf16x8 a1 = *(bf16x8*)&Cs[rw0 + 16 + (lane & 15)][koff];
        #pragma unroll
        for (int ni = 0; ni < 4; ni++) {
          bf16x8 bfr = *(bf16x8*)&Bs[ni * 16 + (lane & 15)][koff];
          sacc[0][ni] = __builtin_amdgcn_mfma_f32_16x16x32_bf16(a0, bfr, sacc[0][ni], 0, 0, 0);
          sacc[1][ni] = __builtin_amdgcn_mfma_f32_16x16x32_bf16(a1, bfr, sacc[1][ni], 0, 0, 0);
        }
      }
      #pragma unroll
      for (int mi = 0; mi < 2; mi++) {
        #pragma unroll
        for (int ni = 0; ni < 4; ni++) {
          #pragma unroll
          for (int r = 0; r < 4; r++) {
            int row = rw0 + mi * 16 + (lane >> 4) * 4 + r;
            int scol = ni * 16 + (lane & 15);
            int kglob = rt * 128 + row;
            int sglob = s0 + scol;
            float val = 0.f;
            if (sglob <= kglob) val = sacc[mi][ni][r] * __expf(Akl[row] - Asl[scol]);
            Sm[row][scol] = f2bf(val);
          }
        }
      }
    }
    __syncthreads();
    #pragma unroll
    for (int ks = 0; ks < 2; ks++) {
      int koff = (lane >> 4) * 8 + ks * 32;
      bf16x8 af[4], bfr[4];
      #pragma unroll
      for (int mi = 0; mi < 4; mi++) af[mi] = *(bf16x8*)&Sm[wr * 64 + mi * 16 + (lane & 15)][koff];
      #pragma unroll
      for (int ni = 0; ni < 4; ni++) bfr[ni] = *(bf16x8*)&Xt[wc * 64 + ni * 16 + (lane & 15)][koff];
      #pragma unroll
      for (int mi = 0; mi < 4; mi++)
        #pragma unroll
        for (int ni = 0; ni < 4; ni++)
          acc[mi][ni] = __builtin_amdgcn_mfma_f32_16x16x32_bf16(af[mi], bfr[ni], acc[mi][ni], 0, 0, 0);
    }
  }

  float ekr[16];
  #pragma unroll
  for (int mi = 0; mi < 4; mi++)
    #pragma unroll
    for (int r = 0; r < 4; r++)
      ekr[mi * 4 + r] = __expf(Akl[wr * 64 + mi * 16 + (lane >> 4) * 4 + r]);

  int cbid = (b * NCHUNK + c) * NH + h;
  const float* sinb = sin_ + (long)cbid * HD * NSTATE;
  #pragma unroll
  for (int ni = 0; ni < 4; ni++) {
    f32x4 offacc[4] = {};
    int p = wc * 64 + ni * 16 + (lane & 15);
    #pragma unroll
    for (int ks = 0; ks < 2; ks++) {
      int koff = (lane >> 4) * 8 + ks * 32;
      const float* srow = sinb + p * NSTATE + koff;
      float4 sa = *(const float4*)srow;
      float4 sbv = *(const float4*)(srow + 4);
      bf16x8 bfr;
      bfr[0] = (short)f2bf(sa.x);  bfr[1] = (short)f2bf(sa.y);
      bfr[2] = (short)f2bf(sa.z);  bfr[3] = (short)f2bf(sa.w);
      bfr[4] = (short)f2bf(sbv.x); bfr[5] = (short)f2bf(sbv.y);
      bfr[6] = (short)f2bf(sbv.z); bfr[7] = (short)f2bf(sbv.w);
      #pragma unroll
      for (int mi = 0; mi < 4; mi++) {
        bf16x8 af = *(bf16x8*)&Cs[wr * 64 + mi * 16 + (lane & 15)][koff];
        offacc[mi] = __builtin_amdgcn_mfma_f32_16x16x32_bf16(af, bfr, offacc[mi], 0, 0, 0);
      }
    }
    #pragma unroll
    for (int mi = 0; mi < 4; mi++)
      #pragma unroll
      for (int r = 0; r < 4; r++)
        acc[mi][ni][r] += ekr[mi * 4 + r] * offacc[mi][r];
  }

  float dsk = Dskip[h];
  #pragma unroll
  for (int mi = 0; mi < 4; mi++) {
    #pragma unroll
    for (int r = 0; r < 4; r++) {
      int row = wr * 64 + mi * 16 + (lane >> 4) * 4 + r;
      long t = tbase + row;
      #pragma unroll
      for (int ni = 0; ni < 4; ni++) {
        int p = wc * 64 + ni * 16 + (lane & 15);
        float xsv = bf2f(xbc[t * CONVD + h * HD + p]);
        Y[t * DINNER + h * HD + p] = f2bf(acc[mi][ni][r] + dsk * xsv);
      }
    }
  }
}

// ---------- gate+RMSNorm (local rows only) fused with late weight cvt ----------
__global__ __launch_bounds__(256) void gate_rms_cvt_kernel(
    const bf16t* __restrict__ z, const float* __restrict__ nw,
    bf16t* __restrict__ Y,
    const float* __restrict__ outw, const float* __restrict__ f1w,
    const float* __restrict__ f2w, bf16t* __restrict__ o_out,
    bf16t* __restrict__ o_f1, bf16t* __restrict__ o_f2) {
  int blk = blockIdx.x;
  if (blk < B_ * L_) {
    long r = (long)(blk >> 11) * T_ + G_ + (blk & 2047);
    const bf16t* zrow = z + r * DINNER;
    bf16t* yrow = Y + r * DINNER;
    int tid = threadIdx.x;
    float v[8]; float sq = 0.f;
    #pragma unroll
    for (int i = 0; i < 4; i++) {
      int d = tid * 2 + 512 * i;
      ushort2 zu = *(const ushort2*)&zrow[d];
      ushort2 yu = *(const ushort2*)&yrow[d];
      float z0 = bf2f(zu.x), z1 = bf2f(zu.y);
      float y0 = bf2f(yu.x) * (z0 / (1.f + __expf(-z0)));
      float y1 = bf2f(yu.y) * (z1 / (1.f + __expf(-z1)));
      v[2 * i] = y0; v[2 * i + 1] = y1;
      sq += y0 * y0 + y1 * y1;
    }
    float2 r2 = block_reduce2(sq, 0.f);
    float rms = rsqrtf(r2.x * (1.f / DINNER) + EPSV);
    #pragma unroll
    for (int i = 0; i < 4; i++) {
      int d = tid * 2 + 512 * i;
      ushort2 o;
      o.x = f2bf(v[2 * i] * rms * nw[d]);
      o.y = f2bf(v[2 * i + 1] * rms * nw[d + 1]);
      *(ushort2*)&yrow[d] = o;
    }
  } else {
    long i = (long)(blk - B_ * L_) * 1024 + threadIdx.x * 4;
    const long n1 = (long)DM * DINNER;          // 2097152
    const long n2 = (long)(DM / 2) * DM;        // 524288
    const float* src; bf16t* dst; long off;
    if (i < n1) { src = outw; dst = o_out; off = i; }
    else if (i < n1 + n2) { src = f1w; dst = o_f1; off = i - n1; }
    else { src = f2w; dst = o_f2; off = i - n1 - n2; }
    float4 v = *(const float4*)&src[off];
    ushort4 o;
    o.x = f2bf(v.x); o.y = f2bf(v.y); o.z = f2bf(v.z); o.w = f2bf(v.w);
    *(ushort4*)&dst[off] = o;
  }
}

// ---------- residual add + LayerNorm3 -> bf16 (mfull compact [8192][1024]) ----------
__global__ __launch_bounds__(256) void res_ln3_kernel(
    const bf16t* __restrict__ mfull, const bf16t* __restrict__ x,
    const float* __restrict__ w3, const float* __restrict__ b3,
    bf16t* __restrict__ x2) {
  int rl = blockIdx.x;                  // b*L_ + tl
  int tl = rl & 2047, b = rl >> 11;
  long rt = (long)b * T_ + G_ + tl;
  const bf16t* m = mfull + (long)rl * DM;
  const bf16t* xr = x + rt * DM;
  int tid = threadIdx.x;
  float v[4]; float s = 0.f, sq = 0.f;
  #pragma unroll
  for (int i = 0; i < 2; i++) {
    int d = tid * 2 + 512 * i;
    ushort2 mu2 = *(const ushort2*)&m[d];
    ushort2 xu2 = *(const ushort2*)&xr[d];
    float a0 = bf2f(mu2.x) + bf2f(xu2.x);
    float a1 = bf2f(mu2.y) + bf2f(xu2.y);
    v[2 * i] = a0; v[2 * i + 1] = a1;
    s += a0 + a1; sq += a0 * a0 + a1 * a1;
  }
  float2 r2 = block_reduce2(s, sq);
  float mu = r2.x * (1.f / DM);
  float var = r2.y * (1.f / DM) - mu * mu;
  float rstd = rsqrtf(var + EPSV);
  bf16t* dst = x2 + (long)rl * DM;
  #pragma unroll
  for (int i = 0; i < 2; i++) {
    int d = tid * 2 + 512 * i;
    ushort2 o;
    o.x = f2bf((v[2 * i] - mu) * rstd * w3[d] + b3[d]);
    o.y = f2bf((v[2 * i + 1] - mu) * rstd * w3[d + 1] + b3[d + 1]);
    *(ushort2*)&dst[d] = o;
  }
}

extern "C" void kernel_launch(void* const* d_in, const int* in_sizes, int n_in,
                              void* d_out, int out_size, void* d_ws, size_t ws_size,
                              hipStream_t stream) {
  const float* localr = (const float*)d_in[0];
  const float* globalr= (const float*)d_in[1];
  const float* n1w = (const float*)d_in[2];
  const float* n1b = (const float*)d_in[3];
  const float* n2w = (const float*)d_in[4];
  const float* n2b = (const float*)d_in[5];
  const float* n3w = (const float*)d_in[6];
  const float* n3b = (const float*)d_in[7];
  const float* inpw= (const float*)d_in[8];
  const float* convw=(const float*)d_in[9];
  const float* convb=(const float*)d_in[10];
  const float* dtb = (const float*)d_in[11];
  const float* alog= (const float*)d_in[12];
  const float* dskp= (const float*)d_in[13];
  const float* ssdw= (const float*)d_in[14];
  const float* outw= (const float*)d_in[15];
  const float* f1w = (const float*)d_in[16];
  const float* f1b = (const float*)d_in[17];
  const float* f2w = (const float*)d_in[18];
  const float* f2b = (const float*)d_in[19];

  // ---- workspace layout (byte offsets); peak ~150 MB ----
  char* ws = (char*)d_ws;
  bf16t* x     = (bf16t*)(ws + 0);             // 9216*1024 bf16
  bf16t* z     = (bf16t*)(ws + 18874368);      // 9216*2048 bf16
  bf16t* mfull = (bf16t*)(ws + 18874368);      //   overlay: 8192*1024 bf16 compact
  bf16t* xpre  = (bf16t*)(ws + 56623104);      // 9216*2176 bf16
  bf16t* Yb    = (bf16t*)(ws + 56623104);      //   overlay: 9216*2048 bf16 (after conv)
  float* dtraw = (float*)(ws + 96731136);      // 9216*16 f32
  float* dt    = (float*)(ws + 97320960);      // 9216*16 f32
  float* Acum  = (float*)(ws + 97910784);      // 64*9*256 f32
  bf16t* xbc   = (bf16t*)(ws + 98500608);      // 9216*2176 bf16
  bf16t* x2bf  = (bf16t*)(ws + 98500608);      //   overlay after ssd_y: 8192*1024 bf16
  bf16t* hbuf  = (bf16t*)(ws + 115277824);     //   overlay: 8192*512 bf16
  bf16t* outw_bf = (bf16t*)(ws + 123666432);   //   overlay: 1024*2048 bf16
  bf16t* f1w_bf  = (bf16t*)(ws + 127860736);   //   overlay: 512*1024 bf16
  bf16t* f2w_bf  = (bf16t*)(ws + 128909312);   //   overlay: 1024*512 bf16
  float* cs    = (float*)(ws + 138608640);     // 576*8192 f32
  bf16t* inpw_bf = (bf16t*)(ws + 138608640);   //   overlay BEFORE chunk_states

  ln_cvt_kernel<<<B_ * T_ + 4352, 256, 0, stream>>>(
      localr, globalr, n1w, n1b, n2w, n2b, x, inpw, inpw_bf);

  gemm_inproj_mfma<<<dim3(NPROJ_PAD / 256, (B_ * T_) / 128), 512, 0, stream>>>(
      x, inpw_bf, z, xpre, dtraw);

  cumsum_kernel<<<B_ * NH * NCHUNK, 256, 0, stream>>>(dtraw, dtb, alog, dt, Acum);

  conv_kernel<<<(B_ * T_ / CROWS) * 272 / 256, 256, 0, stream>>>(xpre, convw, convb, xbc);

  chunk_states_kernel<<<B_ * (NCHUNK - 1) * NH, 256, 0, stream>>>(xbc, dt, Acum, cs);

  state_pass_kernel<<<dim3(B_ * NH, 8), 256, 0, stream>>>(cs, Acum);

  ssd_y_kernel<<<dim3(B_ * (NCHUNK - 1) * NH, 2), 256, 0, stream>>>(
      xbc, dt, Acum, cs, dskp, Yb);

  gate_rms_cvt_kernel<<<B_ * L_ + 3072, 256, 0, stream>>>(
      z, ssdw, Yb, outw, f1w, f2w, outw_bf, f1w_bf, f2w_bf);

  gemm_mfma<1, true><<<dim3(DM / 128, (B_ * L_) / 128), 256, 0, stream>>>(
      Yb, outw_bf, nullptr, nullptr, nullptr, mfull, DM, DINNER);

  res_ln3_kernel<<<B_ * L_, 256, 0, stream>>>(mfull, x, n3w, n3b, x2bf);

  gemm_mfma<2, false><<<dim3((DM / 2) / 128, (B_ * L_) / 128), 256, 0, stream>>>(
      x2bf, f1w_bf, f1b, nullptr, nullptr, hbuf, DM / 2, DM);

  gemm_mfma<3, false><<<dim3(DM / 128, (B_ * L_) / 128), 256, 0, stream>>>(
      hbuf, f2w_bf, f2b, x2bf, (float*)d_out, nullptr, DM, DM / 2);
}

// Round 9
// 533.154 us; speedup vs baseline: 5.8010x; 1.0404x over previous
//
#include <hip/hip_runtime.h>
#include <math.h>

#define B_ 4
#define L_ 2048
#define G_ 256
#define T_ 2304          // G_ + L_
#define DM 1024
#define DINNER 2048
#define NH 16
#define HD 128
#define NSTATE 64
#define CONVD 2176       // DINNER + 2*NSTATE
#define DPROJ 4240       // 2*DINNER + 2*NSTATE + NH
#define NPROJ_PAD 4352   // DPROJ padded to 128
#define NCHUNK 9
#define CK 256
#define EPSV 1e-5f
#define CROWS 16         // conv rows per thread

typedef unsigned short bf16t;
using bf16x8 = __attribute__((ext_vector_type(8))) short;
using f32x4  = __attribute__((ext_vector_type(4))) float;

__device__ __forceinline__ float bf2f(bf16t u) {
  return __uint_as_float(((unsigned int)u) << 16);
}
__device__ __forceinline__ bf16t f2bf(float f) {
  unsigned int u = __float_as_uint(f);
  u += 0x7FFFu + ((u >> 16) & 1u);
  return (bf16t)(u >> 16);
}

__device__ __forceinline__ void g2lds16(const bf16t* g, short* l) {
  __builtin_amdgcn_global_load_lds(
      (const __attribute__((address_space(1))) unsigned int*)g,
      (__attribute__((address_space(3))) unsigned int*)l, 16, 0, 0);
}

// ---------- block-wide reduction of two values (blockDim == 256) ----------
__device__ __forceinline__ float2 block_reduce2(float a, float b) {
  __shared__ float sa[4], sb[4];
  #pragma unroll
  for (int off = 32; off > 0; off >>= 1) {
    a += __shfl_down(a, off, 64);
    b += __shfl_down(b, off, 64);
  }
  int lane = threadIdx.x & 63, wid = threadIdx.x >> 6;
  if (lane == 0) { sa[wid] = a; sb[wid] = b; }
  __syncthreads();
  return make_float2(sa[0] + sa[1] + sa[2] + sa[3], sb[0] + sb[1] + sb[2] + sb[3]);
}

// ---------- LN1/LN2+concat (blocks 0..9215) fused with in_proj weight cvt ----------
__global__ __launch_bounds__(256) void ln_cvt_kernel(
    const float* __restrict__ localr, const float* __restrict__ globalr,
    const float* __restrict__ w1, const float* __restrict__ b1,
    const float* __restrict__ w2, const float* __restrict__ b2,
    bf16t* __restrict__ x, const float* __restrict__ inpw,
    bf16t* __restrict__ inpw_bf) {
  int blk = blockIdx.x;
  if (blk < B_ * T_) {
    int t = blk % T_, b = blk / T_;
    const float *src, *w, *bb;
    if (t < G_) { src = globalr + ((long)b * G_ + t) * DM;        w = w2; bb = b2; }
    else        { src = localr  + ((long)b * L_ + (t - G_)) * DM; w = w1; bb = b1; }
    int d = threadIdx.x * 4;
    float4 v = *(const float4*)&src[d];
    float s = v.x + v.y + v.z + v.w;
    float sq = v.x * v.x + v.y * v.y + v.z * v.z + v.w * v.w;
    float2 r2 = block_reduce2(s, sq);
    float mu = r2.x * (1.f / DM);
    float var = r2.y * (1.f / DM) - mu * mu;
    float rstd = rsqrtf(var + EPSV);
    float4 wv = *(const float4*)&w[d];
    float4 bv = *(const float4*)&bb[d];
    ushort4 o;
    o.x = f2bf((v.x - mu) * rstd * wv.x + bv.x);
    o.y = f2bf((v.y - mu) * rstd * wv.y + bv.y);
    o.z = f2bf((v.z - mu) * rstd * wv.z + bv.z);
    o.w = f2bf((v.w - mu) * rstd * wv.w + bv.w);
    *(ushort4*)&x[(long)blk * DM + d] = o;
  } else {
    long i = (long)(blk - B_ * T_) * 1024 + threadIdx.x * 4;
    const long nreal = (long)DPROJ * DM, ntot = (long)NPROJ_PAD * DM;
    if (i < ntot) {
      ushort4 o = {0, 0, 0, 0};
      if (i < nreal) {
        float4 v = *(const float4*)&inpw[i];
        o.x = f2bf(v.x); o.y = f2bf(v.y); o.z = f2bf(v.z); o.w = f2bf(v.w);
      }
      *(ushort4*)&inpw_bf[i] = o;
    }
  }
}

// ---------- MFMA bf16 GEMM 128x128, bank-conflict-free via XOR source swizzle ----------
// EPI 0: route -> z / xpre; dt block scalar f32            (in_proj)
// EPI 1: Cb bf16 plain       (out_proj -> compact mfull; OFFS row remap on A)
// EPI 2: Cb bf16 gelu(v+bias)                              (ffn1)
// EPI 3: Cf f32 v+bias+res                                 (ffn2 -> d_out)
template<int EPI, bool OFFS>
__global__ __launch_bounds__(256) void gemm_mfma(
    const bf16t* __restrict__ A, const bf16t* __restrict__ W,
    const float* __restrict__ bias, const bf16t* __restrict__ res,
    float* __restrict__ Cf, bf16t* __restrict__ Cb,
    bf16t* __restrict__ z, bf16t* __restrict__ xpre, float* __restrict__ dtr,
    int N, int K) {
  __shared__ __align__(16) short LDS[128 * 136];
  short* As = LDS;              // [128][32] (columns source-swizzled per row)
  short* Ws = LDS + 128 * 32;   // [128][32]
  int tid = threadIdx.x;
  int lane = tid & 63, w = tid >> 6;
  int wr = w >> 1, wc = w & 1;
  int bm = blockIdx.y * 128, bn = blockIdx.x * 128;
  long bmA = OFFS ? ((long)(bm >> 11) * T_ + G_ + (bm & 2047)) : (long)bm;

  // staging: row r gets its 32 columns permuted by colgroup ^= (r>>1)&3;
  // keeps 64B-line coalescing, makes K-loop ds_read_b128 2-way (free).
  int r1 = tid >> 2,         s1 = (((tid & 3) ^ ((r1 >> 1) & 3))) * 8;
  int r2 = (tid + 256) >> 2, s2 = (((tid & 3) ^ ((r2 >> 1) & 3))) * 8;
  const bf16t* gA1 = A + (bmA + r1) * K + s1;
  const bf16t* gA2 = A + (bmA + r2) * K + s2;
  const bf16t* gW1 = W + (long)(bn + r1) * K + s1;
  const bf16t* gW2 = W + (long)(bn + r2) * K + s2;
  short* lA1 = As + tid * 8;
  short* lA2 = As + (tid + 256) * 8;
  short* lW1 = Ws + tid * 8;
  short* lW2 = Ws + (tid + 256) * 8;

  int arow = wr * 64 + (lane & 15);
  int brow = wc * 64 + (lane & 15);
  // read-side XOR correction; uniform across mi/ni since (row>>1)&3 == ((lane&15)>>1)&3
  int koff = (((lane >> 4) ^ (((lane & 15) >> 1) & 3))) * 8;

  f32x4 acc[4][4] = {};
  for (int k0 = 0; k0 < K; k0 += 32) {
    g2lds16(gA1 + k0, lA1);
    g2lds16(gA2 + k0, lA2);
    g2lds16(gW1 + k0, lW1);
    g2lds16(gW2 + k0, lW2);
    __syncthreads();
    bf16x8 af[4], bf[4];
    #pragma unroll
    for (int mi = 0; mi < 4; mi++) af[mi] = *(bf16x8*)&As[(arow + mi * 16) * 32 + koff];
    #pragma unroll
    for (int ni = 0; ni < 4; ni++) bf[ni] = *(bf16x8*)&Ws[(brow + ni * 16) * 32 + koff];
    #pragma unroll
    for (int mi = 0; mi < 4; mi++)
      #pragma unroll
      for (int ni = 0; ni < 4; ni++)
        acc[mi][ni] = __builtin_amdgcn_mfma_f32_16x16x32_bf16(af[mi], bf[ni], acc[mi][ni], 0, 0, 0);
    __syncthreads();
  }

  int rb = wr * 64 + (lane >> 4) * 4;
  int cb = wc * 64 + (lane & 15);

  // in_proj dt tile (bn == 4224): only first 16 cols real, f32 scalar path
  if (EPI == 0 && bn >= DINNER + CONVD) {
    #pragma unroll
    for (int mi = 0; mi < 4; mi++)
      #pragma unroll
      for (int ni = 0; ni < 4; ni++)
        #pragma unroll
        for (int r = 0; r < 4; r++) {
          int col = cb + ni * 16;
          if (col < NH)
            dtr[(long)(bm + rb + mi * 16 + r) * NH + col] = acc[mi][ni][r];
        }
    return;
  }

  if (EPI == 3) {
    float* Cs32 = (float*)LDS;                 // [64][136]
    #pragma unroll
    for (int pass = 0; pass < 2; pass++) {
      __syncthreads();
      if (wr == pass) {
        #pragma unroll
        for (int mi = 0; mi < 4; mi++)
          #pragma unroll
          for (int ni = 0; ni < 4; ni++)
            #pragma unroll
            for (int r = 0; r < 4; r++) {
              int lrow = (lane >> 4) * 4 + mi * 16 + r;
              Cs32[lrow * 136 + cb + ni * 16] = acc[mi][ni][r];
            }
      }
      __syncthreads();
      #pragma unroll
      for (int q = 0; q < 4; q++) {
        int row = q * 16 + (tid >> 4);
        int col = (tid & 15) * 8;
        long grow = bm + pass * 64 + row; int gcol = bn + col;
        float4 v0 = *(float4*)&Cs32[row * 136 + col];
        float4 v1 = *(float4*)&Cs32[row * 136 + col + 4];
        float4 b0 = *(const float4*)&bias[gcol];
        float4 b1 = *(const float4*)&bias[gcol + 4];
        bf16x8 rv = *(const bf16x8*)&res[grow * N + gcol];
        v0.x += b0.x + bf2f((bf16t)rv[0]); v0.y += b0.y + bf2f((bf16t)rv[1]);
        v0.z += b0.z + bf2f((bf16t)rv[2]); v0.w += b0.w + bf2f((bf16t)rv[3]);
        v1.x += b1.x + bf2f((bf16t)rv[4]); v1.y += b1.y + bf2f((bf16t)rv[5]);
        v1.z += b1.z + bf2f((bf16t)rv[6]); v1.w += b1.w + bf2f((bf16t)rv[7]);
        *(float4*)&Cf[grow * N + gcol] = v0;
        *(float4*)&Cf[grow * N + gcol + 4] = v1;
      }
    }
    return;
  }

  __syncthreads();
  bf16t* Cs = (bf16t*)LDS;                     // [128][136]
  #pragma unroll
  for (int mi = 0; mi < 4; mi++)
    #pragma unroll
    for (int ni = 0; ni < 4; ni++)
      #pragma unroll
      for (int r = 0; r < 4; r++) {
        float v = acc[mi][ni][r];
        if (EPI == 2) {
          v += bias[bn + cb + ni * 16];
          v = 0.5f * v * (1.f + erff(v * 0.70710678118f));
        }
        Cs[(rb + mi * 16 + r) * 136 + cb + ni * 16] = f2bf(v);
      }
  __syncthreads();
  #pragma unroll
  for (int pass = 0; pass < 8; pass++) {
    int row = pass * 16 + (tid >> 4);
    int col = (tid & 15) * 8;
    bf16x8 vv = *(bf16x8*)&Cs[row * 136 + col];
    long grow = bm + row; int gcol = bn + col;
    if (EPI == 0) {
      if (bn < DINNER) *(bf16x8*)&z[grow * DINNER + gcol] = vv;
      else             *(bf16x8*)&xpre[grow * CONVD + (gcol - DINNER)] = vv;
    } else {
      *(bf16x8*)&Cb[grow * N + gcol] = vv;
    }
  }
}

// ---------- dt (softplus) + per-chunk inclusive cumsum of dt*A ----------
__global__ __launch_bounds__(256) void cumsum_kernel(
    const float* __restrict__ dtraw, const float* __restrict__ dt_bias,
    const float* __restrict__ A_log, float* __restrict__ dt,
    float* __restrict__ Acum) {
  int bid = blockIdx.x;                 // (b*NH+h)*NCHUNK + c
  int c = bid % NCHUNK; int hh = bid / NCHUNK;
  int h = hh % NH; int b = hh / NH;
  int k = threadIdx.x;
  float a = -__expf(A_log[h]);
  long t = (long)b * T_ + c * CK + k;
  float v0 = dtraw[t * NH + h] + dt_bias[h];
  float dtv = (v0 > 20.f) ? v0 : log1pf(__expf(v0));
  dt[t * NH + h] = dtv;
  float v = dtv * a;
  __shared__ float buf[2][CK];
  int cur = 0;
  buf[0][k] = v; __syncthreads();
  for (int off = 1; off < CK; off <<= 1) {
    float tv = buf[cur][k];
    if (k >= off) tv += buf[cur][k - off];
    buf[1 - cur][k] = tv; cur ^= 1; __syncthreads();
  }
  Acum[(long)bid * CK + k] = buf[cur][k];
}

// ---------- causal conv(4) + bias + silu: rolling window ----------
__global__ __launch_bounds__(256) void conv_kernel(
    const bf16t* __restrict__ xpre, const float* __restrict__ cw,
    const float* __restrict__ cb, bf16t* __restrict__ out) {
  int gt = blockIdx.x * 256 + threadIdx.x;    // < 576*272
  int cg = gt % 272; int rt = gt / 272;
  int c0 = cg * 8;
  long r0 = (long)rt * CROWS;
  int t0 = (int)(r0 % T_);

  float wreg[4][8];
  #pragma unroll
  for (int j = 0; j < 8; j++) {
    float4 wa = *(const float4*)&cw[(c0 + j) * 4];
    wreg[0][j] = wa.x; wreg[1][j] = wa.y; wreg[2][j] = wa.z; wreg[3][j] = wa.w;
  }
  float4 cb0 = *(const float4*)&cb[c0];
  float4 cb1 = *(const float4*)&cb[c0 + 4];
  float bias[8] = {cb0.x, cb0.y, cb0.z, cb0.w, cb1.x, cb1.y, cb1.z, cb1.w};

  bf16x8 win[4];
  #pragma unroll
  for (int i = 0; i < 3; i++) {
    if (t0 - 3 + i >= 0) win[i] = *(const bf16x8*)&xpre[(r0 - 3 + i) * CONVD + c0];
    else                 win[i] = bf16x8{0,0,0,0,0,0,0,0};
  }

  #pragma unroll
  for (int k = 0; k < CROWS; k++) {
    win[3] = *(const bf16x8*)&xpre[(r0 + k) * CONVD + c0];
    float acc[8];
    #pragma unroll
    for (int j = 0; j < 8; j++) acc[j] = bias[j];
    #pragma unroll
    for (int i = 0; i < 4; i++)
      #pragma unroll
      for (int j = 0; j < 8; j++)
        acc[j] += bf2f((bf16t)win[i][j]) * wreg[i][j];
    bf16x8 o;
    #pragma unroll
    for (int j = 0; j < 8; j++) {
      float s = acc[j] / (1.f + __expf(-acc[j]));
      o[j] = (short)f2bf(s);
    }
    *(bf16x8*)&out[(r0 + k) * CONVD + c0] = o;
    win[0] = win[1]; win[1] = win[2]; win[2] = win[3];
  }
}

// ---------- per-chunk states via MFMA (chunks 0..7 only; chunk 8 unused) ----------
__global__ __launch_bounds__(256) void chunk_states_kernel(
    const bf16t* __restrict__ xbc, const float* __restrict__ dt,
    const float* __restrict__ Acum, float* __restrict__ cs) {
  int bid = blockIdx.x;                 // 512
  int h = bid & 15; int bc = bid >> 4;
  int c = bc & 7; int b = bc >> 3;
  int tid = threadIdx.x;
  int lane = tid & 63, w = tid >> 6;
  long tch = (long)b * T_ + c * CK;
  int acb = ((b * NH + h) * NCHUNK + c) * CK;
  float Alast = Acum[acb + CK - 1];

  __shared__ bf16t Xt[128][72];
  __shared__ bf16t Bt[64][72];
  __shared__ float wk[64];

  f32x4 acc[8] = {};
  for (int kb = 0; kb < 4; kb++) {
    int s0 = kb * 64;
    __syncthreads();
    if (tid < 64)
      wk[tid] = __expf(Alast - Acum[acb + s0 + tid]) * dt[(tch + s0 + tid) * NH + h];
    __syncthreads();
    for (int e = tid; e < 64 * 32; e += 256) {
      int s = e & 63, p4 = e >> 6;
      ushort4 u = *(const ushort4*)&xbc[(tch + s0 + s) * CONVD + h * HD + p4 * 4];
      float wv = wk[s];
      Xt[p4 * 4 + 0][s] = f2bf(bf2f(u.x) * wv);
      Xt[p4 * 4 + 1][s] = f2bf(bf2f(u.y) * wv);
      Xt[p4 * 4 + 2][s] = f2bf(bf2f(u.z) * wv);
      Xt[p4 * 4 + 3][s] = f2bf(bf2f(u.w) * wv);
    }
    for (int e = tid; e < 64 * 16; e += 256) {
      int s = e & 63, n4 = e >> 6;
      ushort4 u = *(const ushort4*)&xbc[(tch + s0 + s) * CONVD + DINNER + n4 * 4];
      Bt[n4 * 4 + 0][s] = u.x; Bt[n4 * 4 + 1][s] = u.y;
      Bt[n4 * 4 + 2][s] = u.z; Bt[n4 * 4 + 3][s] = u.w;
    }
    __syncthreads();
    #pragma unroll
    for (int ks = 0; ks < 2; ks++) {
      int koff = (lane >> 4) * 8 + ks * 32;
      bf16x8 bfr = *(bf16x8*)&Bt[w * 16 + (lane & 15)][koff];
      #pragma unroll
      for (int mi = 0; mi < 8; mi++) {
        bf16x8 af = *(bf16x8*)&Xt[mi * 16 + (lane & 15)][koff];
        acc[mi] = __builtin_amdgcn_mfma_f32_16x16x32_bf16(af, bfr, acc[mi], 0, 0, 0);
      }
    }
  }
  int cbid = (b * NCHUNK + c) * NH + h;
  float* out = cs + (long)cbid * HD * NSTATE;
  int n = w * 16 + (lane & 15);
  #pragma unroll
  for (int mi = 0; mi < 8; mi++) {
    #pragma unroll
    for (int r = 0; r < 4; r++) {
      int p = mi * 16 + (lane >> 4) * 4 + r;
      out[p * NSTATE + n] = acc[mi][r];
    }
  }
}

// ---------- sequential inter-chunk recurrence, IN PLACE ----------
__global__ __launch_bounds__(256) void state_pass_kernel(
    float* __restrict__ cs, const float* __restrict__ Acum) {
  int bh = blockIdx.x;                  // b*NH + h
  int b = bh / NH, h = bh % NH;
  int e0 = blockIdx.y * 1024 + threadIdx.x;
  for (int q = 0; q < 4; q++) {
    int e = e0 + q * 256;
    float s = 0.f;
    for (int c = 0; c < NCHUNK; c++) {
      long idx = ((long)(b * NCHUNK + c) * NH + h) * (HD * NSTATE) + e;
      if (c < NCHUNK - 1) {
        float tmp = cs[idx];
        cs[idx] = s;
        float g = __expf(Acum[((b * NH + h) * NCHUNK + c) * CK + CK - 1]);
        s = s * g + tmp;
      } else {
        cs[idx] = s;
      }
    }
  }
}

// ---------- SSD Y via MFMA (chunks 1..8; chunk 0's Y is discarded downstream) ----------
__global__ __launch_bounds__(256) void ssd_y_kernel(
    const bf16t* __restrict__ xbc, const float* __restrict__ dt,
    const float* __restrict__ Acum, const float* __restrict__ sin_,
    const float* __restrict__ Dskip, bf16t* __restrict__ Y) {
  int bid = blockIdx.x;                 // 512
  int h = bid & 15; int bc = bid >> 4;
  int c = 1 + (bc & 7); int b = bc >> 3;
  int rt = blockIdx.y;
  int tid = threadIdx.x;
  int lane = tid & 63, w = tid >> 6;
  int wr = w >> 1, wc = w & 1;
  long tch = (long)b * T_ + c * CK;
  long tbase = tch + rt * 128;
  int acb = ((b * NH + h) * NCHUNK + c) * CK;

  __shared__ bf16t Cs[128][72];
  __shared__ bf16t Bs[64][72];
  __shared__ bf16t Xt[128][72];
  __shared__ bf16t Sm[128][72];
  __shared__ float Akl[128];
  __shared__ float Asl[64];
  __shared__ float dts[64];

  for (int e = tid; e < 128 * 8; e += 256) {
    int row = e >> 3, seg = (e & 7) * 8;
    *(bf16x8*)&Cs[row][seg] =
        *(const bf16x8*)&xbc[(tbase + row) * CONVD + DINNER + NSTATE + seg];
  }
  if (tid < 128) Akl[tid] = Acum[acb + rt * 128 + tid];

  f32x4 acc[4][4] = {};
  int nsb = 2 * (rt + 1);
  for (int sb = 0; sb < nsb; sb++) {
    int s0 = sb * 64;
    __syncthreads();
    if (tid < 64) {
      Asl[tid] = Acum[acb + s0 + tid];
      dts[tid] = dt[(tch + s0 + tid) * NH + h];
    }
    __syncthreads();
    for (int e = tid; e < 64 * 8; e += 256) {
      int row = e >> 3, seg = (e & 7) * 8;
      *(bf16x8*)&Bs[row][seg] =
          *(const bf16x8*)&xbc[(tch + s0 + row) * CONVD + DINNER + seg];
    }
    for (int e = tid; e < 64 * 32; e += 256) {
      int s = e & 63, p4 = e >> 6;
      ushort4 u = *(const ushort4*)&xbc[(tch + s0 + s) * CONVD + h * HD + p4 * 4];
      float dtv = dts[s];
      Xt[p4 * 4 + 0][s] = f2bf(bf2f(u.x) * dtv);
      Xt[p4 * 4 + 1][s] = f2bf(bf2f(u.y) * dtv);
      Xt[p4 * 4 + 2][s] = f2bf(bf2f(u.z) * dtv);
      Xt[p4 * 4 + 3][s] = f2bf(bf2f(u.w) * dtv);
    }
    __syncthreads();
    {
      f32x4 sacc[2][4] = {};
      int rw0 = w * 32;
      #pragma unroll
      for (int ks = 0; ks < 2; ks++) {
        int koff = (lane >> 4) * 8 + ks * 32;
        bf16x8 a0 = *(bf16x8*)&Cs[rw0 + (lane & 15)][koff];
        bf16x8 a1 = *(bf16x8*)&Cs[rw0 + 16 + (lane & 15)][koff];
        #pragma unroll
        for (int ni = 0; ni < 4; ni++) {
          bf16x8 bfr = *(bf16x8*)&Bs[ni * 16 + (lane & 15)][koff];
          sacc[0][ni] = __builtin_amdgcn_mfma_f32_16x16x32_bf16(a0, bfr, sacc[0][ni], 0, 0, 0);
          sacc[1][ni] = __builtin_amdgcn_mfma_f32_16x16x32_bf16(a1, bfr, sacc[1][ni], 0, 0, 0);
        }
      }
      #pragma unroll
      for (int mi = 0; mi < 2; mi++) {
        #pragma unroll
        for (int ni = 0; ni < 4; ni++) {
          #pragma unroll
          for (int r = 0; r < 4; r++) {
            int row = rw0 + mi * 16 + (lane >> 4) * 4 + r;
            int scol = ni * 16 + (lane & 15);
            int kglob = rt * 128 + row;
            int sglob = s0 + scol;
            float val = 0.f;
            if (sglob <= kglob) val = sacc[mi][ni][r] * __expf(Akl[row] - Asl[scol]);
            Sm[row][scol] = f2bf(val);
          }
        }
      }
    }
    __syncthreads();
    #pragma unroll
    for (int ks = 0; ks < 2; ks++) {
      int koff = (lane >> 4) * 8 + ks * 32;
      bf16x8 af[4], bfr[4];
      #pragma unroll
      for (int mi = 0; mi < 4; mi++) af[mi] = *(bf16x8*)&Sm[wr * 64 + mi * 16 + (lane & 15)][koff];
      #pragma unroll
      for (int ni = 0; ni < 4; ni++) bfr[ni] = *(bf16x8*)&Xt[wc * 64 + ni * 16 + (lane & 15)][koff];
      #pragma unroll
      for (int mi = 0; mi < 4; mi++)
        #pragma unroll
        for (int ni = 0; ni < 4; ni++)
          acc[mi][ni] = __builtin_amdgcn_mfma_f32_16x16x32_bf16(af[mi], bfr[ni], acc[mi][ni], 0, 0, 0);
    }
  }

  float ekr[16];
  #pragma unroll
  for (int mi = 0; mi < 4; mi++)
    #pragma unroll
    for (int r = 0; r < 4; r++)
      ekr[mi * 4 + r] = __expf(Akl[wr * 64 + mi * 16 + (lane >> 4) * 4 + r]);

  int cbid = (b * NCHUNK + c) * NH + h;
  const float* sinb = sin_ + (long)cbid * HD * NSTATE;
  #pragma unroll
  for (int ni = 0; ni < 4; ni++) {
    f32x4 offacc[4] = {};
    int p = wc * 64 + ni * 16 + (lane & 15);
    #pragma unroll
    for (int ks = 0; ks < 2; ks++) {
      int koff = (lane >> 4) * 8 + ks * 32;
      const float* srow = sinb + p * NSTATE + koff;
      float4 sa = *(const float4*)srow;
      float4 sbv = *(const float4*)(srow + 4);
      bf16x8 bfr;
      bfr[0] = (short)f2bf(sa.x);  bfr[1] = (short)f2bf(sa.y);
      bfr[2] = (short)f2bf(sa.z);  bfr[3] = (short)f2bf(sa.w);
      bfr[4] = (short)f2bf(sbv.x); bfr[5] = (short)f2bf(sbv.y);
      bfr[6] = (short)f2bf(sbv.z); bfr[7] = (short)f2bf(sbv.w);
      #pragma unroll
      for (int mi = 0; mi < 4; mi++) {
        bf16x8 af = *(bf16x8*)&Cs[wr * 64 + mi * 16 + (lane & 15)][koff];
        offacc[mi] = __builtin_amdgcn_mfma_f32_16x16x32_bf16(af, bfr, offacc[mi], 0, 0, 0);
      }
    }
    #pragma unroll
    for (int mi = 0; mi < 4; mi++)
      #pragma unroll
      for (int r = 0; r < 4; r++)
        acc[mi][ni][r] += ekr[mi * 4 + r] * offacc[mi][r];
  }

  float dsk = Dskip[h];
  #pragma unroll
  for (int mi = 0; mi < 4; mi++) {
    #pragma unroll
    for (int r = 0; r < 4; r++) {
      int row = wr * 64 + mi * 16 + (lane >> 4) * 4 + r;
      long t = tbase + row;
      #pragma unroll
      for (int ni = 0; ni < 4; ni++) {
        int p = wc * 64 + ni * 16 + (lane & 15);
        float xsv = bf2f(xbc[t * CONVD + h * HD + p]);
        Y[t * DINNER + h * HD + p] = f2bf(acc[mi][ni][r] + dsk * xsv);
      }
    }
  }
}

// ---------- gate+RMSNorm (local rows only) fused with late weight cvt ----------
__global__ __launch_bounds__(256) void gate_rms_cvt_kernel(
    const bf16t* __restrict__ z, const float* __restrict__ nw,
    bf16t* __restrict__ Y,
    const float* __restrict__ outw, const float* __restrict__ f1w,
    const float* __restrict__ f2w, bf16t* __restrict__ o_out,
    bf16t* __restrict__ o_f1, bf16t* __restrict__ o_f2) {
  int blk = blockIdx.x;
  if (blk < B_ * L_) {
    long r = (long)(blk >> 11) * T_ + G_ + (blk & 2047);
    const bf16t* zrow = z + r * DINNER;
    bf16t* yrow = Y + r * DINNER;
    int tid = threadIdx.x;
    float v[8]; float sq = 0.f;
    #pragma unroll
    for (int i = 0; i < 4; i++) {
      int d = tid * 2 + 512 * i;
      ushort2 zu = *(const ushort2*)&zrow[d];
      ushort2 yu = *(const ushort2*)&yrow[d];
      float z0 = bf2f(zu.x), z1 = bf2f(zu.y);
      float y0 = bf2f(yu.x) * (z0 / (1.f + __expf(-z0)));
      float y1 = bf2f(yu.y) * (z1 / (1.f + __expf(-z1)));
      v[2 * i] = y0; v[2 * i + 1] = y1;
      sq += y0 * y0 + y1 * y1;
    }
    float2 r2 = block_reduce2(sq, 0.f);
    float rms = rsqrtf(r2.x * (1.f / DINNER) + EPSV);
    #pragma unroll
    for (int i = 0; i < 4; i++) {
      int d = tid * 2 + 512 * i;
      ushort2 o;
      o.x = f2bf(v[2 * i] * rms * nw[d]);
      o.y = f2bf(v[2 * i + 1] * rms * nw[d + 1]);
      *(ushort2*)&yrow[d] = o;
    }
  } else {
    long i = (long)(blk - B_ * L_) * 1024 + threadIdx.x * 4;
    const long n1 = (long)DM * DINNER;          // 2097152
    const long n2 = (long)(DM / 2) * DM;        // 524288
    const float* src; bf16t* dst; long off;
    if (i < n1) { src = outw; dst = o_out; off = i; }
    else if (i < n1 + n2) { src = f1w; dst = o_f1; off = i - n1; }
    else { src = f2w; dst = o_f2; off = i - n1 - n2; }
    float4 v = *(const float4*)&src[off];
    ushort4 o;
    o.x = f2bf(v.x); o.y = f2bf(v.y); o.z = f2bf(v.z); o.w = f2bf(v.w);
    *(ushort4*)&dst[off] = o;
  }
}

// ---------- residual add + LayerNorm3 -> bf16 (mfull compact [8192][1024]) ----------
__global__ __launch_bounds__(256) void res_ln3_kernel(
    const bf16t* __restrict__ mfull, const bf16t* __restrict__ x,
    const float* __restrict__ w3, const float* __restrict__ b3,
    bf16t* __restrict__ x2) {
  int rl = blockIdx.x;                  // b*L_ + tl
  int tl = rl & 2047, b = rl >> 11;
  long rt = (long)b * T_ + G_ + tl;
  const bf16t* m = mfull + (long)rl * DM;
  const bf16t* xr = x + rt * DM;
  int tid = threadIdx.x;
  float v[4]; float s = 0.f, sq = 0.f;
  #pragma unroll
  for (int i = 0; i < 2; i++) {
    int d = tid * 2 + 512 * i;
    ushort2 mu2 = *(const ushort2*)&m[d];
    ushort2 xu2 = *(const ushort2*)&xr[d];
    float a0 = bf2f(mu2.x) + bf2f(xu2.x);
    float a1 = bf2f(mu2.y) + bf2f(xu2.y);
    v[2 * i] = a0; v[2 * i + 1] = a1;
    s += a0 + a1; sq += a0 * a0 + a1 * a1;
  }
  float2 r2 = block_reduce2(s, sq);
  float mu = r2.x * (1.f / DM);
  float var = r2.y * (1.f / DM) - mu * mu;
  float rstd = rsqrtf(var + EPSV);
  bf16t* dst = x2 + (long)rl * DM;
  #pragma unroll
  for (int i = 0; i < 2; i++) {
    int d = tid * 2 + 512 * i;
    ushort2 o;
    o.x = f2bf((v[2 * i] - mu) * rstd * w3[d] + b3[d]);
    o.y = f2bf((v[2 * i + 1] - mu) * rstd * w3[d + 1] + b3[d + 1]);
    *(ushort2*)&dst[d] = o;
  }
}

extern "C" void kernel_launch(void* const* d_in, const int* in_sizes, int n_in,
                              void* d_out, int out_size, void* d_ws, size_t ws_size,
                              hipStream_t stream) {
  const float* localr = (const float*)d_in[0];
  const float* globalr= (const float*)d_in[1];
  const float* n1w = (const float*)d_in[2];
  const float* n1b = (const float*)d_in[3];
  const float* n2w = (const float*)d_in[4];
  const float* n2b = (const float*)d_in[5];
  const float* n3w = (const float*)d_in[6];
  const float* n3b = (const float*)d_in[7];
  const float* inpw= (const float*)d_in[8];
  const float* convw=(const float*)d_in[9];
  const float* convb=(const float*)d_in[10];
  const float* dtb = (const float*)d_in[11];
  const float* alog= (const float*)d_in[12];
  const float* dskp= (const float*)d_in[13];
  const float* ssdw= (const float*)d_in[14];
  const float* outw= (const float*)d_in[15];
  const float* f1w = (const float*)d_in[16];
  const float* f1b = (const float*)d_in[17];
  const float* f2w = (const float*)d_in[18];
  const float* f2b = (const float*)d_in[19];

  // ---- workspace layout (byte offsets); peak ~150 MB ----
  char* ws = (char*)d_ws;
  bf16t* x     = (bf16t*)(ws + 0);             // 9216*1024 bf16
  bf16t* z     = (bf16t*)(ws + 18874368);      // 9216*2048 bf16
  bf16t* mfull = (bf16t*)(ws + 18874368);      //   overlay: 8192*1024 bf16 compact
  bf16t* xpre  = (bf16t*)(ws + 56623104);      // 9216*2176 bf16
  bf16t* Yb    = (bf16t*)(ws + 56623104);      //   overlay: 9216*2048 bf16 (after conv)
  float* dtraw = (float*)(ws + 96731136);      // 9216*16 f32
  float* dt    = (float*)(ws + 97320960);      // 9216*16 f32
  float* Acum  = (float*)(ws + 97910784);      // 64*9*256 f32
  bf16t* xbc   = (bf16t*)(ws + 98500608);      // 9216*2176 bf16
  bf16t* x2bf  = (bf16t*)(ws + 98500608);      //   overlay after ssd_y: 8192*1024 bf16
  bf16t* hbuf  = (bf16t*)(ws + 115277824);     //   overlay: 8192*512 bf16
  bf16t* outw_bf = (bf16t*)(ws + 123666432);   //   overlay: 1024*2048 bf16
  bf16t* f1w_bf  = (bf16t*)(ws + 127860736);   //   overlay: 512*1024 bf16
  bf16t* f2w_bf  = (bf16t*)(ws + 128909312);   //   overlay: 1024*512 bf16
  float* cs    = (float*)(ws + 138608640);     // 576*8192 f32
  bf16t* inpw_bf = (bf16t*)(ws + 138608640);   //   overlay BEFORE chunk_states

  ln_cvt_kernel<<<B_ * T_ + 4352, 256, 0, stream>>>(
      localr, globalr, n1w, n1b, n2w, n2b, x, inpw, inpw_bf);

  gemm_mfma<0, false><<<dim3(NPROJ_PAD / 128, (B_ * T_) / 128), 256, 0, stream>>>(
      x, inpw_bf, nullptr, nullptr, nullptr, nullptr, z, xpre, dtraw, NPROJ_PAD, DM);

  cumsum_kernel<<<B_ * NH * NCHUNK, 256, 0, stream>>>(dtraw, dtb, alog, dt, Acum);

  conv_kernel<<<(B_ * T_ / CROWS) * 272 / 256, 256, 0, stream>>>(xpre, convw, convb, xbc);

  chunk_states_kernel<<<B_ * (NCHUNK - 1) * NH, 256, 0, stream>>>(xbc, dt, Acum, cs);

  state_pass_kernel<<<dim3(B_ * NH, 8), 256, 0, stream>>>(cs, Acum);

  ssd_y_kernel<<<dim3(B_ * (NCHUNK - 1) * NH, 2), 256, 0, stream>>>(
      xbc, dt, Acum, cs, dskp, Yb);

  gate_rms_cvt_kernel<<<B_ * L_ + 3072, 256, 0, stream>>>(
      z, ssdw, Yb, outw, f1w, f2w, outw_bf, f1w_bf, f2w_bf);

  gemm_mfma<1, true><<<dim3(DM / 128, (B_ * L_) / 128), 256, 0, stream>>>(
      Yb, outw_bf, nullptr, nullptr, nullptr, mfull, nullptr, nullptr, nullptr,
      DM, DINNER);

  res_ln3_kernel<<<B_ * L_, 256, 0, stream>>>(mfull, x, n3w, n3b, x2bf);

  gemm_mfma<2, false><<<dim3((DM / 2) / 128, (B_ * L_) / 128), 256, 0, stream>>>(
      x2bf, f1w_bf, f1b, nullptr, nullptr, hbuf, nullptr, nullptr, nullptr,
      DM / 2, DM);

  gemm_mfma<3, false><<<dim3(DM / 128, (B_ * L_) / 128), 256, 0, stream>>>(
      hbuf, f2w_bf, f2b, x2bf, (float*)d_out, nullptr, nullptr, nullptr, nullptr,
      DM, DM / 2);
}